// Round 1
// baseline (812.144 us; speedup 1.0000x reference)
//
#include <hip/hip_runtime.h>

#define N_NODES 50000
#define E_EDGES 800000
#define EA (E_EDGES + N_NODES)   // 850000 edges incl self loops
#define CH 128                   // HEADS*OUT
#define NG 128                   // num graphs
#define NEG 0.2f
#define GR 32                    // gemm rows per block

// ---------------- CSR build ----------------
__global__ void hist_kernel(const int* __restrict__ ei, int* __restrict__ deg) {
    int e = blockIdx.x * blockDim.x + threadIdx.x;
    if (e >= EA) return;
    int d = (e < E_EDGES) ? ei[E_EDGES + e] : (e - E_EDGES);
    atomicAdd(&deg[d], 1);
}

__global__ void scan_kernel(const int* __restrict__ deg, int* __restrict__ rowstart) {
    __shared__ int buf[1024];
    __shared__ int carry_s;
    if (threadIdx.x == 0) carry_s = 0;
    __syncthreads();
    for (int base = 0; base < N_NODES; base += 1024) {
        int i = base + threadIdx.x;
        int v = (i < N_NODES) ? deg[i] : 0;
        buf[threadIdx.x] = v;
        __syncthreads();
        for (int off = 1; off < 1024; off <<= 1) {
            int t = (threadIdx.x >= off) ? buf[threadIdx.x - off] : 0;
            __syncthreads();
            buf[threadIdx.x] += t;
            __syncthreads();
        }
        if (i < N_NODES) rowstart[i] = carry_s + buf[threadIdx.x] - v;  // exclusive
        __syncthreads();
        if (threadIdx.x == 1023) carry_s += buf[1023];
        __syncthreads();
    }
    if (threadIdx.x == 0) rowstart[N_NODES] = carry_s;
}

__global__ void scatter_kernel(const int* __restrict__ ei, const int* __restrict__ rowstart,
                               int* __restrict__ cursor, int* __restrict__ csr) {
    int e = blockIdx.x * blockDim.x + threadIdx.x;
    if (e >= EA) return;
    int d = (e < E_EDGES) ? ei[E_EDGES + e] : (e - E_EDGES);
    int pos = rowstart[d] + atomicAdd(&cursor[d], 1);
    csr[pos] = e;
}

// ---------------- dense: H = X @ W  (N x 128) @ (128 x 128) ----------------
__global__ __launch_bounds__(256) void gemm_kernel(const float* __restrict__ X,
                                                   const float* __restrict__ W,
                                                   float* __restrict__ H) {
    __shared__ float Ws[128 * 64];
    __shared__ float Xs[GR][129];   // +1 pad: avoid 4-way bank conflict on column reads
    int row0 = blockIdx.x * GR;
    for (int i = threadIdx.x; i < GR * 128; i += 256) {
        int r = row0 + (i >> 7);
        Xs[i >> 7][i & 127] = (r < N_NODES) ? X[r * 128 + (i & 127)] : 0.f;
    }
    int c_in = threadIdx.x & 63;
    int rsub = threadIdx.x >> 6;   // 0..3
    for (int half = 0; half < 2; ++half) {
        __syncthreads();           // Ws reuse + Xs ready
        for (int i = threadIdx.x; i < 128 * 64; i += 256)
            Ws[i] = W[(i >> 6) * 128 + half * 64 + (i & 63)];
        __syncthreads();
        float acc[8] = {0, 0, 0, 0, 0, 0, 0, 0};
        for (int k = 0; k < 128; ++k) {
            float w = Ws[k * 64 + c_in];
#pragma unroll
            for (int i = 0; i < 8; ++i)
                acc[i] += Xs[rsub * 8 + i][k] * w;
        }
        int c = half * 64 + c_in;
#pragma unroll
        for (int i = 0; i < 8; ++i) {
            int r = row0 + rsub * 8 + i;
            if (r < N_NODES) H[r * 128 + c] = acc[i];
        }
    }
}

// ---------------- alpha_src / alpha_dst per node (one wave per node) ----------------
__global__ __launch_bounds__(256) void alpha_kernel(const float* __restrict__ H,
                                                    const float* __restrict__ as_,
                                                    const float* __restrict__ ad_,
                                                    float* __restrict__ als,
                                                    float* __restrict__ ald) {
    int n = blockIdx.x * (blockDim.x >> 6) + (threadIdx.x >> 6);
    if (n >= N_NODES) return;
    int lane = threadIdx.x & 63;
    float h0 = H[n * 128 + lane];
    float h1 = H[n * 128 + 64 + lane];
    float s0 = h0 * as_[lane], s1 = h1 * as_[64 + lane];
    float d0 = h0 * ad_[lane], d1 = h1 * ad_[64 + lane];
    for (int o = 32; o; o >>= 1) {
        s0 += __shfl_xor(s0, o); s1 += __shfl_xor(s1, o);
        d0 += __shfl_xor(d0, o); d1 += __shfl_xor(d1, o);
    }
    if (lane == 0) {
        als[n * 2] = s0; als[n * 2 + 1] = s1;
        ald[n * 2] = d0; ald[n * 2 + 1] = d1;
    }
}

// ---------------- per-node softmax + weighted aggregation (one wave per node) ----------------
__global__ __launch_bounds__(256) void agg_kernel(const float* __restrict__ H,
                                                  const int* __restrict__ ei,
                                                  const float* __restrict__ ec,
                                                  const float* __restrict__ nc,
                                                  const float* __restrict__ als,
                                                  const float* __restrict__ ald,
                                                  const int* __restrict__ rowstart,
                                                  const int* __restrict__ csr,
                                                  const float* __restrict__ bias,
                                                  float* __restrict__ Ho) {
    int n = blockIdx.x * (blockDim.x >> 6) + (threadIdx.x >> 6);
    if (n >= N_NODES) return;
    int lane = threadIdx.x & 63;
    int start = rowstart[n], end = rowstart[n + 1];
    float adv0 = ald[n * 2], adv1 = ald[n * 2 + 1];

    // pass 1: segment max (every node has a self loop -> non-empty)
    float m0 = -1e30f, m1 = -1e30f;
    for (int i = start + lane; i < end; i += 64) {
        int e = csr[i];
        int s = (e < E_EDGES) ? ei[e] : (e - E_EDGES);
        float a0 = als[s * 2] + adv0;     a0 = (a0 > 0.f) ? a0 : NEG * a0;
        float a1 = als[s * 2 + 1] + adv1; a1 = (a1 > 0.f) ? a1 : NEG * a1;
        m0 = fmaxf(m0, a0); m1 = fmaxf(m1, a1);
    }
    for (int o = 32; o; o >>= 1) { m0 = fmaxf(m0, __shfl_xor(m0, o)); m1 = fmaxf(m1, __shfl_xor(m1, o)); }

    // pass 2: sum of exp
    float s0 = 0.f, s1 = 0.f;
    for (int i = start + lane; i < end; i += 64) {
        int e = csr[i];
        int s = (e < E_EDGES) ? ei[e] : (e - E_EDGES);
        float a0 = als[s * 2] + adv0;     a0 = (a0 > 0.f) ? a0 : NEG * a0;
        float a1 = als[s * 2 + 1] + adv1; a1 = (a1 > 0.f) ? a1 : NEG * a1;
        s0 += __expf(a0 - m0); s1 += __expf(a1 - m1);
    }
    for (int o = 32; o; o >>= 1) { s0 += __shfl_xor(s0, o); s1 += __shfl_xor(s1, o); }
    float inv0 = 1.f / (s0 + 1e-16f), inv1 = 1.f / (s1 + 1e-16f);

    // pass 3: weighted gather; lane owns channels (lane) and (64+lane)
    float acc0 = 0.f, acc1 = 0.f;
    for (int i = start; i < end; ++i) {
        int e = csr[i];
        int s; float nq;
        if (e < E_EDGES) { s = ei[e]; nq = ec[e]; }
        else             { s = e - E_EDGES; nq = nc[s]; }
        float a0 = als[s * 2] + adv0;     a0 = (a0 > 0.f) ? a0 : NEG * a0;
        float a1 = als[s * 2 + 1] + adv1; a1 = (a1 > 0.f) ? a1 : NEG * a1;
        float w0 = nq * __expf(a0 - m0) * inv0;
        float w1 = nq * __expf(a1 - m1) * inv1;
        acc0 += w0 * H[s * 128 + lane];
        acc1 += w1 * H[s * 128 + 64 + lane];
    }
    float o0 = acc0 + bias[lane];
    float o1 = acc1 + bias[64 + lane];
    Ho[n * 128 + lane]      = o0 > 0.f ? o0 : 0.f;
    Ho[n * 128 + 64 + lane] = o1 > 0.f ? o1 : 0.f;
}

// ---------------- global mean pool (batch is sorted) ----------------
__global__ void pool_kernel(const float* __restrict__ H, const int* __restrict__ batch,
                            float* __restrict__ pooled) {
    int g = blockIdx.x;
    int lo = 0, hi = N_NODES;
    while (lo < hi) { int mid = (lo + hi) >> 1; if (batch[mid] < g) lo = mid + 1; else hi = mid; }
    int start = lo;
    hi = N_NODES;
    while (lo < hi) { int mid = (lo + hi) >> 1; if (batch[mid] <= g) lo = mid + 1; else hi = mid; }
    int end = lo;
    int c = threadIdx.x;   // 128 threads
    float acc = 0.f;
    for (int i = start; i < end; ++i) acc += H[i * 128 + c];
    pooled[g * 128 + c] = acc / fmaxf((float)(end - start), 1.f);
}

// ---------------- classifier: pooled @ Wc + bc ----------------
__global__ void cls_kernel(const float* __restrict__ pooled, const float* __restrict__ Wc,
                           const float* __restrict__ bc, float* __restrict__ outp) {
    int g = blockIdx.x;
    __shared__ float p[128];
    p[threadIdx.x] = pooled[g * 128 + threadIdx.x];
    __syncthreads();
    if (threadIdx.x < 10) {
        float acc = bc[threadIdx.x];
        for (int k = 0; k < 128; ++k) acc += p[k] * Wc[k * 10 + threadIdx.x];
        outp[g * 10 + threadIdx.x] = acc;
    }
}

extern "C" void kernel_launch(void* const* d_in, const int* in_sizes, int n_in,
                              void* d_out, int out_size, void* d_ws, size_t ws_size,
                              hipStream_t stream) {
    const float* x     = (const float*)d_in[0];
    const int*   ei    = (const int*)d_in[1];     // [2,E]: src @0, dst @E
    const int*   batch = (const int*)d_in[2];
    const float* nc    = (const float*)d_in[3];
    const float* ec    = (const float*)d_in[4];
    const float* W0    = (const float*)d_in[5];
    const float* as0   = (const float*)d_in[6];
    const float* ad0   = (const float*)d_in[7];
    const float* b0    = (const float*)d_in[8];
    const float* W1    = (const float*)d_in[9];
    const float* as1   = (const float*)d_in[10];
    const float* ad1   = (const float*)d_in[11];
    const float* b1    = (const float*)d_in[12];
    const float* Wc    = (const float*)d_in[13];
    const float* bc    = (const float*)d_in[14];
    float* out = (float*)d_out;

    char* ws = (char*)d_ws;
    size_t off = 0;
    auto alloc = [&](size_t bytes) { void* p = ws + off; off += (bytes + 255) & ~size_t(255); return p; };
    float* h0       = (float*)alloc(sizeof(float) * N_NODES * 128);
    float* h1       = (float*)alloc(sizeof(float) * N_NODES * 128);
    float* als      = (float*)alloc(sizeof(float) * N_NODES * 2);
    float* ald      = (float*)alloc(sizeof(float) * N_NODES * 2);
    int*   deg      = (int*)alloc(sizeof(int) * N_NODES);
    int*   rowstart = (int*)alloc(sizeof(int) * (N_NODES + 1));
    int*   cursor   = (int*)alloc(sizeof(int) * N_NODES);
    int*   csr      = (int*)alloc(sizeof(int) * EA);
    float* pooled   = (float*)alloc(sizeof(float) * NG * 128);

    hipMemsetAsync(deg, 0, sizeof(int) * N_NODES, stream);
    hipMemsetAsync(cursor, 0, sizeof(int) * N_NODES, stream);

    hist_kernel<<<(EA + 255) / 256, 256, 0, stream>>>(ei, deg);
    scan_kernel<<<1, 1024, 0, stream>>>(deg, rowstart);
    scatter_kernel<<<(EA + 255) / 256, 256, 0, stream>>>(ei, rowstart, cursor, csr);

    int gemm_grid   = (N_NODES + GR - 1) / GR;
    int nwaveblocks = (N_NODES * 64 + 255) / 256;   // 4 nodes (waves) per 256-thread block

    // layer 0
    gemm_kernel<<<gemm_grid, 256, 0, stream>>>(x, W0, h0);
    alpha_kernel<<<nwaveblocks, 256, 0, stream>>>(h0, as0, ad0, als, ald);
    agg_kernel<<<nwaveblocks, 256, 0, stream>>>(h0, ei, ec, nc, als, ald, rowstart, csr, b0, h1);

    // layer 1
    gemm_kernel<<<gemm_grid, 256, 0, stream>>>(h1, W1, h0);
    alpha_kernel<<<nwaveblocks, 256, 0, stream>>>(h0, as1, ad1, als, ald);
    agg_kernel<<<nwaveblocks, 256, 0, stream>>>(h0, ei, ec, nc, als, ald, rowstart, csr, b1, h1);

    // pool + classifier
    pool_kernel<<<NG, 128, 0, stream>>>(h1, batch, pooled);
    cls_kernel<<<NG, 128, 0, stream>>>(pooled, Wc, bc, out);
}

// Round 2
// 580.332 us; speedup vs baseline: 1.3994x; 1.3994x over previous
//
#include <hip/hip_runtime.h>

#define N_NODES 50000
#define E_EDGES 800000
#define EA (E_EDGES + N_NODES)   // 850000 edges incl self loops
#define CH 128                   // HEADS*OUT
#define NG 128                   // num graphs
#define NEG 0.2f
#define GR 32                    // gemm rows per block
#define NB_SCAN ((N_NODES + 255) / 256)   // 196 scan blocks

// ---------------- CSR build ----------------
__global__ void hist_kernel(const int* __restrict__ ei, int* __restrict__ deg) {
    int e = blockIdx.x * blockDim.x + threadIdx.x;
    if (e >= EA) return;
    int d = (e < E_EDGES) ? ei[E_EDGES + e] : (e - E_EDGES);
    atomicAdd(&deg[d], 1);
}

// two-level scan: per-block sums -> scan of partials -> per-block exclusive scan + offset
__global__ void partial_kernel(const int* __restrict__ deg, int* __restrict__ part) {
    __shared__ int buf[4];
    int i = blockIdx.x * 256 + threadIdx.x;
    int v = (i < N_NODES) ? deg[i] : 0;
    for (int o = 32; o; o >>= 1) v += __shfl_xor(v, o);
    if ((threadIdx.x & 63) == 0) buf[threadIdx.x >> 6] = v;
    __syncthreads();
    if (threadIdx.x == 0) part[blockIdx.x] = buf[0] + buf[1] + buf[2] + buf[3];
}

__global__ void scanpart_kernel(int* __restrict__ part, int* __restrict__ rowstart) {
    __shared__ int buf[256];
    int t = threadIdx.x;
    int v = (t < NB_SCAN) ? part[t] : 0;
    buf[t] = v;
    __syncthreads();
    for (int o = 1; o < 256; o <<= 1) {
        int u = (t >= o) ? buf[t - o] : 0;
        __syncthreads();
        buf[t] += u;
        __syncthreads();
    }
    if (t < NB_SCAN) part[t] = buf[t] - v;          // exclusive
    if (t == NB_SCAN - 1) rowstart[N_NODES] = buf[t]; // total (= EA)
}

__global__ void rowstart_kernel(const int* __restrict__ deg, const int* __restrict__ part,
                                int* __restrict__ rowstart) {
    __shared__ int buf[256];
    int i = blockIdx.x * 256 + threadIdx.x;
    int v = (i < N_NODES) ? deg[i] : 0;
    buf[threadIdx.x] = v;
    __syncthreads();
    for (int o = 1; o < 256; o <<= 1) {
        int u = (threadIdx.x >= o) ? buf[threadIdx.x - o] : 0;
        __syncthreads();
        buf[threadIdx.x] += u;
        __syncthreads();
    }
    if (i < N_NODES) rowstart[i] = part[blockIdx.x] + buf[threadIdx.x] - v;
}

__global__ void scatter_kernel(const int* __restrict__ ei, const int* __restrict__ rowstart,
                               int* __restrict__ cursor, int* __restrict__ csr) {
    int e = blockIdx.x * blockDim.x + threadIdx.x;
    if (e >= EA) return;
    int d = (e < E_EDGES) ? ei[E_EDGES + e] : (e - E_EDGES);
    int pos = rowstart[d] + atomicAdd(&cursor[d], 1);
    csr[pos] = e;
}

// ---------------- dense: H = X @ W  (N x 128) @ (128 x 128) ----------------
__global__ __launch_bounds__(256) void gemm_kernel(const float* __restrict__ X,
                                                   const float* __restrict__ W,
                                                   float* __restrict__ H) {
    __shared__ float Ws[128 * 64];
    __shared__ float Xs[GR][129];
    int row0 = blockIdx.x * GR;
    for (int i = threadIdx.x; i < GR * 128; i += 256) {
        int r = row0 + (i >> 7);
        Xs[i >> 7][i & 127] = (r < N_NODES) ? X[r * 128 + (i & 127)] : 0.f;
    }
    int c_in = threadIdx.x & 63;
    int rsub = threadIdx.x >> 6;
    for (int half = 0; half < 2; ++half) {
        __syncthreads();
        for (int i = threadIdx.x; i < 128 * 64; i += 256)
            Ws[i] = W[(i >> 6) * 128 + half * 64 + (i & 63)];
        __syncthreads();
        float acc[8] = {0, 0, 0, 0, 0, 0, 0, 0};
        for (int k = 0; k < 128; ++k) {
            float w = Ws[k * 64 + c_in];
#pragma unroll
            for (int i = 0; i < 8; ++i)
                acc[i] += Xs[rsub * 8 + i][k] * w;
        }
        int c = half * 64 + c_in;
#pragma unroll
        for (int i = 0; i < 8; ++i) {
            int r = row0 + rsub * 8 + i;
            if (r < N_NODES) H[r * 128 + c] = acc[i];
        }
    }
}

// ---------------- alpha_src / alpha_dst per node (one wave per node) ----------------
__global__ __launch_bounds__(256) void alpha_kernel(const float* __restrict__ H,
                                                    const float* __restrict__ as_,
                                                    const float* __restrict__ ad_,
                                                    float* __restrict__ als,
                                                    float* __restrict__ ald) {
    int n = blockIdx.x * (blockDim.x >> 6) + (threadIdx.x >> 6);
    if (n >= N_NODES) return;
    int lane = threadIdx.x & 63;
    float h0 = H[n * 128 + lane];
    float h1 = H[n * 128 + 64 + lane];
    float s0 = h0 * as_[lane], s1 = h1 * as_[64 + lane];
    float d0 = h0 * ad_[lane], d1 = h1 * ad_[64 + lane];
    for (int o = 32; o; o >>= 1) {
        s0 += __shfl_xor(s0, o); s1 += __shfl_xor(s1, o);
        d0 += __shfl_xor(d0, o); d1 += __shfl_xor(d1, o);
    }
    if (lane == 0) {
        als[n * 2] = s0; als[n * 2 + 1] = s1;
        ald[n * 2] = d0; ald[n * 2 + 1] = d1;
    }
}

// ---------------- per-node softmax + aggregation: lane-parallel edge resolve ----------------
__global__ __launch_bounds__(256) void agg_kernel(const float* __restrict__ H,
                                                  const int* __restrict__ ei,
                                                  const float* __restrict__ ec,
                                                  const float* __restrict__ nc,
                                                  const float* __restrict__ als,
                                                  const float* __restrict__ ald,
                                                  const int* __restrict__ rowstart,
                                                  const int* __restrict__ csr,
                                                  const float* __restrict__ bias,
                                                  float* __restrict__ Ho) {
    int n = blockIdx.x * (blockDim.x >> 6) + (threadIdx.x >> 6);
    if (n >= N_NODES) return;
    int lane = threadIdx.x & 63;
    int start = rowstart[n], end = rowstart[n + 1];
    int deg = end - start;
    float adv0 = ald[n * 2], adv1 = ald[n * 2 + 1];

    // chunk 0 (covers deg<=64, i.e. essentially every node): lane j owns edge j
    int   s_reg  = n;
    float nq_reg = 0.f, a0_reg = -1e30f, a1_reg = -1e30f;
    if (lane < deg) {
        int e = csr[start + lane];
        if (e < E_EDGES) { s_reg = ei[e]; nq_reg = ec[e]; }
        else             { s_reg = e - E_EDGES; nq_reg = nc[s_reg]; }
        float a0 = als[s_reg * 2]     + adv0; a0_reg = (a0 > 0.f) ? a0 : NEG * a0;
        float a1 = als[s_reg * 2 + 1] + adv1; a1_reg = (a1 > 0.f) ? a1 : NEG * a1;
    }
    float m0 = a0_reg, m1 = a1_reg;
    // rare multi-chunk fallback for max
    for (int i = start + 64 + lane; i < end; i += 64) {
        int e = csr[i];
        int s = (e < E_EDGES) ? ei[e] : (e - E_EDGES);
        float a0 = als[s * 2] + adv0;     a0 = (a0 > 0.f) ? a0 : NEG * a0;
        float a1 = als[s * 2 + 1] + adv1; a1 = (a1 > 0.f) ? a1 : NEG * a1;
        m0 = fmaxf(m0, a0); m1 = fmaxf(m1, a1);
    }
    for (int o = 32; o; o >>= 1) { m0 = fmaxf(m0, __shfl_xor(m0, o)); m1 = fmaxf(m1, __shfl_xor(m1, o)); }

    float e0_reg = __expf(a0_reg - m0), e1_reg = __expf(a1_reg - m1);
    float s0 = e0_reg, s1 = e1_reg;
    for (int i = start + 64 + lane; i < end; i += 64) {
        int e = csr[i];
        int s = (e < E_EDGES) ? ei[e] : (e - E_EDGES);
        float a0 = als[s * 2] + adv0;     a0 = (a0 > 0.f) ? a0 : NEG * a0;
        float a1 = als[s * 2 + 1] + adv1; a1 = (a1 > 0.f) ? a1 : NEG * a1;
        s0 += __expf(a0 - m0); s1 += __expf(a1 - m1);
    }
    for (int o = 32; o; o >>= 1) { s0 += __shfl_xor(s0, o); s1 += __shfl_xor(s1, o); }
    float inv0 = 1.f / (s0 + 1e-16f), inv1 = 1.f / (s1 + 1e-16f);

    // per-lane final weights for chunk 0
    float w0_reg = nq_reg * e0_reg * inv0;
    float w1_reg = nq_reg * e1_reg * inv1;

    // aggregation: s and w come from registers via shfl -> single independent load/iter
    float acc0 = 0.f, acc1 = 0.f;
    int cnt = (deg < 64) ? deg : 64;
#pragma unroll 4
    for (int j = 0; j < cnt; ++j) {
        int   s  = __shfl(s_reg, j);
        float w0 = __shfl(w0_reg, j);
        float w1 = __shfl(w1_reg, j);
        const float* hp = H + (size_t)s * 128;
        acc0 += w0 * hp[lane];
        acc1 += w1 * hp[64 + lane];
    }
    // rare multi-chunk fallback: serial uniform loop
    for (int i = start + 64; i < end; ++i) {
        int e = csr[i];
        int s; float nq;
        if (e < E_EDGES) { s = ei[e]; nq = ec[e]; }
        else             { s = e - E_EDGES; nq = nc[s]; }
        float a0 = als[s * 2] + adv0;     a0 = (a0 > 0.f) ? a0 : NEG * a0;
        float a1 = als[s * 2 + 1] + adv1; a1 = (a1 > 0.f) ? a1 : NEG * a1;
        float w0 = nq * __expf(a0 - m0) * inv0;
        float w1 = nq * __expf(a1 - m1) * inv1;
        acc0 += w0 * H[s * 128 + lane];
        acc1 += w1 * H[s * 128 + 64 + lane];
    }
    float o0 = acc0 + bias[lane];
    float o1 = acc1 + bias[64 + lane];
    Ho[n * 128 + lane]      = o0 > 0.f ? o0 : 0.f;
    Ho[n * 128 + 64 + lane] = o1 > 0.f ? o1 : 0.f;
}

// ---------------- global mean pool (batch is sorted) ----------------
__global__ void pool_kernel(const float* __restrict__ H, const int* __restrict__ batch,
                            float* __restrict__ pooled) {
    int g = blockIdx.x;
    int lo = 0, hi = N_NODES;
    while (lo < hi) { int mid = (lo + hi) >> 1; if (batch[mid] < g) lo = mid + 1; else hi = mid; }
    int start = lo;
    hi = N_NODES;
    while (lo < hi) { int mid = (lo + hi) >> 1; if (batch[mid] <= g) lo = mid + 1; else hi = mid; }
    int end = lo;
    int c = threadIdx.x;
    float acc = 0.f;
    for (int i = start; i < end; ++i) acc += H[i * 128 + c];
    pooled[g * 128 + c] = acc / fmaxf((float)(end - start), 1.f);
}

// ---------------- classifier: pooled @ Wc + bc ----------------
__global__ void cls_kernel(const float* __restrict__ pooled, const float* __restrict__ Wc,
                           const float* __restrict__ bc, float* __restrict__ outp) {
    int g = blockIdx.x;
    __shared__ float p[128];
    p[threadIdx.x] = pooled[g * 128 + threadIdx.x];
    __syncthreads();
    if (threadIdx.x < 10) {
        float acc = bc[threadIdx.x];
        for (int k = 0; k < 128; ++k) acc += p[k] * Wc[k * 10 + threadIdx.x];
        outp[g * 10 + threadIdx.x] = acc;
    }
}

extern "C" void kernel_launch(void* const* d_in, const int* in_sizes, int n_in,
                              void* d_out, int out_size, void* d_ws, size_t ws_size,
                              hipStream_t stream) {
    const float* x     = (const float*)d_in[0];
    const int*   ei    = (const int*)d_in[1];
    const int*   batch = (const int*)d_in[2];
    const float* nc    = (const float*)d_in[3];
    const float* ec    = (const float*)d_in[4];
    const float* W0    = (const float*)d_in[5];
    const float* as0   = (const float*)d_in[6];
    const float* ad0   = (const float*)d_in[7];
    const float* b0    = (const float*)d_in[8];
    const float* W1    = (const float*)d_in[9];
    const float* as1   = (const float*)d_in[10];
    const float* ad1   = (const float*)d_in[11];
    const float* b1    = (const float*)d_in[12];
    const float* Wc    = (const float*)d_in[13];
    const float* bc    = (const float*)d_in[14];
    float* out = (float*)d_out;

    char* ws = (char*)d_ws;
    size_t off = 0;
    auto alloc = [&](size_t bytes) { void* p = ws + off; off += (bytes + 255) & ~size_t(255); return p; };
    float* h0       = (float*)alloc(sizeof(float) * N_NODES * 128);
    float* h1       = (float*)alloc(sizeof(float) * N_NODES * 128);
    float* als      = (float*)alloc(sizeof(float) * N_NODES * 2);
    float* ald      = (float*)alloc(sizeof(float) * N_NODES * 2);
    int*   deg      = (int*)alloc(sizeof(int) * N_NODES);
    int*   part     = (int*)alloc(sizeof(int) * NB_SCAN);
    int*   rowstart = (int*)alloc(sizeof(int) * (N_NODES + 1));
    int*   cursor   = (int*)alloc(sizeof(int) * N_NODES);
    int*   csr      = (int*)alloc(sizeof(int) * EA);
    float* pooled   = (float*)alloc(sizeof(float) * NG * 128);

    hipMemsetAsync(deg, 0, sizeof(int) * N_NODES, stream);
    hipMemsetAsync(cursor, 0, sizeof(int) * N_NODES, stream);

    hist_kernel<<<(EA + 255) / 256, 256, 0, stream>>>(ei, deg);
    partial_kernel<<<NB_SCAN, 256, 0, stream>>>(deg, part);
    scanpart_kernel<<<1, 256, 0, stream>>>(part, rowstart);
    rowstart_kernel<<<NB_SCAN, 256, 0, stream>>>(deg, part, rowstart);
    scatter_kernel<<<(EA + 255) / 256, 256, 0, stream>>>(ei, rowstart, cursor, csr);

    int gemm_grid   = (N_NODES + GR - 1) / GR;
    int nwaveblocks = (N_NODES * 64 + 255) / 256;

    // layer 0
    gemm_kernel<<<gemm_grid, 256, 0, stream>>>(x, W0, h0);
    alpha_kernel<<<nwaveblocks, 256, 0, stream>>>(h0, as0, ad0, als, ald);
    agg_kernel<<<nwaveblocks, 256, 0, stream>>>(h0, ei, ec, nc, als, ald, rowstart, csr, b0, h1);

    // layer 1
    gemm_kernel<<<gemm_grid, 256, 0, stream>>>(h1, W1, h0);
    alpha_kernel<<<nwaveblocks, 256, 0, stream>>>(h0, as1, ad1, als, ald);
    agg_kernel<<<nwaveblocks, 256, 0, stream>>>(h0, ei, ec, nc, als, ald, rowstart, csr, b1, h1);

    // pool + classifier
    pool_kernel<<<NG, 128, 0, stream>>>(h1, batch, pooled);
    cls_kernel<<<NG, 128, 0, stream>>>(pooled, Wc, bc, out);
}

// Round 3
// 502.477 us; speedup vs baseline: 1.6163x; 1.1549x over previous
//
#include <hip/hip_runtime.h>

#define N_NODES 50000
#define E_EDGES 800000
#define EA (E_EDGES + N_NODES)   // 850000 edges incl self loops
#define CH 128                   // HEADS*OUT
#define NG 128                   // num graphs
#define NEG 0.2f
#define GR 32                    // gemm rows per block
#define NB_SCAN ((N_NODES + 255) / 256)   // 196 scan blocks
#define PCHUNK 64                // pool rows per block

// ---------------- CSR build ----------------
__global__ void hist_kernel(const int* __restrict__ ei, int* __restrict__ deg) {
    int e = blockIdx.x * blockDim.x + threadIdx.x;
    if (e >= EA) return;
    int d = (e < E_EDGES) ? ei[E_EDGES + e] : (e - E_EDGES);
    atomicAdd(&deg[d], 1);
}

// two-level scan: per-block sums -> scan of partials -> per-block exclusive scan + offset
__global__ void partial_kernel(const int* __restrict__ deg, int* __restrict__ part) {
    __shared__ int buf[4];
    int i = blockIdx.x * 256 + threadIdx.x;
    int v = (i < N_NODES) ? deg[i] : 0;
    for (int o = 32; o; o >>= 1) v += __shfl_xor(v, o);
    if ((threadIdx.x & 63) == 0) buf[threadIdx.x >> 6] = v;
    __syncthreads();
    if (threadIdx.x == 0) part[blockIdx.x] = buf[0] + buf[1] + buf[2] + buf[3];
}

__global__ void scanpart_kernel(int* __restrict__ part, int* __restrict__ rowstart) {
    __shared__ int buf[256];
    int t = threadIdx.x;
    int v = (t < NB_SCAN) ? part[t] : 0;
    buf[t] = v;
    __syncthreads();
    for (int o = 1; o < 256; o <<= 1) {
        int u = (t >= o) ? buf[t - o] : 0;
        __syncthreads();
        buf[t] += u;
        __syncthreads();
    }
    if (t < NB_SCAN) part[t] = buf[t] - v;          // exclusive
    if (t == NB_SCAN - 1) rowstart[N_NODES] = buf[t]; // total (= EA)
}

__global__ void rowstart_kernel(const int* __restrict__ deg, const int* __restrict__ part,
                                int* __restrict__ rowstart) {
    __shared__ int buf[256];
    int i = blockIdx.x * 256 + threadIdx.x;
    int v = (i < N_NODES) ? deg[i] : 0;
    buf[threadIdx.x] = v;
    __syncthreads();
    for (int o = 1; o < 256; o <<= 1) {
        int u = (threadIdx.x >= o) ? buf[threadIdx.x - o] : 0;
        __syncthreads();
        buf[threadIdx.x] += u;
        __syncthreads();
    }
    if (i < N_NODES) rowstart[i] = part[blockIdx.x] + buf[threadIdx.x] - v;
}

__global__ void scatter_kernel(const int* __restrict__ ei, const int* __restrict__ rowstart,
                               int* __restrict__ cursor, int* __restrict__ csr) {
    int e = blockIdx.x * blockDim.x + threadIdx.x;
    if (e >= EA) return;
    int d = (e < E_EDGES) ? ei[E_EDGES + e] : (e - E_EDGES);
    int pos = rowstart[d] + atomicAdd(&cursor[d], 1);
    csr[pos] = e;
}

// ---------------- dense: H = X @ W  (N x 128) @ (128 x 128) ----------------
__global__ __launch_bounds__(256) void gemm_kernel(const float* __restrict__ X,
                                                   const float* __restrict__ W,
                                                   float* __restrict__ H) {
    __shared__ float Ws[128 * 64];
    __shared__ float Xs[GR][129];
    int row0 = blockIdx.x * GR;
    for (int i = threadIdx.x; i < GR * 128; i += 256) {
        int r = row0 + (i >> 7);
        Xs[i >> 7][i & 127] = (r < N_NODES) ? X[r * 128 + (i & 127)] : 0.f;
    }
    int c_in = threadIdx.x & 63;
    int rsub = threadIdx.x >> 6;
    for (int half = 0; half < 2; ++half) {
        __syncthreads();
        for (int i = threadIdx.x; i < 128 * 64; i += 256)
            Ws[i] = W[(i >> 6) * 128 + half * 64 + (i & 63)];
        __syncthreads();
        float acc[8] = {0, 0, 0, 0, 0, 0, 0, 0};
        for (int k = 0; k < 128; ++k) {
            float w = Ws[k * 64 + c_in];
#pragma unroll
            for (int i = 0; i < 8; ++i)
                acc[i] += Xs[rsub * 8 + i][k] * w;
        }
        int c = half * 64 + c_in;
#pragma unroll
        for (int i = 0; i < 8; ++i) {
            int r = row0 + rsub * 8 + i;
            if (r < N_NODES) H[r * 128 + c] = acc[i];
        }
    }
}

// ---------------- alpha_src / alpha_dst per node (one wave per node) ----------------
__global__ __launch_bounds__(256) void alpha_kernel(const float* __restrict__ H,
                                                    const float* __restrict__ as_,
                                                    const float* __restrict__ ad_,
                                                    float* __restrict__ als,
                                                    float* __restrict__ ald) {
    int n = blockIdx.x * (blockDim.x >> 6) + (threadIdx.x >> 6);
    if (n >= N_NODES) return;
    int lane = threadIdx.x & 63;
    float h0 = H[n * 128 + lane];
    float h1 = H[n * 128 + 64 + lane];
    float s0 = h0 * as_[lane], s1 = h1 * as_[64 + lane];
    float d0 = h0 * ad_[lane], d1 = h1 * ad_[64 + lane];
    for (int o = 32; o; o >>= 1) {
        s0 += __shfl_xor(s0, o); s1 += __shfl_xor(s1, o);
        d0 += __shfl_xor(d0, o); d1 += __shfl_xor(d1, o);
    }
    if (lane == 0) {
        als[n * 2] = s0; als[n * 2 + 1] = s1;
        ald[n * 2] = d0; ald[n * 2 + 1] = d1;
    }
}

// ---------------- per-node softmax + aggregation: lane-parallel edge resolve ----------------
__global__ __launch_bounds__(256) void agg_kernel(const float* __restrict__ H,
                                                  const int* __restrict__ ei,
                                                  const float* __restrict__ ec,
                                                  const float* __restrict__ nc,
                                                  const float* __restrict__ als,
                                                  const float* __restrict__ ald,
                                                  const int* __restrict__ rowstart,
                                                  const int* __restrict__ csr,
                                                  const float* __restrict__ bias,
                                                  float* __restrict__ Ho) {
    int n = blockIdx.x * (blockDim.x >> 6) + (threadIdx.x >> 6);
    if (n >= N_NODES) return;
    int lane = threadIdx.x & 63;
    int start = rowstart[n], end = rowstart[n + 1];
    int deg = end - start;
    float adv0 = ald[n * 2], adv1 = ald[n * 2 + 1];

    // chunk 0 (covers deg<=64, i.e. essentially every node): lane j owns edge j
    int   s_reg  = n;
    float nq_reg = 0.f, a0_reg = -1e30f, a1_reg = -1e30f;
    if (lane < deg) {
        int e = csr[start + lane];
        if (e < E_EDGES) { s_reg = ei[e]; nq_reg = ec[e]; }
        else             { s_reg = e - E_EDGES; nq_reg = nc[s_reg]; }
        float a0 = als[s_reg * 2]     + adv0; a0_reg = (a0 > 0.f) ? a0 : NEG * a0;
        float a1 = als[s_reg * 2 + 1] + adv1; a1_reg = (a1 > 0.f) ? a1 : NEG * a1;
    }
    float m0 = a0_reg, m1 = a1_reg;
    for (int i = start + 64 + lane; i < end; i += 64) {
        int e = csr[i];
        int s = (e < E_EDGES) ? ei[e] : (e - E_EDGES);
        float a0 = als[s * 2] + adv0;     a0 = (a0 > 0.f) ? a0 : NEG * a0;
        float a1 = als[s * 2 + 1] + adv1; a1 = (a1 > 0.f) ? a1 : NEG * a1;
        m0 = fmaxf(m0, a0); m1 = fmaxf(m1, a1);
    }
    for (int o = 32; o; o >>= 1) { m0 = fmaxf(m0, __shfl_xor(m0, o)); m1 = fmaxf(m1, __shfl_xor(m1, o)); }

    float e0_reg = __expf(a0_reg - m0), e1_reg = __expf(a1_reg - m1);
    float s0 = e0_reg, s1 = e1_reg;
    for (int i = start + 64 + lane; i < end; i += 64) {
        int e = csr[i];
        int s = (e < E_EDGES) ? ei[e] : (e - E_EDGES);
        float a0 = als[s * 2] + adv0;     a0 = (a0 > 0.f) ? a0 : NEG * a0;
        float a1 = als[s * 2 + 1] + adv1; a1 = (a1 > 0.f) ? a1 : NEG * a1;
        s0 += __expf(a0 - m0); s1 += __expf(a1 - m1);
    }
    for (int o = 32; o; o >>= 1) { s0 += __shfl_xor(s0, o); s1 += __shfl_xor(s1, o); }
    float inv0 = 1.f / (s0 + 1e-16f), inv1 = 1.f / (s1 + 1e-16f);

    float w0_reg = nq_reg * e0_reg * inv0;
    float w1_reg = nq_reg * e1_reg * inv1;

    float acc0 = 0.f, acc1 = 0.f;
    int cnt = (deg < 64) ? deg : 64;
#pragma unroll 4
    for (int j = 0; j < cnt; ++j) {
        int   s  = __shfl(s_reg, j);
        float w0 = __shfl(w0_reg, j);
        float w1 = __shfl(w1_reg, j);
        const float* hp = H + (size_t)s * 128;
        acc0 += w0 * hp[lane];
        acc1 += w1 * hp[64 + lane];
    }
    for (int i = start + 64; i < end; ++i) {
        int e = csr[i];
        int s; float nq;
        if (e < E_EDGES) { s = ei[e]; nq = ec[e]; }
        else             { s = e - E_EDGES; nq = nc[s]; }
        float a0 = als[s * 2] + adv0;     a0 = (a0 > 0.f) ? a0 : NEG * a0;
        float a1 = als[s * 2 + 1] + adv1; a1 = (a1 > 0.f) ? a1 : NEG * a1;
        float w0 = nq * __expf(a0 - m0) * inv0;
        float w1 = nq * __expf(a1 - m1) * inv1;
        acc0 += w0 * H[s * 128 + lane];
        acc1 += w1 * H[s * 128 + 64 + lane];
    }
    float o0 = acc0 + bias[lane];
    float o1 = acc1 + bias[64 + lane];
    Ho[n * 128 + lane]      = o0 > 0.f ? o0 : 0.f;
    Ho[n * 128 + 64 + lane] = o1 > 0.f ? o1 : 0.f;
}

// ---------------- global mean pool: chunked partial sums + atomics ----------------
__global__ __launch_bounds__(128) void pool_partial(const float* __restrict__ H,
                                                    const int* __restrict__ batch,
                                                    float* __restrict__ sums) {
    int row0 = blockIdx.x * PCHUNK;
    int c = threadIdx.x;               // 128 threads: one channel each
    int end = row0 + PCHUNK; if (end > N_NODES) end = N_NODES;
    float acc = 0.f;
    int curg = batch[row0];
    for (int i = row0; i < end; ++i) {
        int g = batch[i];              // sorted; uniform across the block
        if (g != curg) { atomicAdd(&sums[curg * 128 + c], acc); acc = 0.f; curg = g; }
        acc += H[(size_t)i * 128 + c];
    }
    atomicAdd(&sums[curg * 128 + c], acc);
}

// ---------------- classifier: (sums/cnt) @ Wc + bc ----------------
__global__ void cls_kernel(const float* __restrict__ sums, const int* __restrict__ batch,
                           const float* __restrict__ Wc, const float* __restrict__ bc,
                           float* __restrict__ outp) {
    int g = blockIdx.x;
    __shared__ float p[128];
    __shared__ int cnt_s;
    if (threadIdx.x == 0) {
        int lo = 0, hi = N_NODES;
        while (lo < hi) { int mid = (lo + hi) >> 1; if (batch[mid] < g) lo = mid + 1; else hi = mid; }
        int start = lo;
        hi = N_NODES;
        while (lo < hi) { int mid = (lo + hi) >> 1; if (batch[mid] <= g) lo = mid + 1; else hi = mid; }
        cnt_s = lo - start;
    }
    __syncthreads();
    float inv = 1.f / fmaxf((float)cnt_s, 1.f);
    p[threadIdx.x] = sums[g * 128 + threadIdx.x] * inv;
    __syncthreads();
    if (threadIdx.x < 10) {
        float acc = bc[threadIdx.x];
        for (int k = 0; k < 128; ++k) acc += p[k] * Wc[k * 10 + threadIdx.x];
        outp[g * 10 + threadIdx.x] = acc;
    }
}

extern "C" void kernel_launch(void* const* d_in, const int* in_sizes, int n_in,
                              void* d_out, int out_size, void* d_ws, size_t ws_size,
                              hipStream_t stream) {
    const float* x     = (const float*)d_in[0];
    const int*   ei    = (const int*)d_in[1];
    const int*   batch = (const int*)d_in[2];
    const float* nc    = (const float*)d_in[3];
    const float* ec    = (const float*)d_in[4];
    const float* W0    = (const float*)d_in[5];
    const float* as0   = (const float*)d_in[6];
    const float* ad0   = (const float*)d_in[7];
    const float* b0    = (const float*)d_in[8];
    const float* W1    = (const float*)d_in[9];
    const float* as1   = (const float*)d_in[10];
    const float* ad1   = (const float*)d_in[11];
    const float* b1    = (const float*)d_in[12];
    const float* Wc    = (const float*)d_in[13];
    const float* bc    = (const float*)d_in[14];
    float* out = (float*)d_out;

    char* ws = (char*)d_ws;
    size_t off = 0;
    auto alloc = [&](size_t bytes) { void* p = ws + off; off += (bytes + 255) & ~size_t(255); return p; };
    float* h0       = (float*)alloc(sizeof(float) * N_NODES * 128);
    float* h1       = (float*)alloc(sizeof(float) * N_NODES * 128);
    float* als      = (float*)alloc(sizeof(float) * N_NODES * 2);
    float* ald      = (float*)alloc(sizeof(float) * N_NODES * 2);
    int*   deg      = (int*)alloc(sizeof(int) * N_NODES);
    int*   part     = (int*)alloc(sizeof(int) * NB_SCAN);
    int*   rowstart = (int*)alloc(sizeof(int) * (N_NODES + 1));
    int*   cursor   = (int*)alloc(sizeof(int) * N_NODES);
    int*   csr      = (int*)alloc(sizeof(int) * EA);
    float* sums     = (float*)alloc(sizeof(float) * NG * 128);

    hipMemsetAsync(deg, 0, sizeof(int) * N_NODES, stream);
    hipMemsetAsync(cursor, 0, sizeof(int) * N_NODES, stream);
    hipMemsetAsync(sums, 0, sizeof(float) * NG * 128, stream);

    hist_kernel<<<(EA + 255) / 256, 256, 0, stream>>>(ei, deg);
    partial_kernel<<<NB_SCAN, 256, 0, stream>>>(deg, part);
    scanpart_kernel<<<1, 256, 0, stream>>>(part, rowstart);
    rowstart_kernel<<<NB_SCAN, 256, 0, stream>>>(deg, part, rowstart);
    scatter_kernel<<<(EA + 255) / 256, 256, 0, stream>>>(ei, rowstart, cursor, csr);

    int gemm_grid   = (N_NODES + GR - 1) / GR;
    int nwaveblocks = (N_NODES * 64 + 255) / 256;

    // layer 0
    gemm_kernel<<<gemm_grid, 256, 0, stream>>>(x, W0, h0);
    alpha_kernel<<<nwaveblocks, 256, 0, stream>>>(h0, as0, ad0, als, ald);
    agg_kernel<<<nwaveblocks, 256, 0, stream>>>(h0, ei, ec, nc, als, ald, rowstart, csr, b0, h1);

    // layer 1
    gemm_kernel<<<gemm_grid, 256, 0, stream>>>(h1, W1, h0);
    alpha_kernel<<<nwaveblocks, 256, 0, stream>>>(h0, as1, ad1, als, ald);
    agg_kernel<<<nwaveblocks, 256, 0, stream>>>(h0, ei, ec, nc, als, ald, rowstart, csr, b1, h1);

    // pool + classifier
    pool_partial<<<(N_NODES + PCHUNK - 1) / PCHUNK, 128, 0, stream>>>(h1, batch, sums);
    cls_kernel<<<NG, 128, 0, stream>>>(sums, batch, Wc, bc, out);
}

// Round 4
// 389.709 us; speedup vs baseline: 2.0840x; 1.2894x over previous
//
#include <hip/hip_runtime.h>

#define N_NODES 50000
#define E_EDGES 800000
#define EA (E_EDGES + N_NODES)   // 850000 edges incl self loops
#define CH 128                   // HEADS*OUT
#define NG 128                   // num graphs
#define NEG 0.2f
#define NB_SCAN ((N_NODES + 255) / 256)   // 196 scan blocks
#define PCHUNK 64                // pool rows per block
#define GROWS 64                 // gemm rows per block

// ---------------- CSR build ----------------
__global__ void hist_kernel(const int* __restrict__ ei, int* __restrict__ deg) {
    int e = blockIdx.x * blockDim.x + threadIdx.x;
    if (e >= EA) return;
    int d = (e < E_EDGES) ? ei[E_EDGES + e] : (e - E_EDGES);
    atomicAdd(&deg[d], 1);
}

__global__ void partial_kernel(const int* __restrict__ deg, int* __restrict__ part) {
    __shared__ int buf[4];
    int i = blockIdx.x * 256 + threadIdx.x;
    int v = (i < N_NODES) ? deg[i] : 0;
    for (int o = 32; o; o >>= 1) v += __shfl_xor(v, o);
    if ((threadIdx.x & 63) == 0) buf[threadIdx.x >> 6] = v;
    __syncthreads();
    if (threadIdx.x == 0) part[blockIdx.x] = buf[0] + buf[1] + buf[2] + buf[3];
}

__global__ void scanpart_kernel(int* __restrict__ part, int* __restrict__ rowstart) {
    __shared__ int buf[256];
    int t = threadIdx.x;
    int v = (t < NB_SCAN) ? part[t] : 0;
    buf[t] = v;
    __syncthreads();
    for (int o = 1; o < 256; o <<= 1) {
        int u = (t >= o) ? buf[t - o] : 0;
        __syncthreads();
        buf[t] += u;
        __syncthreads();
    }
    if (t < NB_SCAN) part[t] = buf[t] - v;
    if (t == NB_SCAN - 1) rowstart[N_NODES] = buf[t];
}

__global__ void rowstart_kernel(const int* __restrict__ deg, const int* __restrict__ part,
                                int* __restrict__ rowstart) {
    __shared__ int buf[256];
    int i = blockIdx.x * 256 + threadIdx.x;
    int v = (i < N_NODES) ? deg[i] : 0;
    buf[threadIdx.x] = v;
    __syncthreads();
    for (int o = 1; o < 256; o <<= 1) {
        int u = (threadIdx.x >= o) ? buf[threadIdx.x - o] : 0;
        __syncthreads();
        buf[threadIdx.x] += u;
        __syncthreads();
    }
    if (i < N_NODES) rowstart[i] = part[blockIdx.x] + buf[threadIdx.x] - v;
}

__global__ void scatter_kernel(const int* __restrict__ ei, const int* __restrict__ rowstart,
                               int* __restrict__ cursor, int* __restrict__ csr) {
    int e = blockIdx.x * blockDim.x + threadIdx.x;
    if (e >= EA) return;
    int d = (e < E_EDGES) ? ei[E_EDGES + e] : (e - E_EDGES);
    int pos = rowstart[d] + atomicAdd(&cursor[d], 1);
    csr[pos] = e;
}

// ---------------- fused GEMM + alpha: H = X@W; als/ald = (H.as, H.ad) ----------------
// block: 256 threads, tile 64 rows x 128 cols; per-thread 4 rows x 8 cols.
__global__ __launch_bounds__(256, 2) void gemm_alpha(const float* __restrict__ X,
                                                     const float* __restrict__ W,
                                                     const float* __restrict__ as_,
                                                     const float* __restrict__ ad_,
                                                     float* __restrict__ H,
                                                     float* __restrict__ als,
                                                     float* __restrict__ ald) {
    __shared__ float Ws[32][128];    // 16 KB, restaged 4x
    __shared__ float Xs[GROWS][132]; // 33 KB, pad 132 keeps 16B alignment + kills bank conflicts
    const int tid = threadIdx.x;
    const int row0 = blockIdx.x * GROWS;

    // stage X tile (coalesced float4 reads, conflict-free b128 LDS writes)
    for (int i = 0; i < 8; ++i) {
        int idx = tid + i * 256;          // 0..2047
        int r = idx >> 5, fq = idx & 31;
        int gr = row0 + r;
        float4 v = make_float4(0.f, 0.f, 0.f, 0.f);
        if (gr < N_NODES) v = ((const float4*)X)[(size_t)gr * 32 + fq];
        *(float4*)&Xs[r][fq * 4] = v;
    }

    const int ct = tid & 15, rt = tid >> 4;
    const int c0 = ct * 8, r0 = rt * 4;
    float acc[4][8];
#pragma unroll
    for (int i = 0; i < 4; ++i)
#pragma unroll
        for (int j = 0; j < 8; ++j) acc[i][j] = 0.f;

    for (int chunk = 0; chunk < 4; ++chunk) {
        __syncthreads();
        for (int i = 0; i < 4; ++i) {
            int idx = tid + i * 256;      // 0..1023 float4s = 32x128 floats
            int kr = idx >> 5, fq = idx & 31;
            *(float4*)&Ws[kr][fq * 4] = ((const float4*)W)[(size_t)(chunk * 32 + kr) * 32 + fq];
        }
        __syncthreads();
#pragma unroll 8
        for (int kk = 0; kk < 32; ++kk) {
            int k = chunk * 32 + kk;
            float x0 = Xs[r0 + 0][k], x1 = Xs[r0 + 1][k];
            float x2 = Xs[r0 + 2][k], x3 = Xs[r0 + 3][k];
            float4 wa = *(float4*)&Ws[kk][c0];
            float4 wb = *(float4*)&Ws[kk][c0 + 4];
            float w[8] = {wa.x, wa.y, wa.z, wa.w, wb.x, wb.y, wb.z, wb.w};
#pragma unroll
            for (int j = 0; j < 8; ++j) {
                acc[0][j] += x0 * w[j];
                acc[1][j] += x1 * w[j];
                acc[2][j] += x2 * w[j];
                acc[3][j] += x3 * w[j];
            }
        }
    }

    // epilogue: store H + fused alpha dot products
    float asv[8], adv[8];
#pragma unroll
    for (int j = 0; j < 8; ++j) { asv[j] = as_[c0 + j]; adv[j] = ad_[c0 + j]; }
    int head = (tid >> 3) & 1;   // colthreads 0-7 -> head 0, 8-15 -> head 1

#pragma unroll
    for (int i = 0; i < 4; ++i) {
        int r = row0 + r0 + i;
        if (r < N_NODES) {
            float4 va = make_float4(acc[i][0], acc[i][1], acc[i][2], acc[i][3]);
            float4 vb = make_float4(acc[i][4], acc[i][5], acc[i][6], acc[i][7]);
            *(float4*)&H[(size_t)r * 128 + c0] = va;
            *(float4*)&H[(size_t)r * 128 + c0 + 4] = vb;
        }
        float ss = 0.f, dd = 0.f;
#pragma unroll
        for (int j = 0; j < 8; ++j) { ss += acc[i][j] * asv[j]; dd += acc[i][j] * adv[j]; }
        // reduce across the 8 colthreads of this head (all lanes execute)
        ss += __shfl_xor(ss, 1); dd += __shfl_xor(dd, 1);
        ss += __shfl_xor(ss, 2); dd += __shfl_xor(dd, 2);
        ss += __shfl_xor(ss, 4); dd += __shfl_xor(dd, 4);
        if (r < N_NODES && (tid & 7) == 0) {
            als[r * 2 + head] = ss;
            ald[r * 2 + head] = dd;
        }
    }
}

// ---------------- per-node softmax + aggregation: lane-parallel edge resolve ----------------
__global__ __launch_bounds__(256) void agg_kernel(const float* __restrict__ H,
                                                  const int* __restrict__ ei,
                                                  const float* __restrict__ ec,
                                                  const float* __restrict__ nc,
                                                  const float* __restrict__ als,
                                                  const float* __restrict__ ald,
                                                  const int* __restrict__ rowstart,
                                                  const int* __restrict__ csr,
                                                  const float* __restrict__ bias,
                                                  float* __restrict__ Ho) {
    int n = blockIdx.x * (blockDim.x >> 6) + (threadIdx.x >> 6);
    if (n >= N_NODES) return;
    int lane = threadIdx.x & 63;
    int start = rowstart[n], end = rowstart[n + 1];
    int deg = end - start;
    float adv0 = ald[n * 2], adv1 = ald[n * 2 + 1];

    int   s_reg  = n;
    float nq_reg = 0.f, a0_reg = -1e30f, a1_reg = -1e30f;
    if (lane < deg) {
        int e = csr[start + lane];
        if (e < E_EDGES) { s_reg = ei[e]; nq_reg = ec[e]; }
        else             { s_reg = e - E_EDGES; nq_reg = nc[s_reg]; }
        float a0 = als[s_reg * 2]     + adv0; a0_reg = (a0 > 0.f) ? a0 : NEG * a0;
        float a1 = als[s_reg * 2 + 1] + adv1; a1_reg = (a1 > 0.f) ? a1 : NEG * a1;
    }
    float m0 = a0_reg, m1 = a1_reg;
    for (int i = start + 64 + lane; i < end; i += 64) {
        int e = csr[i];
        int s = (e < E_EDGES) ? ei[e] : (e - E_EDGES);
        float a0 = als[s * 2] + adv0;     a0 = (a0 > 0.f) ? a0 : NEG * a0;
        float a1 = als[s * 2 + 1] + adv1; a1 = (a1 > 0.f) ? a1 : NEG * a1;
        m0 = fmaxf(m0, a0); m1 = fmaxf(m1, a1);
    }
    for (int o = 32; o; o >>= 1) { m0 = fmaxf(m0, __shfl_xor(m0, o)); m1 = fmaxf(m1, __shfl_xor(m1, o)); }

    float e0_reg = __expf(a0_reg - m0), e1_reg = __expf(a1_reg - m1);
    float s0 = e0_reg, s1 = e1_reg;
    for (int i = start + 64 + lane; i < end; i += 64) {
        int e = csr[i];
        int s = (e < E_EDGES) ? ei[e] : (e - E_EDGES);
        float a0 = als[s * 2] + adv0;     a0 = (a0 > 0.f) ? a0 : NEG * a0;
        float a1 = als[s * 2 + 1] + adv1; a1 = (a1 > 0.f) ? a1 : NEG * a1;
        s0 += __expf(a0 - m0); s1 += __expf(a1 - m1);
    }
    for (int o = 32; o; o >>= 1) { s0 += __shfl_xor(s0, o); s1 += __shfl_xor(s1, o); }
    float inv0 = 1.f / (s0 + 1e-16f), inv1 = 1.f / (s1 + 1e-16f);

    float w0_reg = nq_reg * e0_reg * inv0;
    float w1_reg = nq_reg * e1_reg * inv1;

    float acc0 = 0.f, acc1 = 0.f;
    int cnt = (deg < 64) ? deg : 64;
#pragma unroll 4
    for (int j = 0; j < cnt; ++j) {
        int   s  = __shfl(s_reg, j);
        float w0 = __shfl(w0_reg, j);
        float w1 = __shfl(w1_reg, j);
        const float* hp = H + (size_t)s * 128;
        acc0 += w0 * hp[lane];
        acc1 += w1 * hp[64 + lane];
    }
    for (int i = start + 64; i < end; ++i) {
        int e = csr[i];
        int s; float nq;
        if (e < E_EDGES) { s = ei[e]; nq = ec[e]; }
        else             { s = e - E_EDGES; nq = nc[s]; }
        float a0 = als[s * 2] + adv0;     a0 = (a0 > 0.f) ? a0 : NEG * a0;
        float a1 = als[s * 2 + 1] + adv1; a1 = (a1 > 0.f) ? a1 : NEG * a1;
        float w0 = nq * __expf(a0 - m0) * inv0;
        float w1 = nq * __expf(a1 - m1) * inv1;
        acc0 += w0 * H[s * 128 + lane];
        acc1 += w1 * H[s * 128 + 64 + lane];
    }
    float o0 = acc0 + bias[lane];
    float o1 = acc1 + bias[64 + lane];
    Ho[n * 128 + lane]      = o0 > 0.f ? o0 : 0.f;
    Ho[n * 128 + 64 + lane] = o1 > 0.f ? o1 : 0.f;
}

// ---------------- global mean pool: chunked partial sums + atomics ----------------
__global__ __launch_bounds__(128) void pool_partial(const float* __restrict__ H,
                                                    const int* __restrict__ batch,
                                                    float* __restrict__ sums) {
    int row0 = blockIdx.x * PCHUNK;
    int c = threadIdx.x;
    int end = row0 + PCHUNK; if (end > N_NODES) end = N_NODES;
    float acc = 0.f;
    int curg = batch[row0];
    for (int i = row0; i < end; ++i) {
        int g = batch[i];
        if (g != curg) { atomicAdd(&sums[curg * 128 + c], acc); acc = 0.f; curg = g; }
        acc += H[(size_t)i * 128 + c];
    }
    atomicAdd(&sums[curg * 128 + c], acc);
}

// ---------------- classifier: (sums/cnt) @ Wc + bc ----------------
__global__ void cls_kernel(const float* __restrict__ sums, const int* __restrict__ batch,
                           const float* __restrict__ Wc, const float* __restrict__ bc,
                           float* __restrict__ outp) {
    int g = blockIdx.x;
    __shared__ float p[128];
    __shared__ int cnt_s;
    if (threadIdx.x == 0) {
        int lo = 0, hi = N_NODES;
        while (lo < hi) { int mid = (lo + hi) >> 1; if (batch[mid] < g) lo = mid + 1; else hi = mid; }
        int start = lo;
        hi = N_NODES;
        while (lo < hi) { int mid = (lo + hi) >> 1; if (batch[mid] <= g) lo = mid + 1; else hi = mid; }
        cnt_s = lo - start;
    }
    __syncthreads();
    float inv = 1.f / fmaxf((float)cnt_s, 1.f);
    p[threadIdx.x] = sums[g * 128 + threadIdx.x] * inv;
    __syncthreads();
    if (threadIdx.x < 10) {
        float acc = bc[threadIdx.x];
        for (int k = 0; k < 128; ++k) acc += p[k] * Wc[k * 10 + threadIdx.x];
        outp[g * 10 + threadIdx.x] = acc;
    }
}

extern "C" void kernel_launch(void* const* d_in, const int* in_sizes, int n_in,
                              void* d_out, int out_size, void* d_ws, size_t ws_size,
                              hipStream_t stream) {
    const float* x     = (const float*)d_in[0];
    const int*   ei    = (const int*)d_in[1];
    const int*   batch = (const int*)d_in[2];
    const float* nc    = (const float*)d_in[3];
    const float* ec    = (const float*)d_in[4];
    const float* W0    = (const float*)d_in[5];
    const float* as0   = (const float*)d_in[6];
    const float* ad0   = (const float*)d_in[7];
    const float* b0    = (const float*)d_in[8];
    const float* W1    = (const float*)d_in[9];
    const float* as1   = (const float*)d_in[10];
    const float* ad1   = (const float*)d_in[11];
    const float* b1    = (const float*)d_in[12];
    const float* Wc    = (const float*)d_in[13];
    const float* bc    = (const float*)d_in[14];
    float* out = (float*)d_out;

    char* ws = (char*)d_ws;
    size_t off = 0;
    auto alloc = [&](size_t bytes) { void* p = ws + off; off += (bytes + 255) & ~size_t(255); return p; };
    float* h0       = (float*)alloc(sizeof(float) * N_NODES * 128);
    float* h1       = (float*)alloc(sizeof(float) * N_NODES * 128);
    float* als      = (float*)alloc(sizeof(float) * N_NODES * 2);
    float* ald      = (float*)alloc(sizeof(float) * N_NODES * 2);
    int*   deg      = (int*)alloc(sizeof(int) * N_NODES);
    int*   part     = (int*)alloc(sizeof(int) * NB_SCAN);
    int*   rowstart = (int*)alloc(sizeof(int) * (N_NODES + 1));
    int*   cursor   = (int*)alloc(sizeof(int) * N_NODES);
    int*   csr      = (int*)alloc(sizeof(int) * EA);
    float* sums     = (float*)alloc(sizeof(float) * NG * 128);

    hipMemsetAsync(deg, 0, sizeof(int) * N_NODES, stream);
    hipMemsetAsync(cursor, 0, sizeof(int) * N_NODES, stream);
    hipMemsetAsync(sums, 0, sizeof(float) * NG * 128, stream);

    hist_kernel<<<(EA + 255) / 256, 256, 0, stream>>>(ei, deg);
    partial_kernel<<<NB_SCAN, 256, 0, stream>>>(deg, part);
    scanpart_kernel<<<1, 256, 0, stream>>>(part, rowstart);
    rowstart_kernel<<<NB_SCAN, 256, 0, stream>>>(deg, part, rowstart);
    scatter_kernel<<<(EA + 255) / 256, 256, 0, stream>>>(ei, rowstart, cursor, csr);

    int gemm_grid   = (N_NODES + GROWS - 1) / GROWS;   // 782
    int nwaveblocks = (N_NODES * 64 + 255) / 256;

    // layer 0
    gemm_alpha<<<gemm_grid, 256, 0, stream>>>(x, W0, as0, ad0, h0, als, ald);
    agg_kernel<<<nwaveblocks, 256, 0, stream>>>(h0, ei, ec, nc, als, ald, rowstart, csr, b0, h1);

    // layer 1
    gemm_alpha<<<gemm_grid, 256, 0, stream>>>(h1, W1, as1, ad1, h0, als, ald);
    agg_kernel<<<nwaveblocks, 256, 0, stream>>>(h0, ei, ec, nc, als, ald, rowstart, csr, b1, h1);

    // pool + classifier
    pool_partial<<<(N_NODES + PCHUNK - 1) / PCHUNK, 128, 0, stream>>>(h1, batch, sums);
    cls_kernel<<<NG, 128, 0, stream>>>(sums, batch, Wc, bc, out);
}

// Round 5
// 352.199 us; speedup vs baseline: 2.3059x; 1.1065x over previous
//
#include <hip/hip_runtime.h>

#define N_NODES 50000
#define E_EDGES 800000
#define EA (E_EDGES + N_NODES)   // 850000 edges incl self loops
#define CH 128                   // HEADS*OUT
#define NG 128                   // num graphs
#define NEG 0.2f
#define NB_SCAN ((N_NODES + 255) / 256)   // 196 scan blocks
#define PCHUNK 64                // pool rows per block
#define GROWS 64                 // gemm rows per block

// bf16 helpers (RNE pack, exact unpack)
__device__ __forceinline__ unsigned bf16_rne(float x) {
    unsigned u = __float_as_uint(x);
    return (u + 0x7fffu + ((u >> 16) & 1u)) >> 16;
}
__device__ __forceinline__ unsigned packbf2(float a, float b) {
    return bf16_rne(a) | (bf16_rne(b) << 16);
}
__device__ __forceinline__ float bfu_lo(unsigned v) { return __uint_as_float(v << 16); }
__device__ __forceinline__ float bfu_hi(unsigned v) { return __uint_as_float(v & 0xffff0000u); }

// ---------------- CSR build ----------------
__global__ void hist_kernel(const int* __restrict__ ei, int* __restrict__ deg) {
    int e = blockIdx.x * blockDim.x + threadIdx.x;
    if (e >= EA) return;
    int d = (e < E_EDGES) ? ei[E_EDGES + e] : (e - E_EDGES);
    atomicAdd(&deg[d], 1);
}

__global__ void partial_kernel(const int* __restrict__ deg, int* __restrict__ part) {
    __shared__ int buf[4];
    int i = blockIdx.x * 256 + threadIdx.x;
    int v = (i < N_NODES) ? deg[i] : 0;
    for (int o = 32; o; o >>= 1) v += __shfl_xor(v, o);
    if ((threadIdx.x & 63) == 0) buf[threadIdx.x >> 6] = v;
    __syncthreads();
    if (threadIdx.x == 0) part[blockIdx.x] = buf[0] + buf[1] + buf[2] + buf[3];
}

__global__ void scanpart_kernel(int* __restrict__ part, int* __restrict__ rowstart) {
    __shared__ int buf[256];
    int t = threadIdx.x;
    int v = (t < NB_SCAN) ? part[t] : 0;
    buf[t] = v;
    __syncthreads();
    for (int o = 1; o < 256; o <<= 1) {
        int u = (t >= o) ? buf[t - o] : 0;
        __syncthreads();
        buf[t] += u;
        __syncthreads();
    }
    if (t < NB_SCAN) part[t] = buf[t] - v;
    if (t == NB_SCAN - 1) rowstart[N_NODES] = buf[t];
}

__global__ void rowstart_kernel(const int* __restrict__ deg, const int* __restrict__ part,
                                int* __restrict__ rowstart) {
    __shared__ int buf[256];
    int i = blockIdx.x * 256 + threadIdx.x;
    int v = (i < N_NODES) ? deg[i] : 0;
    buf[threadIdx.x] = v;
    __syncthreads();
    for (int o = 1; o < 256; o <<= 1) {
        int u = (threadIdx.x >= o) ? buf[threadIdx.x - o] : 0;
        __syncthreads();
        buf[threadIdx.x] += u;
        __syncthreads();
    }
    if (i < N_NODES) rowstart[i] = part[blockIdx.x] + buf[threadIdx.x] - v;
}

__global__ void scatter_kernel(const int* __restrict__ ei, const int* __restrict__ rowstart,
                               int* __restrict__ cursor, int* __restrict__ csr) {
    int e = blockIdx.x * blockDim.x + threadIdx.x;
    if (e >= EA) return;
    int d = (e < E_EDGES) ? ei[E_EDGES + e] : (e - E_EDGES);
    int pos = rowstart[d] + atomicAdd(&cursor[d], 1);
    csr[pos] = e;
}

// ---------------- fused GEMM + alpha: Hb(bf16) = X@W; als/ald = (H.as, H.ad) ----------------
// block: 256 threads, tile 64 rows x 128 cols; per-thread 4 rows x 8 cols.
__global__ __launch_bounds__(256, 2) void gemm_alpha(const float* __restrict__ X,
                                                     const float* __restrict__ W,
                                                     const float* __restrict__ as_,
                                                     const float* __restrict__ ad_,
                                                     unsigned* __restrict__ Hb,
                                                     float* __restrict__ als,
                                                     float* __restrict__ ald) {
    __shared__ float Ws[32][128];    // 16 KB, restaged 4x
    __shared__ float Xs[GROWS][132]; // 33 KB
    const int tid = threadIdx.x;
    const int row0 = blockIdx.x * GROWS;

    for (int i = 0; i < 8; ++i) {
        int idx = tid + i * 256;
        int r = idx >> 5, fq = idx & 31;
        int gr = row0 + r;
        float4 v = make_float4(0.f, 0.f, 0.f, 0.f);
        if (gr < N_NODES) v = ((const float4*)X)[(size_t)gr * 32 + fq];
        *(float4*)&Xs[r][fq * 4] = v;
    }

    const int ct = tid & 15, rt = tid >> 4;
    const int c0 = ct * 8, r0 = rt * 4;
    float acc[4][8];
#pragma unroll
    for (int i = 0; i < 4; ++i)
#pragma unroll
        for (int j = 0; j < 8; ++j) acc[i][j] = 0.f;

    for (int chunk = 0; chunk < 4; ++chunk) {
        __syncthreads();
        for (int i = 0; i < 4; ++i) {
            int idx = tid + i * 256;
            int kr = idx >> 5, fq = idx & 31;
            *(float4*)&Ws[kr][fq * 4] = ((const float4*)W)[(size_t)(chunk * 32 + kr) * 32 + fq];
        }
        __syncthreads();
#pragma unroll 8
        for (int kk = 0; kk < 32; ++kk) {
            int k = chunk * 32 + kk;
            float x0 = Xs[r0 + 0][k], x1 = Xs[r0 + 1][k];
            float x2 = Xs[r0 + 2][k], x3 = Xs[r0 + 3][k];
            float4 wa = *(float4*)&Ws[kk][c0];
            float4 wb = *(float4*)&Ws[kk][c0 + 4];
            float w[8] = {wa.x, wa.y, wa.z, wa.w, wb.x, wb.y, wb.z, wb.w};
#pragma unroll
            for (int j = 0; j < 8; ++j) {
                acc[0][j] += x0 * w[j];
                acc[1][j] += x1 * w[j];
                acc[2][j] += x2 * w[j];
                acc[3][j] += x3 * w[j];
            }
        }
    }

    float asv[8], adv[8];
#pragma unroll
    for (int j = 0; j < 8; ++j) { asv[j] = as_[c0 + j]; adv[j] = ad_[c0 + j]; }
    int head = (tid >> 3) & 1;

#pragma unroll
    for (int i = 0; i < 4; ++i) {
        int r = row0 + r0 + i;
        if (r < N_NODES) {
            uint4 pk;
            pk.x = packbf2(acc[i][0], acc[i][1]);
            pk.y = packbf2(acc[i][2], acc[i][3]);
            pk.z = packbf2(acc[i][4], acc[i][5]);
            pk.w = packbf2(acc[i][6], acc[i][7]);
            *(uint4*)&Hb[(size_t)r * 64 + ct * 4] = pk;
        }
        float ss = 0.f, dd = 0.f;
#pragma unroll
        for (int j = 0; j < 8; ++j) { ss += acc[i][j] * asv[j]; dd += acc[i][j] * adv[j]; }
        ss += __shfl_xor(ss, 1); dd += __shfl_xor(dd, 1);
        ss += __shfl_xor(ss, 2); dd += __shfl_xor(dd, 2);
        ss += __shfl_xor(ss, 4); dd += __shfl_xor(dd, 4);
        if (r < N_NODES && (tid & 7) == 0) {
            als[r * 2 + head] = ss;
            ald[r * 2 + head] = dd;
        }
    }
}

// ---------------- per-node softmax + aggregation (bf16 gather) ----------------
__global__ __launch_bounds__(256) void agg_kernel(const unsigned* __restrict__ Hb,
                                                  const int* __restrict__ ei,
                                                  const float* __restrict__ ec,
                                                  const float* __restrict__ nc,
                                                  const float* __restrict__ als,
                                                  const float* __restrict__ ald,
                                                  const int* __restrict__ rowstart,
                                                  const int* __restrict__ csr,
                                                  const float* __restrict__ bias,
                                                  float* __restrict__ Ho) {
    int n = blockIdx.x * (blockDim.x >> 6) + (threadIdx.x >> 6);
    if (n >= N_NODES) return;
    int lane = threadIdx.x & 63;
    int start = rowstart[n], end = rowstart[n + 1];
    int deg = end - start;
    const float2* als2 = (const float2*)als;
    float2 adn = ((const float2*)ald)[n];

    // lane j owns edge j (covers deg<=64, i.e. essentially every node)
    int   s_reg  = n;
    float nq_reg = 0.f, a0_reg = -1e30f, a1_reg = -1e30f;
    if (lane < deg) {
        int e = csr[start + lane];
        if (e < E_EDGES) { s_reg = ei[e]; nq_reg = ec[e]; }
        else             { s_reg = e - E_EDGES; nq_reg = nc[s_reg]; }
        float2 av = als2[s_reg];
        float a0 = av.x + adn.x; a0_reg = (a0 > 0.f) ? a0 : NEG * a0;
        float a1 = av.y + adn.y; a1_reg = (a1 > 0.f) ? a1 : NEG * a1;
    }
    float m0 = a0_reg, m1 = a1_reg;
    for (int i = start + 64 + lane; i < end; i += 64) {
        int e = csr[i];
        int s = (e < E_EDGES) ? ei[e] : (e - E_EDGES);
        float2 av = als2[s];
        float a0 = av.x + adn.x; a0 = (a0 > 0.f) ? a0 : NEG * a0;
        float a1 = av.y + adn.y; a1 = (a1 > 0.f) ? a1 : NEG * a1;
        m0 = fmaxf(m0, a0); m1 = fmaxf(m1, a1);
    }
    for (int o = 32; o; o >>= 1) { m0 = fmaxf(m0, __shfl_xor(m0, o)); m1 = fmaxf(m1, __shfl_xor(m1, o)); }

    float e0_reg = __expf(a0_reg - m0), e1_reg = __expf(a1_reg - m1);
    float s0 = e0_reg, s1 = e1_reg;
    for (int i = start + 64 + lane; i < end; i += 64) {
        int e = csr[i];
        int s = (e < E_EDGES) ? ei[e] : (e - E_EDGES);
        float2 av = als2[s];
        float a0 = av.x + adn.x; a0 = (a0 > 0.f) ? a0 : NEG * a0;
        float a1 = av.y + adn.y; a1 = (a1 > 0.f) ? a1 : NEG * a1;
        s0 += __expf(a0 - m0); s1 += __expf(a1 - m1);
    }
    for (int o = 32; o; o >>= 1) { s0 += __shfl_xor(s0, o); s1 += __shfl_xor(s1, o); }
    float inv0 = 1.f / (s0 + 1e-16f), inv1 = 1.f / (s1 + 1e-16f);

    // per-lane final weights, packed bf16x2 for a single shfl broadcast
    unsigned wpack_reg = packbf2(nq_reg * e0_reg * inv0, nq_reg * e1_reg * inv1);

    // gather: lane owns channels 2*lane and 2*lane+1 (one 4B uint = whole 256B row per wave)
    const bool h0sel = (lane < 32);   // channels 0..63 -> head 0
    float acc0 = 0.f, acc1 = 0.f;
    int cnt = (deg < 64) ? deg : 64;
#pragma unroll 8
    for (int j = 0; j < cnt; ++j) {
        int      s  = __shfl(s_reg, j);
        unsigned wp = __shfl(wpack_reg, j);
        unsigned wb = h0sel ? (wp << 16) : (wp & 0xffff0000u);
        float    w  = __uint_as_float(wb);
        unsigned hv = Hb[(size_t)s * 64 + lane];
        acc0 += w * bfu_lo(hv);
        acc1 += w * bfu_hi(hv);
    }
    // rare fallback deg>64
    for (int i = start + 64; i < end; ++i) {
        int e = csr[i];
        int s; float nq;
        if (e < E_EDGES) { s = ei[e]; nq = ec[e]; }
        else             { s = e - E_EDGES; nq = nc[s]; }
        float2 av = als2[s];
        float a0 = av.x + adn.x; a0 = (a0 > 0.f) ? a0 : NEG * a0;
        float a1 = av.y + adn.y; a1 = (a1 > 0.f) ? a1 : NEG * a1;
        float w0 = nq * __expf(a0 - m0) * inv0;
        float w1 = nq * __expf(a1 - m1) * inv1;
        float w  = h0sel ? w0 : w1;
        unsigned hv = Hb[(size_t)s * 64 + lane];
        acc0 += w * bfu_lo(hv);
        acc1 += w * bfu_hi(hv);
    }
    float2 bb = ((const float2*)bias)[lane];
    float o0 = acc0 + bb.x;
    float o1 = acc1 + bb.y;
    float2 ov;
    ov.x = o0 > 0.f ? o0 : 0.f;
    ov.y = o1 > 0.f ? o1 : 0.f;
    ((float2*)(Ho + (size_t)n * 128))[lane] = ov;
}

// ---------------- global mean pool: chunked partial sums + atomics ----------------
__global__ __launch_bounds__(128) void pool_partial(const float* __restrict__ H,
                                                    const int* __restrict__ batch,
                                                    float* __restrict__ sums) {
    int row0 = blockIdx.x * PCHUNK;
    int c = threadIdx.x;
    int end = row0 + PCHUNK; if (end > N_NODES) end = N_NODES;
    float acc = 0.f;
    int curg = batch[row0];
    for (int i = row0; i < end; ++i) {
        int g = batch[i];
        if (g != curg) { atomicAdd(&sums[curg * 128 + c], acc); acc = 0.f; curg = g; }
        acc += H[(size_t)i * 128 + c];
    }
    atomicAdd(&sums[curg * 128 + c], acc);
}

// ---------------- classifier: (sums/cnt) @ Wc + bc ----------------
__global__ void cls_kernel(const float* __restrict__ sums, const int* __restrict__ batch,
                           const float* __restrict__ Wc, const float* __restrict__ bc,
                           float* __restrict__ outp) {
    int g = blockIdx.x;
    __shared__ float p[128];
    __shared__ int cnt_s;
    if (threadIdx.x == 0) {
        int lo = 0, hi = N_NODES;
        while (lo < hi) { int mid = (lo + hi) >> 1; if (batch[mid] < g) lo = mid + 1; else hi = mid; }
        int start = lo;
        hi = N_NODES;
        while (lo < hi) { int mid = (lo + hi) >> 1; if (batch[mid] <= g) lo = mid + 1; else hi = mid; }
        cnt_s = lo - start;
    }
    __syncthreads();
    float inv = 1.f / fmaxf((float)cnt_s, 1.f);
    p[threadIdx.x] = sums[g * 128 + threadIdx.x] * inv;
    __syncthreads();
    if (threadIdx.x < 10) {
        float acc = bc[threadIdx.x];
        for (int k = 0; k < 128; ++k) acc += p[k] * Wc[k * 10 + threadIdx.x];
        outp[g * 10 + threadIdx.x] = acc;
    }
}

extern "C" void kernel_launch(void* const* d_in, const int* in_sizes, int n_in,
                              void* d_out, int out_size, void* d_ws, size_t ws_size,
                              hipStream_t stream) {
    const float* x     = (const float*)d_in[0];
    const int*   ei    = (const int*)d_in[1];
    const int*   batch = (const int*)d_in[2];
    const float* nc    = (const float*)d_in[3];
    const float* ec    = (const float*)d_in[4];
    const float* W0    = (const float*)d_in[5];
    const float* as0   = (const float*)d_in[6];
    const float* ad0   = (const float*)d_in[7];
    const float* b0    = (const float*)d_in[8];
    const float* W1    = (const float*)d_in[9];
    const float* as1   = (const float*)d_in[10];
    const float* ad1   = (const float*)d_in[11];
    const float* b1    = (const float*)d_in[12];
    const float* Wc    = (const float*)d_in[13];
    const float* bc    = (const float*)d_in[14];
    float* out = (float*)d_out;

    char* ws = (char*)d_ws;
    size_t off = 0;
    auto alloc = [&](size_t bytes) { void* p = ws + off; off += (bytes + 255) & ~size_t(255); return p; };
    float*    t0       = (float*)alloc(sizeof(float) * N_NODES * 128);
    float*    t1       = (float*)alloc(sizeof(float) * N_NODES * 128);
    unsigned* Hb       = (unsigned*)alloc(sizeof(unsigned) * N_NODES * 64);  // bf16 H
    float*    als      = (float*)alloc(sizeof(float) * N_NODES * 2);
    float*    ald      = (float*)alloc(sizeof(float) * N_NODES * 2);
    int*      deg      = (int*)alloc(sizeof(int) * N_NODES);
    int*      part     = (int*)alloc(sizeof(int) * NB_SCAN);
    int*      rowstart = (int*)alloc(sizeof(int) * (N_NODES + 1));
    int*      cursor   = (int*)alloc(sizeof(int) * N_NODES);
    int*      csr      = (int*)alloc(sizeof(int) * EA);
    float*    sums     = (float*)alloc(sizeof(float) * NG * 128);

    hipMemsetAsync(deg, 0, sizeof(int) * N_NODES, stream);
    hipMemsetAsync(cursor, 0, sizeof(int) * N_NODES, stream);
    hipMemsetAsync(sums, 0, sizeof(float) * NG * 128, stream);

    hist_kernel<<<(EA + 255) / 256, 256, 0, stream>>>(ei, deg);
    partial_kernel<<<NB_SCAN, 256, 0, stream>>>(deg, part);
    scanpart_kernel<<<1, 256, 0, stream>>>(part, rowstart);
    rowstart_kernel<<<NB_SCAN, 256, 0, stream>>>(deg, part, rowstart);
    scatter_kernel<<<(EA + 255) / 256, 256, 0, stream>>>(ei, rowstart, cursor, csr);

    int gemm_grid   = (N_NODES + GROWS - 1) / GROWS;   // 782
    int nwaveblocks = (N_NODES * 64 + 255) / 256;

    // layer 0
    gemm_alpha<<<gemm_grid, 256, 0, stream>>>(x, W0, as0, ad0, Hb, als, ald);
    agg_kernel<<<nwaveblocks, 256, 0, stream>>>(Hb, ei, ec, nc, als, ald, rowstart, csr, b0, t0);

    // layer 1
    gemm_alpha<<<gemm_grid, 256, 0, stream>>>(t0, W1, as1, ad1, Hb, als, ald);
    agg_kernel<<<nwaveblocks, 256, 0, stream>>>(Hb, ei, ec, nc, als, ald, rowstart, csr, b1, t1);

    // pool + classifier
    pool_partial<<<(N_NODES + PCHUNK - 1) / PCHUNK, 128, 0, stream>>>(t1, batch, sums);
    cls_kernel<<<NG, 128, 0, stream>>>(sums, batch, Wc, bc, out);
}

// Round 6
// 323.765 us; speedup vs baseline: 2.5084x; 1.0878x over previous
//
#include <hip/hip_runtime.h>

#define N_NODES 50000
#define E_EDGES 800000
#define EA (E_EDGES + N_NODES)   // 850000 edges incl self loops
#define CH 128                   // HEADS*OUT
#define NG 128                   // num graphs
#define NEG 0.2f
#define NB_SCAN ((N_NODES + 255) / 256)   // 196 scan blocks
#define PCHUNK 64                // pool rows per block

typedef _Float16 half8  __attribute__((ext_vector_type(8)));
typedef _Float16 half2t __attribute__((ext_vector_type(2)));
typedef float    floatx4 __attribute__((ext_vector_type(4)));

// bf16 helpers (RNE pack, exact unpack)
__device__ __forceinline__ unsigned bf16_rne(float x) {
    unsigned u = __float_as_uint(x);
    return (u + 0x7fffu + ((u >> 16) & 1u)) >> 16;
}
__device__ __forceinline__ unsigned packbf2(float a, float b) {
    return bf16_rne(a) | (bf16_rne(b) << 16);
}
__device__ __forceinline__ float bfu_lo(unsigned v) { return __uint_as_float(v << 16); }
__device__ __forceinline__ float bfu_hi(unsigned v) { return __uint_as_float(v & 0xffff0000u); }

// ---------------- CSR build ----------------
__global__ void hist_kernel(const int* __restrict__ ei, int* __restrict__ deg) {
    int e = blockIdx.x * blockDim.x + threadIdx.x;
    if (e >= EA) return;
    int d = (e < E_EDGES) ? ei[E_EDGES + e] : (e - E_EDGES);
    atomicAdd(&deg[d], 1);
}

__global__ void partial_kernel(const int* __restrict__ deg, int* __restrict__ part) {
    __shared__ int buf[4];
    int i = blockIdx.x * 256 + threadIdx.x;
    int v = (i < N_NODES) ? deg[i] : 0;
    for (int o = 32; o; o >>= 1) v += __shfl_xor(v, o);
    if ((threadIdx.x & 63) == 0) buf[threadIdx.x >> 6] = v;
    __syncthreads();
    if (threadIdx.x == 0) part[blockIdx.x] = buf[0] + buf[1] + buf[2] + buf[3];
}

__global__ void scanpart_kernel(int* __restrict__ part, int* __restrict__ rowstart) {
    __shared__ int buf[256];
    int t = threadIdx.x;
    int v = (t < NB_SCAN) ? part[t] : 0;
    buf[t] = v;
    __syncthreads();
    for (int o = 1; o < 256; o <<= 1) {
        int u = (t >= o) ? buf[t - o] : 0;
        __syncthreads();
        buf[t] += u;
        __syncthreads();
    }
    if (t < NB_SCAN) part[t] = buf[t] - v;
    if (t == NB_SCAN - 1) rowstart[N_NODES] = buf[t];
}

__global__ void rowstart_kernel(const int* __restrict__ deg, const int* __restrict__ part,
                                int* __restrict__ rowstart) {
    __shared__ int buf[256];
    int i = blockIdx.x * 256 + threadIdx.x;
    int v = (i < N_NODES) ? deg[i] : 0;
    buf[threadIdx.x] = v;
    __syncthreads();
    for (int o = 1; o < 256; o <<= 1) {
        int u = (threadIdx.x >= o) ? buf[threadIdx.x - o] : 0;
        __syncthreads();
        buf[threadIdx.x] += u;
        __syncthreads();
    }
    if (i < N_NODES) rowstart[i] = part[blockIdx.x] + buf[threadIdx.x] - v;
}

__global__ void scatter_kernel(const int* __restrict__ ei, const int* __restrict__ rowstart,
                               int* __restrict__ cursor, int* __restrict__ csr) {
    int e = blockIdx.x * blockDim.x + threadIdx.x;
    if (e >= EA) return;
    int d = (e < E_EDGES) ? ei[E_EDGES + e] : (e - E_EDGES);
    int pos = rowstart[d] + atomicAdd(&cursor[d], 1);
    csr[pos] = e;
}

// ---------------- W transpose + fp16 convert (both layers in one launch) ----------------
__global__ void wt_kernel(const float* __restrict__ W0, const float* __restrict__ W1,
                          _Float16* __restrict__ Wt0, _Float16* __restrict__ Wt1) {
    int i = blockIdx.x * 256 + threadIdx.x;   // 0..32767
    int sel = i >> 14;
    int j = i & 16383;
    int c = j >> 7, k = j & 127;
    const float* W = sel ? W1 : W0;
    _Float16* Wt = sel ? Wt1 : Wt0;
    Wt[c * 128 + k] = (_Float16)W[k * 128 + c];
}

// ---------------- MFMA GEMM + fused alpha ----------------
// block: 256 threads (4 waves), tile 64 rows x 128 cols, K=128.
// wave w: rows 0..63, cols 32w..32w+31. mfma_f32_16x16x32_f16.
// A-frag: row = l&15, k = (l>>4)*8+j.  C/D: col = l&15, row = (l>>4)*4+reg.
template<int SRC_F32>
__global__ __launch_bounds__(256) void gemm_mfma(const void* __restrict__ Xsrc,
                                                 const _Float16* __restrict__ Wt,
                                                 const float* __restrict__ as_,
                                                 const float* __restrict__ ad_,
                                                 unsigned* __restrict__ Hb,
                                                 float* __restrict__ als,
                                                 float* __restrict__ ald) {
    __shared__ _Float16 As[64][136];    // pad 8 fp16 -> bank-spread b128 reads
    __shared__ _Float16 Bs[128][136];   // Wt[c][k]
    __shared__ float als_s[4][64];
    __shared__ float ald_s[4][64];
    const int tid = threadIdx.x;
    const int row0 = blockIdx.x * 64;

    if (SRC_F32) {
        const float* X = (const float*)Xsrc;
        for (int i = 0; i < 8; ++i) {
            int idx = tid + i * 256;          // float4 units: 64 rows x 32
            int r = idx >> 5, q = idx & 31;
            int gr = row0 + r;
            float4 v = make_float4(0.f, 0.f, 0.f, 0.f);
            if (gr < N_NODES) v = ((const float4*)X)[(size_t)gr * 32 + q];
            half2t p0 = { (_Float16)v.x, (_Float16)v.y };
            half2t p1 = { (_Float16)v.z, (_Float16)v.w };
            *(half2t*)&As[r][q * 4]     = p0;
            *(half2t*)&As[r][q * 4 + 2] = p1;
        }
    } else {
        const uint4* X = (const uint4*)Xsrc;  // fp16 rows: 16 x uint4
        for (int i = 0; i < 4; ++i) {
            int idx = tid + i * 256;          // 64 rows x 16
            int r = idx >> 4, q = idx & 15;
            int gr = row0 + r;
            uint4 v = make_uint4(0u, 0u, 0u, 0u);
            if (gr < N_NODES) v = X[(size_t)gr * 16 + q];
            *(uint4*)&As[r][q * 8] = v;
        }
    }
    for (int i = 0; i < 8; ++i) {
        int idx = tid + i * 256;              // 128 rows x 16
        int r = idx >> 4, q = idx & 15;
        *(uint4*)&Bs[r][q * 8] = ((const uint4*)Wt)[r * 16 + q];
    }
    __syncthreads();

    const int l = tid & 63, wv = tid >> 6;
    const int c0w = wv * 32;
    const int lr = l & 15, lq = l >> 4;

    floatx4 acc[4][2];
#pragma unroll
    for (int m = 0; m < 4; ++m)
#pragma unroll
        for (int n = 0; n < 2; ++n) acc[m][n] = (floatx4){0.f, 0.f, 0.f, 0.f};

#pragma unroll
    for (int kk = 0; kk < 4; ++kk) {
        int kb = kk * 32 + lq * 8;
        half8 a0 = *(const half8*)&As[lr][kb];
        half8 a1 = *(const half8*)&As[16 + lr][kb];
        half8 a2 = *(const half8*)&As[32 + lr][kb];
        half8 a3 = *(const half8*)&As[48 + lr][kb];
        half8 b0 = *(const half8*)&Bs[c0w + lr][kb];
        half8 b1 = *(const half8*)&Bs[c0w + 16 + lr][kb];
        acc[0][0] = __builtin_amdgcn_mfma_f32_16x16x32_f16(a0, b0, acc[0][0], 0, 0, 0);
        acc[1][0] = __builtin_amdgcn_mfma_f32_16x16x32_f16(a1, b0, acc[1][0], 0, 0, 0);
        acc[2][0] = __builtin_amdgcn_mfma_f32_16x16x32_f16(a2, b0, acc[2][0], 0, 0, 0);
        acc[3][0] = __builtin_amdgcn_mfma_f32_16x16x32_f16(a3, b0, acc[3][0], 0, 0, 0);
        acc[0][1] = __builtin_amdgcn_mfma_f32_16x16x32_f16(a0, b1, acc[0][1], 0, 0, 0);
        acc[1][1] = __builtin_amdgcn_mfma_f32_16x16x32_f16(a1, b1, acc[1][1], 0, 0, 0);
        acc[2][1] = __builtin_amdgcn_mfma_f32_16x16x32_f16(a2, b1, acc[2][1], 0, 0, 0);
        acc[3][1] = __builtin_amdgcn_mfma_f32_16x16x32_f16(a3, b1, acc[3][1], 0, 0, 0);
    }

    // epilogue: Hb store (bf16 packed) + fused alpha (from f32 acc)
    float asv0 = as_[c0w + lr],      adv0 = ad_[c0w + lr];
    float asv1 = as_[c0w + 16 + lr], adv1 = ad_[c0w + 16 + lr];
#pragma unroll
    for (int m = 0; m < 4; ++m) {
#pragma unroll
        for (int reg = 0; reg < 4; ++reg) {
            float v0 = acc[m][0][reg];
            float v1 = acc[m][1][reg];
            float ss = v0 * asv0 + v1 * asv1;
            float dd = v0 * adv0 + v1 * adv1;
            ss += __shfl_xor(ss, 1); dd += __shfl_xor(dd, 1);
            ss += __shfl_xor(ss, 2); dd += __shfl_xor(dd, 2);
            ss += __shfl_xor(ss, 4); dd += __shfl_xor(dd, 4);
            ss += __shfl_xor(ss, 8); dd += __shfl_xor(dd, 8);
            int rl = 16 * m + 4 * lq + reg;
            if (lr == 0) { als_s[wv][rl] = ss; ald_s[wv][rl] = dd; }
            float v0x = __shfl_xor(v0, 1);
            float v1x = __shfl_xor(v1, 1);
            int grow = row0 + rl;
            if ((l & 1) == 0 && grow < N_NODES) {
                Hb[(size_t)grow * 64 + ((c0w + lr) >> 1)]      = packbf2(v0, v0x);
                Hb[(size_t)grow * 64 + ((c0w + 16 + lr) >> 1)] = packbf2(v1, v1x);
            }
        }
    }
    __syncthreads();
    int r = tid & 63, sel = tid >> 6;
    int grow = row0 + r;
    if (grow < N_NODES) {
        if (sel == 0)      als[grow * 2 + 0] = als_s[0][r] + als_s[1][r];
        else if (sel == 1) als[grow * 2 + 1] = als_s[2][r] + als_s[3][r];
        else if (sel == 2) ald[grow * 2 + 0] = ald_s[0][r] + ald_s[1][r];
        else               ald[grow * 2 + 1] = ald_s[2][r] + ald_s[3][r];
    }
}

// ---------------- per-node softmax + aggregation (bf16 gather) ----------------
// BODY shared; epilogue writes fp16 (layer 0, feeds next GEMM) or f32 (layer 1, feeds pool)
#define AGG_BODY                                                                          \
    int n = blockIdx.x * (blockDim.x >> 6) + (threadIdx.x >> 6);                          \
    if (n >= N_NODES) return;                                                             \
    int lane = threadIdx.x & 63;                                                          \
    int start = rowstart[n], end = rowstart[n + 1];                                       \
    int deg = end - start;                                                                \
    const float2* als2 = (const float2*)als;                                              \
    float2 adn = ((const float2*)ald)[n];                                                 \
    int   s_reg  = n;                                                                     \
    float nq_reg = 0.f, a0_reg = -1e30f, a1_reg = -1e30f;                                 \
    if (lane < deg) {                                                                     \
        int e = csr[start + lane];                                                        \
        if (e < E_EDGES) { s_reg = ei[e]; nq_reg = ec[e]; }                               \
        else             { s_reg = e - E_EDGES; nq_reg = nc[s_reg]; }                     \
        float2 av = als2[s_reg];                                                          \
        float a0 = av.x + adn.x; a0_reg = (a0 > 0.f) ? a0 : NEG * a0;                     \
        float a1 = av.y + adn.y; a1_reg = (a1 > 0.f) ? a1 : NEG * a1;                     \
    }                                                                                     \
    float m0 = a0_reg, m1 = a1_reg;                                                       \
    for (int i = start + 64 + lane; i < end; i += 64) {                                   \
        int e = csr[i];                                                                   \
        int s = (e < E_EDGES) ? ei[e] : (e - E_EDGES);                                    \
        float2 av = als2[s];                                                              \
        float a0 = av.x + adn.x; a0 = (a0 > 0.f) ? a0 : NEG * a0;                         \
        float a1 = av.y + adn.y; a1 = (a1 > 0.f) ? a1 : NEG * a1;                         \
        m0 = fmaxf(m0, a0); m1 = fmaxf(m1, a1);                                           \
    }                                                                                     \
    for (int o = 32; o; o >>= 1) { m0 = fmaxf(m0, __shfl_xor(m0, o)); m1 = fmaxf(m1, __shfl_xor(m1, o)); } \
    float e0_reg = __expf(a0_reg - m0), e1_reg = __expf(a1_reg - m1);                     \
    float s0 = e0_reg, s1 = e1_reg;                                                       \
    for (int i = start + 64 + lane; i < end; i += 64) {                                   \
        int e = csr[i];                                                                   \
        int s = (e < E_EDGES) ? ei[e] : (e - E_EDGES);                                    \
        float2 av = als2[s];                                                              \
        float a0 = av.x + adn.x; a0 = (a0 > 0.f) ? a0 : NEG * a0;                         \
        float a1 = av.y + adn.y; a1 = (a1 > 0.f) ? a1 : NEG * a1;                         \
        s0 += __expf(a0 - m0); s1 += __expf(a1 - m1);                                     \
    }                                                                                     \
    for (int o = 32; o; o >>= 1) { s0 += __shfl_xor(s0, o); s1 += __shfl_xor(s1, o); }    \
    float inv0 = 1.f / (s0 + 1e-16f), inv1 = 1.f / (s1 + 1e-16f);                         \
    unsigned wpack_reg = packbf2(nq_reg * e0_reg * inv0, nq_reg * e1_reg * inv1);         \
    const bool h0sel = (lane < 32);                                                       \
    float acc0 = 0.f, acc1 = 0.f;                                                         \
    int cnt = (deg < 64) ? deg : 64;                                                      \
    _Pragma("unroll 8")                                                                   \
    for (int j = 0; j < cnt; ++j) {                                                       \
        int      s  = __shfl(s_reg, j);                                                   \
        unsigned wp = __shfl(wpack_reg, j);                                               \
        unsigned wb = h0sel ? (wp << 16) : (wp & 0xffff0000u);                            \
        float    w  = __uint_as_float(wb);                                                \
        unsigned hv = Hb[(size_t)s * 64 + lane];                                          \
        acc0 += w * bfu_lo(hv);                                                           \
        acc1 += w * bfu_hi(hv);                                                           \
    }                                                                                     \
    for (int i = start + 64; i < end; ++i) {                                              \
        int e = csr[i];                                                                   \
        int s; float nq;                                                                  \
        if (e < E_EDGES) { s = ei[e]; nq = ec[e]; }                                       \
        else             { s = e - E_EDGES; nq = nc[s]; }                                 \
        float2 av = als2[s];                                                              \
        float a0 = av.x + adn.x; a0 = (a0 > 0.f) ? a0 : NEG * a0;                         \
        float a1 = av.y + adn.y; a1 = (a1 > 0.f) ? a1 : NEG * a1;                         \
        float w0 = nq * __expf(a0 - m0) * inv0;                                           \
        float w1 = nq * __expf(a1 - m1) * inv1;                                           \
        float w  = h0sel ? w0 : w1;                                                       \
        unsigned hv = Hb[(size_t)s * 64 + lane];                                          \
        acc0 += w * bfu_lo(hv);                                                           \
        acc1 += w * bfu_hi(hv);                                                           \
    }                                                                                     \
    float2 bb = ((const float2*)bias)[lane];                                              \
    float o0 = acc0 + bb.x;                                                               \
    float o1 = acc1 + bb.y;                                                               \
    o0 = o0 > 0.f ? o0 : 0.f;                                                             \
    o1 = o1 > 0.f ? o1 : 0.f;

__global__ __launch_bounds__(256) void agg_f16(const unsigned* __restrict__ Hb,
                                               const int* __restrict__ ei,
                                               const float* __restrict__ ec,
                                               const float* __restrict__ nc,
                                               const float* __restrict__ als,
                                               const float* __restrict__ ald,
                                               const int* __restrict__ rowstart,
                                               const int* __restrict__ csr,
                                               const float* __restrict__ bias,
                                               _Float16* __restrict__ Xh) {
    AGG_BODY
    half2t hv2 = { (_Float16)o0, (_Float16)o1 };
    *(half2t*)&Xh[(size_t)n * 128 + 2 * lane] = hv2;
}

__global__ __launch_bounds__(256) void agg_f32(const unsigned* __restrict__ Hb,
                                               const int* __restrict__ ei,
                                               const float* __restrict__ ec,
                                               const float* __restrict__ nc,
                                               const float* __restrict__ als,
                                               const float* __restrict__ ald,
                                               const int* __restrict__ rowstart,
                                               const int* __restrict__ csr,
                                               const float* __restrict__ bias,
                                               float* __restrict__ Ho) {
    AGG_BODY
    float2 ov; ov.x = o0; ov.y = o1;
    ((float2*)(Ho + (size_t)n * 128))[lane] = ov;
}

// ---------------- global mean pool: chunked partial sums + atomics ----------------
__global__ __launch_bounds__(128) void pool_partial(const float* __restrict__ H,
                                                    const int* __restrict__ batch,
                                                    float* __restrict__ sums) {
    int row0 = blockIdx.x * PCHUNK;
    int c = threadIdx.x;
    int end = row0 + PCHUNK; if (end > N_NODES) end = N_NODES;
    float acc = 0.f;
    int curg = batch[row0];
    for (int i = row0; i < end; ++i) {
        int g = batch[i];
        if (g != curg) { atomicAdd(&sums[curg * 128 + c], acc); acc = 0.f; curg = g; }
        acc += H[(size_t)i * 128 + c];
    }
    atomicAdd(&sums[curg * 128 + c], acc);
}

// ---------------- classifier: (sums/cnt) @ Wc + bc ----------------
__global__ void cls_kernel(const float* __restrict__ sums, const int* __restrict__ batch,
                           const float* __restrict__ Wc, const float* __restrict__ bc,
                           float* __restrict__ outp) {
    int g = blockIdx.x;
    __shared__ float p[128];
    __shared__ int cnt_s;
    if (threadIdx.x == 0) {
        int lo = 0, hi = N_NODES;
        while (lo < hi) { int mid = (lo + hi) >> 1; if (batch[mid] < g) lo = mid + 1; else hi = mid; }
        int start = lo;
        hi = N_NODES;
        while (lo < hi) { int mid = (lo + hi) >> 1; if (batch[mid] <= g) lo = mid + 1; else hi = mid; }
        cnt_s = lo - start;
    }
    __syncthreads();
    float inv = 1.f / fmaxf((float)cnt_s, 1.f);
    p[threadIdx.x] = sums[g * 128 + threadIdx.x] * inv;
    __syncthreads();
    if (threadIdx.x < 10) {
        float acc = bc[threadIdx.x];
        for (int k = 0; k < 128; ++k) acc += p[k] * Wc[k * 10 + threadIdx.x];
        outp[g * 10 + threadIdx.x] = acc;
    }
}

extern "C" void kernel_launch(void* const* d_in, const int* in_sizes, int n_in,
                              void* d_out, int out_size, void* d_ws, size_t ws_size,
                              hipStream_t stream) {
    const float* x     = (const float*)d_in[0];
    const int*   ei    = (const int*)d_in[1];
    const int*   batch = (const int*)d_in[2];
    const float* nc    = (const float*)d_in[3];
    const float* ec    = (const float*)d_in[4];
    const float* W0    = (const float*)d_in[5];
    const float* as0   = (const float*)d_in[6];
    const float* ad0   = (const float*)d_in[7];
    const float* b0    = (const float*)d_in[8];
    const float* W1    = (const float*)d_in[9];
    const float* as1   = (const float*)d_in[10];
    const float* ad1   = (const float*)d_in[11];
    const float* b1    = (const float*)d_in[12];
    const float* Wc    = (const float*)d_in[13];
    const float* bc    = (const float*)d_in[14];
    float* out = (float*)d_out;

    char* ws = (char*)d_ws;
    size_t off = 0;
    auto alloc = [&](size_t bytes) { void* p = ws + off; off += (bytes + 255) & ~size_t(255); return p; };
    unsigned*  Hb       = (unsigned*)alloc(sizeof(unsigned) * N_NODES * 64);   // bf16 H
    _Float16*  Xh       = (_Float16*)alloc(sizeof(_Float16) * N_NODES * 128);  // fp16 layer-1 input
    float*     t1       = (float*)alloc(sizeof(float) * N_NODES * 128);        // f32 layer-1 output
    float*     als      = (float*)alloc(sizeof(float) * N_NODES * 2);
    float*     ald      = (float*)alloc(sizeof(float) * N_NODES * 2);
    _Float16*  Wt0      = (_Float16*)alloc(sizeof(_Float16) * 128 * 128);
    _Float16*  Wt1      = (_Float16*)alloc(sizeof(_Float16) * 128 * 128);
    int*       deg      = (int*)alloc(sizeof(int) * N_NODES);
    int*       part     = (int*)alloc(sizeof(int) * NB_SCAN);
    int*       rowstart = (int*)alloc(sizeof(int) * (N_NODES + 1));
    int*       cursor   = (int*)alloc(sizeof(int) * N_NODES);
    int*       csr      = (int*)alloc(sizeof(int) * EA);
    float*     sums     = (float*)alloc(sizeof(float) * NG * 128);

    hipMemsetAsync(deg, 0, sizeof(int) * N_NODES, stream);
    hipMemsetAsync(cursor, 0, sizeof(int) * N_NODES, stream);
    hipMemsetAsync(sums, 0, sizeof(float) * NG * 128, stream);

    wt_kernel<<<128, 256, 0, stream>>>(W0, W1, Wt0, Wt1);
    hist_kernel<<<(EA + 255) / 256, 256, 0, stream>>>(ei, deg);
    partial_kernel<<<NB_SCAN, 256, 0, stream>>>(deg, part);
    scanpart_kernel<<<1, 256, 0, stream>>>(part, rowstart);
    rowstart_kernel<<<NB_SCAN, 256, 0, stream>>>(deg, part, rowstart);
    scatter_kernel<<<(EA + 255) / 256, 256, 0, stream>>>(ei, rowstart, cursor, csr);

    int gemm_grid   = (N_NODES + 63) / 64;            // 782
    int nwaveblocks = (N_NODES * 64 + 255) / 256;     // 12500

    // layer 0
    gemm_mfma<1><<<gemm_grid, 256, 0, stream>>>(x, Wt0, as0, ad0, Hb, als, ald);
    agg_f16<<<nwaveblocks, 256, 0, stream>>>(Hb, ei, ec, nc, als, ald, rowstart, csr, b0, Xh);

    // layer 1
    gemm_mfma<0><<<gemm_grid, 256, 0, stream>>>(Xh, Wt1, as1, ad1, Hb, als, ald);
    agg_f32<<<nwaveblocks, 256, 0, stream>>>(Hb, ei, ec, nc, als, ald, rowstart, csr, b1, t1);

    // pool + classifier
    pool_partial<<<(N_NODES + PCHUNK - 1) / PCHUNK, 128, 0, stream>>>(t1, batch, sums);
    cls_kernel<<<NG, 128, 0, stream>>>(sums, batch, Wc, bc, out);
}

// Round 7
// 296.887 us; speedup vs baseline: 2.7355x; 1.0905x over previous
//
#include <hip/hip_runtime.h>

#define N_NODES 50000
#define E_EDGES 800000
#define EA (E_EDGES + N_NODES)   // 850000 edges incl self loops
#define NG 128                   // num graphs
#define NEG 0.2f
#define NB_SCAN ((N_NODES + 255) / 256)   // 196 scan blocks

typedef _Float16 half8  __attribute__((ext_vector_type(8)));
typedef _Float16 half4v __attribute__((ext_vector_type(4)));
typedef _Float16 half2t __attribute__((ext_vector_type(2)));
typedef float    floatx4 __attribute__((ext_vector_type(4)));

// bf16 helpers (RNE pack, exact unpack)
__device__ __forceinline__ unsigned bf16_rne(float x) {
    unsigned u = __float_as_uint(x);
    return (u + 0x7fffu + ((u >> 16) & 1u)) >> 16;
}
__device__ __forceinline__ unsigned packbf2(float a, float b) {
    return bf16_rne(a) | (bf16_rne(b) << 16);
}
__device__ __forceinline__ float bfu_lo(unsigned v) { return __uint_as_float(v << 16); }
__device__ __forceinline__ float bfu_hi(unsigned v) { return __uint_as_float(v & 0xffff0000u); }

// ---------------- init: zero deg/cursor + W transpose/convert ----------------
__global__ void init_kernel(const float* __restrict__ W0, const float* __restrict__ W1,
                            _Float16* __restrict__ Wt0, _Float16* __restrict__ Wt1,
                            int* __restrict__ deg, int* __restrict__ cursor) {
    int i = blockIdx.x * 256 + threadIdx.x;
    if (i < N_NODES) { deg[i] = 0; cursor[i] = 0; }
    if (i < 16384) {
        int c = i >> 7, k = i & 127;
        Wt0[c * 128 + k] = (_Float16)W0[k * 128 + c];
        Wt1[c * 128 + k] = (_Float16)W1[k * 128 + c];
    }
}

// ---------------- CSR build ----------------
__global__ void hist_kernel(const int* __restrict__ ei, int* __restrict__ deg) {
    int e = blockIdx.x * blockDim.x + threadIdx.x;
    if (e >= EA) return;
    int d = (e < E_EDGES) ? ei[E_EDGES + e] : (e - E_EDGES);
    atomicAdd(&deg[d], 1);
}

__global__ void partial_kernel(const int* __restrict__ deg, int* __restrict__ part) {
    __shared__ int buf[4];
    int i = blockIdx.x * 256 + threadIdx.x;
    int v = (i < N_NODES) ? deg[i] : 0;
    for (int o = 32; o; o >>= 1) v += __shfl_xor(v, o);
    if ((threadIdx.x & 63) == 0) buf[threadIdx.x >> 6] = v;
    __syncthreads();
    if (threadIdx.x == 0) part[blockIdx.x] = buf[0] + buf[1] + buf[2] + buf[3];
}

__global__ void scanpart_kernel(int* __restrict__ part, int* __restrict__ rowstart) {
    __shared__ int buf[256];
    int t = threadIdx.x;
    int v = (t < NB_SCAN) ? part[t] : 0;
    buf[t] = v;
    __syncthreads();
    for (int o = 1; o < 256; o <<= 1) {
        int u = (t >= o) ? buf[t - o] : 0;
        __syncthreads();
        buf[t] += u;
        __syncthreads();
    }
    if (t < NB_SCAN) part[t] = buf[t] - v;
    if (t == NB_SCAN - 1) rowstart[N_NODES] = buf[t];
}

__global__ void rowstart_kernel(const int* __restrict__ deg, const int* __restrict__ part,
                                int* __restrict__ rowstart) {
    __shared__ int buf[256];
    int i = blockIdx.x * 256 + threadIdx.x;
    int v = (i < N_NODES) ? deg[i] : 0;
    buf[threadIdx.x] = v;
    __syncthreads();
    for (int o = 1; o < 256; o <<= 1) {
        int u = (threadIdx.x >= o) ? buf[threadIdx.x - o] : 0;
        __syncthreads();
        buf[threadIdx.x] += u;
        __syncthreads();
    }
    if (i < N_NODES) rowstart[i] = part[blockIdx.x] + buf[threadIdx.x] - v;
}

__global__ void scatter_kernel(const int* __restrict__ ei, const int* __restrict__ rowstart,
                               int* __restrict__ cursor, int* __restrict__ csr) {
    int e = blockIdx.x * blockDim.x + threadIdx.x;
    if (e >= EA) return;
    int d = (e < E_EDGES) ? ei[E_EDGES + e] : (e - E_EDGES);
    int pos = rowstart[d] + atomicAdd(&cursor[d], 1);
    csr[pos] = e;
}

// ---------------- MFMA GEMM + fused alpha ----------------
// block: 256 threads (4 waves), tile 64 rows x 128 cols, K=128.
// A-frag: row = l&15, k = (l>>4)*8+j.  C/D: col = l&15, row = (l>>4)*4+reg.
template<int SRC_F32>
__global__ __launch_bounds__(256) void gemm_mfma(const void* __restrict__ Xsrc,
                                                 const _Float16* __restrict__ Wt,
                                                 const float* __restrict__ as_,
                                                 const float* __restrict__ ad_,
                                                 unsigned* __restrict__ Hb,
                                                 float* __restrict__ als,
                                                 float* __restrict__ ald) {
    __shared__ _Float16 As[64][136];      // padded; reused as bf16 store-stage in epilogue
    __shared__ _Float16 Bs[128 * 128];    // XOR-swizzled 8-elem groups (no padding)
    __shared__ float als_s[4][64];
    __shared__ float ald_s[4][64];
    const int tid = threadIdx.x;
    const int row0 = blockIdx.x * 64;

    if (SRC_F32) {
        const float* X = (const float*)Xsrc;
        for (int i = 0; i < 8; ++i) {
            int idx = tid + i * 256;          // float4 units: 64 rows x 32
            int r = idx >> 5, q = idx & 31;
            int gr = row0 + r;
            float4 v = make_float4(0.f, 0.f, 0.f, 0.f);
            if (gr < N_NODES) v = ((const float4*)X)[(size_t)gr * 32 + q];
            half2t p0 = { (_Float16)v.x, (_Float16)v.y };
            half2t p1 = { (_Float16)v.z, (_Float16)v.w };
            *(half2t*)&As[r][q * 4]     = p0;
            *(half2t*)&As[r][q * 4 + 2] = p1;
        }
    } else {
        const uint4* X = (const uint4*)Xsrc;  // fp16 rows: 16 x uint4
        for (int i = 0; i < 4; ++i) {
            int idx = tid + i * 256;          // 64 rows x 16
            int r = idx >> 4, q = idx & 15;
            int gr = row0 + r;
            uint4 v = make_uint4(0u, 0u, 0u, 0u);
            if (gr < N_NODES) v = X[(size_t)gr * 16 + q];
            *(uint4*)&As[r][q * 8] = v;
        }
    }
    for (int i = 0; i < 8; ++i) {
        int idx = tid + i * 256;              // 128 rows x 16 groups
        int r = idx >> 4, q = idx & 15;
        *(uint4*)&Bs[r * 128 + ((q ^ (r & 15)) << 3)] = ((const uint4*)Wt)[r * 16 + q];
    }
    __syncthreads();

    const int l = tid & 63, wv = tid >> 6;
    const int c0w = wv * 32;
    const int lr = l & 15, lq = l >> 4;

    floatx4 acc[4][2];
#pragma unroll
    for (int m = 0; m < 4; ++m)
#pragma unroll
        for (int n = 0; n < 2; ++n) acc[m][n] = (floatx4){0.f, 0.f, 0.f, 0.f};

#pragma unroll
    for (int kk = 0; kk < 4; ++kk) {
        int kb = kk * 32 + lq * 8;
        int kg = (kk * 4 + lq) ^ lr;          // swizzled k-group
        half8 a0 = *(const half8*)&As[lr][kb];
        half8 a1 = *(const half8*)&As[16 + lr][kb];
        half8 a2 = *(const half8*)&As[32 + lr][kb];
        half8 a3 = *(const half8*)&As[48 + lr][kb];
        half8 b0 = *(const half8*)&Bs[(c0w + lr) * 128 + (kg << 3)];
        half8 b1 = *(const half8*)&Bs[(c0w + 16 + lr) * 128 + (kg << 3)];
        acc[0][0] = __builtin_amdgcn_mfma_f32_16x16x32_f16(a0, b0, acc[0][0], 0, 0, 0);
        acc[1][0] = __builtin_amdgcn_mfma_f32_16x16x32_f16(a1, b0, acc[1][0], 0, 0, 0);
        acc[2][0] = __builtin_amdgcn_mfma_f32_16x16x32_f16(a2, b0, acc[2][0], 0, 0, 0);
        acc[3][0] = __builtin_amdgcn_mfma_f32_16x16x32_f16(a3, b0, acc[3][0], 0, 0, 0);
        acc[0][1] = __builtin_amdgcn_mfma_f32_16x16x32_f16(a0, b1, acc[0][1], 0, 0, 0);
        acc[1][1] = __builtin_amdgcn_mfma_f32_16x16x32_f16(a1, b1, acc[1][1], 0, 0, 0);
        acc[2][1] = __builtin_amdgcn_mfma_f32_16x16x32_f16(a2, b1, acc[2][1], 0, 0, 0);
        acc[3][1] = __builtin_amdgcn_mfma_f32_16x16x32_f16(a3, b1, acc[3][1], 0, 0, 0);
    }

    __syncthreads();   // all waves done reading As/Bs; reuse As as store stage

    float asv0 = as_[c0w + lr],      adv0 = ad_[c0w + lr];
    float asv1 = as_[c0w + 16 + lr], adv1 = ad_[c0w + 16 + lr];
#pragma unroll
    for (int m = 0; m < 4; ++m) {
#pragma unroll
        for (int reg = 0; reg < 4; ++reg) {
            float v0 = acc[m][0][reg];
            float v1 = acc[m][1][reg];
            int rl = 16 * m + 4 * lq + reg;
            unsigned short* rowp = (unsigned short*)&As[rl][0];
            rowp[c0w + lr]      = (unsigned short)bf16_rne(v0);
            rowp[c0w + 16 + lr] = (unsigned short)bf16_rne(v1);
            float ss = v0 * asv0 + v1 * asv1;
            float dd = v0 * adv0 + v1 * adv1;
            ss += __shfl_xor(ss, 1); dd += __shfl_xor(dd, 1);
            ss += __shfl_xor(ss, 2); dd += __shfl_xor(dd, 2);
            ss += __shfl_xor(ss, 4); dd += __shfl_xor(dd, 4);
            ss += __shfl_xor(ss, 8); dd += __shfl_xor(dd, 8);
            if (lr == 0) { als_s[wv][rl] = ss; ald_s[wv][rl] = dd; }
        }
    }
    __syncthreads();

    // coalesced bf16 H stores: 64 rows x 16 uint4
    for (int i = 0; i < 4; ++i) {
        int idx = tid + i * 256;
        int r = idx >> 4, q = idx & 15;
        int grow = row0 + r;
        if (grow < N_NODES) {
            uint4 v = *(uint4*)((unsigned short*)&As[r][0] + q * 8);
            ((uint4*)Hb)[(size_t)grow * 16 + q] = v;
        }
    }
    int r = tid & 63, sel = tid >> 6;
    int grow = row0 + r;
    if (grow < N_NODES) {
        if (sel == 0)      als[grow * 2 + 0] = als_s[0][r] + als_s[1][r];
        else if (sel == 1) als[grow * 2 + 1] = als_s[2][r] + als_s[3][r];
        else if (sel == 2) ald[grow * 2 + 0] = ald_s[0][r] + ald_s[1][r];
        else               ald[grow * 2 + 1] = ald_s[2][r] + ald_s[3][r];
    }
}

// ---------------- per-node softmax + aggregation ----------------
// MODE 0: fp16 output (feeds next GEMM). MODE 1: bf16-packed output (feeds pool).
// Gather: uint2/lane, 2 edges per iteration via v_readlane broadcast.
template<int MODE>
__global__ __launch_bounds__(256) void agg_kernel(const unsigned* __restrict__ Hb,
                                                  const int* __restrict__ ei,
                                                  const float* __restrict__ ec,
                                                  const float* __restrict__ nc,
                                                  const float* __restrict__ als,
                                                  const float* __restrict__ ald,
                                                  const int* __restrict__ rowstart,
                                                  const int* __restrict__ csr,
                                                  const float* __restrict__ bias,
                                                  void* __restrict__ outp) {
    int n = blockIdx.x * 4 + (threadIdx.x >> 6);
    if (n >= N_NODES) return;
    int lane = threadIdx.x & 63;
    int start = rowstart[n], end = rowstart[n + 1];
    int deg = end - start;
    const float2* als2 = (const float2*)als;
    float2 adn = ((const float2*)ald)[n];

    // lane j owns edge j (covers deg<=64)
    int   s_reg  = n;
    float nq_reg = 0.f, a0_reg = -1e30f, a1_reg = -1e30f;
    if (lane < deg) {
        int e = csr[start + lane];
        if (e < E_EDGES) { s_reg = ei[e]; nq_reg = ec[e]; }
        else             { s_reg = e - E_EDGES; nq_reg = nc[s_reg]; }
        float2 av = als2[s_reg];
        float a0 = av.x + adn.x; a0_reg = (a0 > 0.f) ? a0 : NEG * a0;
        float a1 = av.y + adn.y; a1_reg = (a1 > 0.f) ? a1 : NEG * a1;
    }
    float m0 = a0_reg, m1 = a1_reg;
    for (int i = start + 64 + lane; i < end; i += 64) {
        int e = csr[i];
        int s = (e < E_EDGES) ? ei[e] : (e - E_EDGES);
        float2 av = als2[s];
        float a0 = av.x + adn.x; a0 = (a0 > 0.f) ? a0 : NEG * a0;
        float a1 = av.y + adn.y; a1 = (a1 > 0.f) ? a1 : NEG * a1;
        m0 = fmaxf(m0, a0); m1 = fmaxf(m1, a1);
    }
    for (int o = 32; o; o >>= 1) { m0 = fmaxf(m0, __shfl_xor(m0, o)); m1 = fmaxf(m1, __shfl_xor(m1, o)); }

    float e0_reg = __expf(a0_reg - m0), e1_reg = __expf(a1_reg - m1);
    float s0 = e0_reg, s1 = e1_reg;
    for (int i = start + 64 + lane; i < end; i += 64) {
        int e = csr[i];
        int s = (e < E_EDGES) ? ei[e] : (e - E_EDGES);
        float2 av = als2[s];
        float a0 = av.x + adn.x; a0 = (a0 > 0.f) ? a0 : NEG * a0;
        float a1 = av.y + adn.y; a1 = (a1 > 0.f) ? a1 : NEG * a1;
        s0 += __expf(a0 - m0); s1 += __expf(a1 - m1);
    }
    for (int o = 32; o; o >>= 1) { s0 += __shfl_xor(s0, o); s1 += __shfl_xor(s1, o); }
    float inv0 = 1.f / (s0 + 1e-16f), inv1 = 1.f / (s1 + 1e-16f);

    // lanes >= deg have nq_reg = 0 -> wpack = 0 (harmless)
    unsigned wpack_reg = packbf2(nq_reg * e0_reg * inv0, nq_reg * e1_reg * inv1);

    // gather: lane owns channels 4c..4c+3 (c = lane&31); halves process alternate edges
    const int  c    = lane & 31;
    const int  half = lane >> 5;
    const bool hsel = (c < 16);     // channels < 64 -> head 0
    const uint2* Hb2 = (const uint2*)Hb;
    float acc0 = 0.f, acc1 = 0.f, acc2 = 0.f, acc3 = 0.f;
    int cnt = (deg < 64) ? deg : 64;
#pragma unroll 8
    for (int jp = 0; jp < cnt; jp += 2) {
        int      sa = __builtin_amdgcn_readlane(s_reg, jp);
        int      sb = __builtin_amdgcn_readlane(s_reg, jp + 1);
        unsigned wa = (unsigned)__builtin_amdgcn_readlane((int)wpack_reg, jp);
        unsigned wb = (unsigned)__builtin_amdgcn_readlane((int)wpack_reg, jp + 1);
        int      s  = half ? sb : sa;
        unsigned wp = half ? wb : wa;
        unsigned ws = hsel ? (wp << 16) : (wp & 0xffff0000u);
        float    w  = __uint_as_float(ws);
        uint2 hv = Hb2[(size_t)s * 32 + c];
        acc0 += w * bfu_lo(hv.x);
        acc1 += w * bfu_hi(hv.x);
        acc2 += w * bfu_lo(hv.y);
        acc3 += w * bfu_hi(hv.y);
    }
    // rare fallback deg>64: serial, only half 0 contributes
    for (int i = start + 64; i < end; ++i) {
        int e = csr[i];
        int s; float nq;
        if (e < E_EDGES) { s = ei[e]; nq = ec[e]; }
        else             { s = e - E_EDGES; nq = nc[s]; }
        float2 av = als2[s];
        float a0 = av.x + adn.x; a0 = (a0 > 0.f) ? a0 : NEG * a0;
        float a1 = av.y + adn.y; a1 = (a1 > 0.f) ? a1 : NEG * a1;
        float w0 = nq * __expf(a0 - m0) * inv0;
        float w1 = nq * __expf(a1 - m1) * inv1;
        float w  = (half == 0) ? (hsel ? w0 : w1) : 0.f;
        uint2 hv = Hb2[(size_t)s * 32 + c];
        acc0 += w * bfu_lo(hv.x);
        acc1 += w * bfu_hi(hv.x);
        acc2 += w * bfu_lo(hv.y);
        acc3 += w * bfu_hi(hv.y);
    }
    // combine halves
    acc0 += __shfl_xor(acc0, 32);
    acc1 += __shfl_xor(acc1, 32);
    acc2 += __shfl_xor(acc2, 32);
    acc3 += __shfl_xor(acc3, 32);

    if (half == 0) {
        float4 bb = ((const float4*)bias)[c];
        float o0 = acc0 + bb.x; o0 = o0 > 0.f ? o0 : 0.f;
        float o1 = acc1 + bb.y; o1 = o1 > 0.f ? o1 : 0.f;
        float o2 = acc2 + bb.z; o2 = o2 > 0.f ? o2 : 0.f;
        float o3 = acc3 + bb.w; o3 = o3 > 0.f ? o3 : 0.f;
        if (MODE == 0) {
            half4v hv = { (_Float16)o0, (_Float16)o1, (_Float16)o2, (_Float16)o3 };
            *(half4v*)((_Float16*)outp + (size_t)n * 128 + 4 * c) = hv;
        } else {
            uint2 pv;
            pv.x = packbf2(o0, o1);
            pv.y = packbf2(o2, o3);
            ((uint2*)outp)[(size_t)n * 32 + c] = pv;
        }
    }
}

// ---------------- global mean pool: one block per graph, coalesced bf16 reads ----------------
__global__ __launch_bounds__(256) void pool_kernel(const unsigned* __restrict__ Ob,
                                                   const int* __restrict__ batch,
                                                   float* __restrict__ pooled) {
    int g = blockIdx.x;
    int lo = 0, hi = N_NODES;
    while (lo < hi) { int mid = (lo + hi) >> 1; if (batch[mid] < g) lo = mid + 1; else hi = mid; }
    int start = lo;
    hi = N_NODES;
    while (lo < hi) { int mid = (lo + hi) >> 1; if (batch[mid] <= g) lo = mid + 1; else hi = mid; }
    int end = lo;

    int c2 = threadIdx.x & 63;   // uint index: channels 2c2, 2c2+1
    int r4 = threadIdx.x >> 6;   // 0..3 row groups
    float a0 = 0.f, a1 = 0.f;
    for (int i = start + r4; i < end; i += 4) {
        unsigned hv = Ob[(size_t)i * 64 + c2];
        a0 += bfu_lo(hv);
        a1 += bfu_hi(hv);
    }
    __shared__ float2 red[4][64];
    red[r4][c2].x = a0; red[r4][c2].y = a1;
    __syncthreads();
    if (threadIdx.x < 64) {
        int t = threadIdx.x;
        float inv = 1.f / fmaxf((float)(end - start), 1.f);
        float2 r0 = red[0][t], r1 = red[1][t], r2 = red[2][t], r3 = red[3][t];
        float2 o;
        o.x = (r0.x + r1.x + r2.x + r3.x) * inv;
        o.y = (r0.y + r1.y + r2.y + r3.y) * inv;
        *(float2*)&pooled[g * 128 + 2 * t] = o;
    }
}

// ---------------- classifier: pooled @ Wc + bc ----------------
__global__ void cls_kernel(const float* __restrict__ pooled, const float* __restrict__ Wc,
                           const float* __restrict__ bc, float* __restrict__ outp) {
    int g = blockIdx.x;
    __shared__ float p[128];
    p[threadIdx.x] = pooled[g * 128 + threadIdx.x];
    __syncthreads();
    if (threadIdx.x < 10) {
        float acc = bc[threadIdx.x];
        for (int k = 0; k < 128; ++k) acc += p[k] * Wc[k * 10 + threadIdx.x];
        outp[g * 10 + threadIdx.x] = acc;
    }
}

extern "C" void kernel_launch(void* const* d_in, const int* in_sizes, int n_in,
                              void* d_out, int out_size, void* d_ws, size_t ws_size,
                              hipStream_t stream) {
    const float* x     = (const float*)d_in[0];
    const int*   ei    = (const int*)d_in[1];
    const int*   batch = (const int*)d_in[2];
    const float* nc    = (const float*)d_in[3];
    const float* ec    = (const float*)d_in[4];
    const float* W0    = (const float*)d_in[5];
    const float* as0   = (const float*)d_in[6];
    const float* ad0   = (const float*)d_in[7];
    const float* b0    = (const float*)d_in[8];
    const float* W1    = (const float*)d_in[9];
    const float* as1   = (const float*)d_in[10];
    const float* ad1   = (const float*)d_in[11];
    const float* b1    = (const float*)d_in[12];
    const float* Wc    = (const float*)d_in[13];
    const float* bc    = (const float*)d_in[14];
    float* out = (float*)d_out;

    char* ws = (char*)d_ws;
    size_t off = 0;
    auto alloc = [&](size_t bytes) { void* p = ws + off; off += (bytes + 255) & ~size_t(255); return p; };
    unsigned*  Hb       = (unsigned*)alloc(sizeof(unsigned) * N_NODES * 64);   // bf16 H (pre-attn)
    _Float16*  Xh       = (_Float16*)alloc(sizeof(_Float16) * N_NODES * 128);  // fp16 layer-1 input
    unsigned*  Ob       = (unsigned*)alloc(sizeof(unsigned) * N_NODES * 64);   // bf16 layer-1 output
    float*     als      = (float*)alloc(sizeof(float) * N_NODES * 2);
    float*     ald      = (float*)alloc(sizeof(float) * N_NODES * 2);
    _Float16*  Wt0      = (_Float16*)alloc(sizeof(_Float16) * 128 * 128);
    _Float16*  Wt1      = (_Float16*)alloc(sizeof(_Float16) * 128 * 128);
    int*       deg      = (int*)alloc(sizeof(int) * N_NODES);
    int*       part     = (int*)alloc(sizeof(int) * NB_SCAN);
    int*       rowstart = (int*)alloc(sizeof(int) * (N_NODES + 1));
    int*       cursor   = (int*)alloc(sizeof(int) * N_NODES);
    int*       csr      = (int*)alloc(sizeof(int) * EA);
    float*     pooled   = (float*)alloc(sizeof(float) * NG * 128);

    init_kernel<<<NB_SCAN, 256, 0, stream>>>(W0, W1, Wt0, Wt1, deg, cursor);
    hist_kernel<<<(EA + 255) / 256, 256, 0, stream>>>(ei, deg);
    partial_kernel<<<NB_SCAN, 256, 0, stream>>>(deg, part);
    scanpart_kernel<<<1, 256, 0, stream>>>(part, rowstart);
    rowstart_kernel<<<NB_SCAN, 256, 0, stream>>>(deg, part, rowstart);
    scatter_kernel<<<(EA + 255) / 256, 256, 0, stream>>>(ei, rowstart, cursor, csr);

    int gemm_grid   = (N_NODES + 63) / 64;            // 782
    int nwaveblocks = (N_NODES + 3) / 4;              // 12500

    // layer 0
    gemm_mfma<1><<<gemm_grid, 256, 0, stream>>>(x, Wt0, as0, ad0, Hb, als, ald);
    agg_kernel<0><<<nwaveblocks, 256, 0, stream>>>(Hb, ei, ec, nc, als, ald, rowstart, csr, b0, Xh);

    // layer 1
    gemm_mfma<0><<<gemm_grid, 256, 0, stream>>>(Xh, Wt1, as1, ad1, Hb, als, ald);
    agg_kernel<1><<<nwaveblocks, 256, 0, stream>>>(Hb, ei, ec, nc, als, ald, rowstart, csr, b1, Ob);

    // pool + classifier
    pool_kernel<<<NG, 256, 0, stream>>>(Ob, batch, pooled);
    cls_kernel<<<NG, 128, 0, stream>>>(pooled, Wc, bc, out);
}

// Round 8
// 264.076 us; speedup vs baseline: 3.0754x; 1.1242x over previous
//
#include <hip/hip_runtime.h>

#define N_NODES 50000
#define E_EDGES 800000
#define EA (E_EDGES + N_NODES)   // 850000 edges incl self loops
#define NG 128                   // num graphs
#define NEG 0.2f
#define NB_SCAN ((N_NODES + 255) / 256)   // 196 scan blocks

typedef _Float16 half8  __attribute__((ext_vector_type(8)));
typedef _Float16 half4v __attribute__((ext_vector_type(4)));
typedef _Float16 half2t __attribute__((ext_vector_type(2)));
typedef float    floatx4 __attribute__((ext_vector_type(4)));

// order-preserving f32 -> u32 key for atomicMax
__device__ __forceinline__ unsigned fmax_key(float x) {
    unsigned u = __float_as_uint(x);
    return (u & 0x80000000u) ? ~u : (u | 0x80000000u);
}
__device__ __forceinline__ float fmax_dec(unsigned k) {
    unsigned u = (k & 0x80000000u) ? (k ^ 0x80000000u) : ~k;
    return __uint_as_float(u);
}
__device__ __forceinline__ half2t h2bits(unsigned u) { return __builtin_bit_cast(half2t, u); }

// ---------------- init: zero deg + gmax keys + W transpose/convert ----------------
__global__ void init_kernel(const float* __restrict__ W0, const float* __restrict__ W1,
                            _Float16* __restrict__ Wt0, _Float16* __restrict__ Wt1,
                            int* __restrict__ deg, unsigned* __restrict__ gmax) {
    int i = blockIdx.x * 256 + threadIdx.x;
    if (i < N_NODES) deg[i] = 0;
    if (i < 4) gmax[i] = 0u;
    if (i < 16384) {
        int c = i >> 7, k = i & 127;
        Wt0[c * 128 + k] = (_Float16)W0[k * 128 + c];
        Wt1[c * 128 + k] = (_Float16)W1[k * 128 + c];
    }
}

// ---------------- CSR build ----------------
// hist: count degrees AND record each edge's rank within its dst bucket
__global__ void hist_kernel(const int* __restrict__ ei, int* __restrict__ deg,
                            int* __restrict__ rank) {
    int e = blockIdx.x * blockDim.x + threadIdx.x;
    if (e >= EA) return;
    int d = (e < E_EDGES) ? ei[E_EDGES + e] : (e - E_EDGES);
    rank[e] = atomicAdd(&deg[d], 1);
}

__global__ void partial_kernel(const int* __restrict__ deg, int* __restrict__ part) {
    __shared__ int buf[4];
    int i = blockIdx.x * 256 + threadIdx.x;
    int v = (i < N_NODES) ? deg[i] : 0;
    for (int o = 32; o; o >>= 1) v += __shfl_xor(v, o);
    if ((threadIdx.x & 63) == 0) buf[threadIdx.x >> 6] = v;
    __syncthreads();
    if (threadIdx.x == 0) part[blockIdx.x] = buf[0] + buf[1] + buf[2] + buf[3];
}

__global__ void scanpart_kernel(int* __restrict__ part, int* __restrict__ rowstart) {
    __shared__ int buf[256];
    int t = threadIdx.x;
    int v = (t < NB_SCAN) ? part[t] : 0;
    buf[t] = v;
    __syncthreads();
    for (int o = 1; o < 256; o <<= 1) {
        int u = (t >= o) ? buf[t - o] : 0;
        __syncthreads();
        buf[t] += u;
        __syncthreads();
    }
    if (t < NB_SCAN) part[t] = buf[t] - v;
    if (t == NB_SCAN - 1) rowstart[N_NODES] = buf[t];
}

__global__ void rowstart_kernel(const int* __restrict__ deg, const int* __restrict__ part,
                                int* __restrict__ rowstart) {
    __shared__ int buf[256];
    int i = blockIdx.x * 256 + threadIdx.x;
    int v = (i < N_NODES) ? deg[i] : 0;
    buf[threadIdx.x] = v;
    __syncthreads();
    for (int o = 1; o < 256; o <<= 1) {
        int u = (threadIdx.x >= o) ? buf[threadIdx.x - o] : 0;
        __syncthreads();
        buf[threadIdx.x] += u;
        __syncthreads();
    }
    if (i < N_NODES) rowstart[i] = part[blockIdx.x] + buf[threadIdx.x] - v;
}

// build: atomic-free scatter of resolved (src, nq) payload
__global__ void build_kernel(const int* __restrict__ ei, const float* __restrict__ ec,
                             const float* __restrict__ nc, const int* __restrict__ rowstart,
                             const int* __restrict__ rank, uint2* __restrict__ csr2) {
    int e = blockIdx.x * blockDim.x + threadIdx.x;
    if (e >= EA) return;
    int s, d; float nq;
    if (e < E_EDGES) { s = ei[e]; d = ei[E_EDGES + e]; nq = ec[e]; }
    else             { s = e - E_EDGES; d = s; nq = nc[s]; }
    csr2[rowstart[d] + rank[e]] = make_uint2((unsigned)s, __float_as_uint(nq));
}

// ---------------- MFMA GEMM + fused alpha + global als-max ----------------
// block: 256 threads (4 waves), tile 64 rows x 128 cols, K=128.
// A-frag: row = l&15, k = (l>>4)*8+j.  C/D: col = l&15, row = (l>>4)*4+reg.
template<int SRC_F32>
__global__ __launch_bounds__(256) void gemm_mfma(const void* __restrict__ Xsrc,
                                                 const _Float16* __restrict__ Wt,
                                                 const float* __restrict__ as_,
                                                 const float* __restrict__ ad_,
                                                 unsigned* __restrict__ Hb,   // fp16-packed H
                                                 float* __restrict__ als,
                                                 float* __restrict__ ald,
                                                 unsigned* __restrict__ gmax) {
    __shared__ _Float16 As[64][136];      // padded; reused as fp16 store-stage in epilogue
    __shared__ _Float16 Bs[128 * 128];    // XOR-swizzled 8-elem groups
    __shared__ float als_s[4][64];
    __shared__ float ald_s[4][64];
    const int tid = threadIdx.x;
    const int row0 = blockIdx.x * 64;

    if (SRC_F32) {
        const float* X = (const float*)Xsrc;
        for (int i = 0; i < 8; ++i) {
            int idx = tid + i * 256;
            int r = idx >> 5, q = idx & 31;
            int gr = row0 + r;
            float4 v = make_float4(0.f, 0.f, 0.f, 0.f);
            if (gr < N_NODES) v = ((const float4*)X)[(size_t)gr * 32 + q];
            half2t p0 = { (_Float16)v.x, (_Float16)v.y };
            half2t p1 = { (_Float16)v.z, (_Float16)v.w };
            *(half2t*)&As[r][q * 4]     = p0;
            *(half2t*)&As[r][q * 4 + 2] = p1;
        }
    } else {
        const uint4* X = (const uint4*)Xsrc;
        for (int i = 0; i < 4; ++i) {
            int idx = tid + i * 256;
            int r = idx >> 4, q = idx & 15;
            int gr = row0 + r;
            uint4 v = make_uint4(0u, 0u, 0u, 0u);
            if (gr < N_NODES) v = X[(size_t)gr * 16 + q];
            *(uint4*)&As[r][q * 8] = v;
        }
    }
    for (int i = 0; i < 8; ++i) {
        int idx = tid + i * 256;
        int r = idx >> 4, q = idx & 15;
        *(uint4*)&Bs[r * 128 + ((q ^ (r & 15)) << 3)] = ((const uint4*)Wt)[r * 16 + q];
    }
    __syncthreads();

    const int l = tid & 63, wv = tid >> 6;
    const int c0w = wv * 32;
    const int lr = l & 15, lq = l >> 4;

    floatx4 acc[4][2];
#pragma unroll
    for (int m = 0; m < 4; ++m)
#pragma unroll
        for (int n = 0; n < 2; ++n) acc[m][n] = (floatx4){0.f, 0.f, 0.f, 0.f};

#pragma unroll
    for (int kk = 0; kk < 4; ++kk) {
        int kb = kk * 32 + lq * 8;
        int kg = (kk * 4 + lq) ^ lr;
        half8 a0 = *(const half8*)&As[lr][kb];
        half8 a1 = *(const half8*)&As[16 + lr][kb];
        half8 a2 = *(const half8*)&As[32 + lr][kb];
        half8 a3 = *(const half8*)&As[48 + lr][kb];
        half8 b0 = *(const half8*)&Bs[(c0w + lr) * 128 + (kg << 3)];
        half8 b1 = *(const half8*)&Bs[(c0w + 16 + lr) * 128 + (kg << 3)];
        acc[0][0] = __builtin_amdgcn_mfma_f32_16x16x32_f16(a0, b0, acc[0][0], 0, 0, 0);
        acc[1][0] = __builtin_amdgcn_mfma_f32_16x16x32_f16(a1, b0, acc[1][0], 0, 0, 0);
        acc[2][0] = __builtin_amdgcn_mfma_f32_16x16x32_f16(a2, b0, acc[2][0], 0, 0, 0);
        acc[3][0] = __builtin_amdgcn_mfma_f32_16x16x32_f16(a3, b0, acc[3][0], 0, 0, 0);
        acc[0][1] = __builtin_amdgcn_mfma_f32_16x16x32_f16(a0, b1, acc[0][1], 0, 0, 0);
        acc[1][1] = __builtin_amdgcn_mfma_f32_16x16x32_f16(a1, b1, acc[1][1], 0, 0, 0);
        acc[2][1] = __builtin_amdgcn_mfma_f32_16x16x32_f16(a2, b1, acc[2][1], 0, 0, 0);
        acc[3][1] = __builtin_amdgcn_mfma_f32_16x16x32_f16(a3, b1, acc[3][1], 0, 0, 0);
    }

    __syncthreads();   // reuse As as store stage

    float asv0 = as_[c0w + lr],      adv0 = ad_[c0w + lr];
    float asv1 = as_[c0w + 16 + lr], adv1 = ad_[c0w + 16 + lr];
#pragma unroll
    for (int m = 0; m < 4; ++m) {
#pragma unroll
        for (int reg = 0; reg < 4; ++reg) {
            float v0 = acc[m][0][reg];
            float v1 = acc[m][1][reg];
            int rl = 16 * m + 4 * lq + reg;
            _Float16* rowp = &As[rl][0];
            rowp[c0w + lr]      = (_Float16)v0;
            rowp[c0w + 16 + lr] = (_Float16)v1;
            float ss = v0 * asv0 + v1 * asv1;
            float dd = v0 * adv0 + v1 * adv1;
            ss += __shfl_xor(ss, 1); dd += __shfl_xor(dd, 1);
            ss += __shfl_xor(ss, 2); dd += __shfl_xor(dd, 2);
            ss += __shfl_xor(ss, 4); dd += __shfl_xor(dd, 4);
            ss += __shfl_xor(ss, 8); dd += __shfl_xor(dd, 8);
            if (lr == 0) { als_s[wv][rl] = ss; ald_s[wv][rl] = dd; }
        }
    }
    __syncthreads();

    // coalesced fp16 H stores: 64 rows x 16 uint4
    for (int i = 0; i < 4; ++i) {
        int idx = tid + i * 256;
        int r = idx >> 4, q = idx & 15;
        int grow = row0 + r;
        if (grow < N_NODES) {
            uint4 v = *(uint4*)((unsigned short*)&As[r][0] + q * 8);
            ((uint4*)Hb)[(size_t)grow * 16 + q] = v;
        }
    }
    int r = tid & 63, sel = tid >> 6;
    int grow = row0 + r;
    float v;
    if (sel == 0)      v = als_s[0][r] + als_s[1][r];
    else if (sel == 1) v = als_s[2][r] + als_s[3][r];
    else if (sel == 2) v = ald_s[0][r] + ald_s[1][r];
    else               v = ald_s[2][r] + ald_s[3][r];
    if (grow < N_NODES) {
        if (sel == 0)      als[grow * 2 + 0] = v;
        else if (sel == 1) als[grow * 2 + 1] = v;
        else if (sel == 2) ald[grow * 2 + 0] = v;
        else               ald[grow * 2 + 1] = v;
    }
    if (sel < 2) {           // global per-head max of als (padding rows contribute 0: safe upper bound)
        float mv = v;
        for (int o = 32; o; o >>= 1) mv = fmaxf(mv, __shfl_xor(mv, o));
        if (r == 0) atomicMax(&gmax[sel], fmax_key(mv));
    }
}

// ---------------- per-node softmax + aggregation (fp16 gather, global-max bound) ----------------
__global__ __launch_bounds__(256) void agg_kernel(const uint2* __restrict__ Hb2,
                                                  const uint2* __restrict__ csr2,
                                                  const float* __restrict__ als,
                                                  const float* __restrict__ ald,
                                                  const int* __restrict__ rowstart,
                                                  const unsigned* __restrict__ gmax,
                                                  const float* __restrict__ bias,
                                                  _Float16* __restrict__ outp) {
    int n = blockIdx.x * 4 + (threadIdx.x >> 6);
    if (n >= N_NODES) return;
    int lane = threadIdx.x & 63;
    int start = rowstart[n], end = rowstart[n + 1];
    int deg = end - start;
    const float2* als2 = (const float2*)als;
    float2 adn = ((const float2*)ald)[n];
    // softmax shift: any upper bound works (shift-invariance); global als max keeps exp <= 1
    float g0 = fmax_dec(gmax[0]), g1 = fmax_dec(gmax[1]);
    float t0 = g0 + adn.x; float m0 = (t0 > 0.f) ? t0 : NEG * t0;
    float t1 = g1 + adn.y; float m1 = (t1 > 0.f) ? t1 : NEG * t1;

    // lane j owns edge j (covers deg<=64)
    int   s_reg  = n;
    float nq_reg = 0.f, a0_reg = -1e30f, a1_reg = -1e30f;
    if (lane < deg) {
        uint2 v = csr2[start + lane];
        s_reg  = (int)v.x;
        nq_reg = __uint_as_float(v.y);
        float2 av = als2[s_reg];
        float a0 = av.x + adn.x; a0_reg = (a0 > 0.f) ? a0 : NEG * a0;
        float a1 = av.y + adn.y; a1_reg = (a1 > 0.f) ? a1 : NEG * a1;
    }
    float e0_reg = __expf(a0_reg - m0), e1_reg = __expf(a1_reg - m1);
    float s0 = e0_reg, s1 = e1_reg;
    for (int i = start + 64 + lane; i < end; i += 64) {   // rare deg>64
        uint2 v = csr2[i];
        float2 av = als2[v.x];
        float a0 = av.x + adn.x; a0 = (a0 > 0.f) ? a0 : NEG * a0;
        float a1 = av.y + adn.y; a1 = (a1 > 0.f) ? a1 : NEG * a1;
        s0 += __expf(a0 - m0); s1 += __expf(a1 - m1);
    }
    for (int o = 32; o; o >>= 1) { s0 += __shfl_xor(s0, o); s1 += __shfl_xor(s1, o); }
    float inv0 = 1.f / (s0 + 1e-16f), inv1 = 1.f / (s1 + 1e-16f);

    float w0 = nq_reg * e0_reg * inv0;
    float w1 = nq_reg * e1_reg * inv1;

    // gather: lane owns channels 4c..4c+3 (c = lane&31); halves process alternate edges
    const int  c    = lane & 31;
    const int  half = lane >> 5;
    const bool hsel = (c < 16);                 // channels < 64 -> head 0
    float wsel = hsel ? w0 : w1;                // pre-select this lane's head weight
    float acc0 = 0.f, acc1 = 0.f, acc2 = 0.f, acc3 = 0.f;
    int cnt = (deg < 64) ? deg : 64;
#pragma unroll 8
    for (int jp = 0; jp < cnt; jp += 2) {
        int      sa = __builtin_amdgcn_readlane(s_reg, jp);
        int      sb = __builtin_amdgcn_readlane(s_reg, jp + 1);
        unsigned wa = (unsigned)__builtin_amdgcn_readlane((int)__float_as_uint(wsel), jp);
        unsigned wb = (unsigned)__builtin_amdgcn_readlane((int)__float_as_uint(wsel), jp + 1);
        int   s = half ? sb : sa;
        float w = __uint_as_float(half ? wb : wa);
        uint2 hv = Hb2[(unsigned)(s * 32 + c)];
        half2t ha = h2bits(hv.x);
        half2t hb = h2bits(hv.y);
        acc0 += (float)ha.x * w;     // v_fma_mix_f32
        acc1 += (float)ha.y * w;
        acc2 += (float)hb.x * w;
        acc3 += (float)hb.y * w;
    }
    // rare fallback deg>64: serial, only half 0 contributes
    for (int i = start + 64; i < end; ++i) {
        uint2 v = csr2[i];
        int s = (int)v.x; float nq = __uint_as_float(v.y);
        float2 av = als2[s];
        float a0 = av.x + adn.x; a0 = (a0 > 0.f) ? a0 : NEG * a0;
        float a1 = av.y + adn.y; a1 = (a1 > 0.f) ? a1 : NEG * a1;
        float w0f = nq * __expf(a0 - m0) * inv0;
        float w1f = nq * __expf(a1 - m1) * inv1;
        float w   = (half == 0) ? (hsel ? w0f : w1f) : 0.f;
        uint2 hv = Hb2[(unsigned)(s * 32 + c)];
        half2t ha = h2bits(hv.x);
        half2t hb = h2bits(hv.y);
        acc0 += (float)ha.x * w;
        acc1 += (float)ha.y * w;
        acc2 += (float)hb.x * w;
        acc3 += (float)hb.y * w;
    }
    acc0 += __shfl_xor(acc0, 32);
    acc1 += __shfl_xor(acc1, 32);
    acc2 += __shfl_xor(acc2, 32);
    acc3 += __shfl_xor(acc3, 32);

    if (half == 0) {
        float4 bb = ((const float4*)bias)[c];
        float o0 = acc0 + bb.x; o0 = o0 > 0.f ? o0 : 0.f;
        float o1 = acc1 + bb.y; o1 = o1 > 0.f ? o1 : 0.f;
        float o2 = acc2 + bb.z; o2 = o2 > 0.f ? o2 : 0.f;
        float o3 = acc3 + bb.w; o3 = o3 > 0.f ? o3 : 0.f;
        half4v hvout = { (_Float16)o0, (_Float16)o1, (_Float16)o2, (_Float16)o3 };
        *(half4v*)(outp + (size_t)n * 128 + 4 * c) = hvout;
    }
}

// ---------------- global mean pool: one block per graph, coalesced fp16 reads ----------------
__global__ __launch_bounds__(256) void pool_kernel(const half2t* __restrict__ Obh,
                                                   const int* __restrict__ batch,
                                                   float* __restrict__ pooled) {
    int g = blockIdx.x;
    int lo = 0, hi = N_NODES;
    while (lo < hi) { int mid = (lo + hi) >> 1; if (batch[mid] < g) lo = mid + 1; else hi = mid; }
    int start = lo;
    hi = N_NODES;
    while (lo < hi) { int mid = (lo + hi) >> 1; if (batch[mid] <= g) lo = mid + 1; else hi = mid; }
    int end = lo;

    int c2 = threadIdx.x & 63;   // half2 index: channels 2c2, 2c2+1
    int r4 = threadIdx.x >> 6;   // 0..3 row groups
    float a0 = 0.f, a1 = 0.f;
    for (int i = start + r4; i < end; i += 4) {
        half2t hv = Obh[(size_t)i * 64 + c2];
        a0 += (float)hv.x;
        a1 += (float)hv.y;
    }
    __shared__ float2 red[4][64];
    red[r4][c2].x = a0; red[r4][c2].y = a1;
    __syncthreads();
    if (threadIdx.x < 64) {
        int t = threadIdx.x;
        float inv = 1.f / fmaxf((float)(end - start), 1.f);
        float2 r0 = red[0][t], r1 = red[1][t], r2 = red[2][t], r3 = red[3][t];
        float2 o;
        o.x = (r0.x + r1.x + r2.x + r3.x) * inv;
        o.y = (r0.y + r1.y + r2.y + r3.y) * inv;
        *(float2*)&pooled[g * 128 + 2 * t] = o;
    }
}

// ---------------- classifier: pooled @ Wc + bc ----------------
__global__ void cls_kernel(const float* __restrict__ pooled, const float* __restrict__ Wc,
                           const float* __restrict__ bc, float* __restrict__ outp) {
    int g = blockIdx.x;
    __shared__ float p[128];
    p[threadIdx.x] = pooled[g * 128 + threadIdx.x];
    __syncthreads();
    if (threadIdx.x < 10) {
        float acc = bc[threadIdx.x];
        for (int k = 0; k < 128; ++k) acc += p[k] * Wc[k * 10 + threadIdx.x];
        outp[g * 10 + threadIdx.x] = acc;
    }
}

extern "C" void kernel_launch(void* const* d_in, const int* in_sizes, int n_in,
                              void* d_out, int out_size, void* d_ws, size_t ws_size,
                              hipStream_t stream) {
    const float* x     = (const float*)d_in[0];
    const int*   ei    = (const int*)d_in[1];
    const int*   batch = (const int*)d_in[2];
    const float* nc    = (const float*)d_in[3];
    const float* ec    = (const float*)d_in[4];
    const float* W0    = (const float*)d_in[5];
    const float* as0   = (const float*)d_in[6];
    const float* ad0   = (const float*)d_in[7];
    const float* b0    = (const float*)d_in[8];
    const float* W1    = (const float*)d_in[9];
    const float* as1   = (const float*)d_in[10];
    const float* ad1   = (const float*)d_in[11];
    const float* b1    = (const float*)d_in[12];
    const float* Wc    = (const float*)d_in[13];
    const float* bc    = (const float*)d_in[14];
    float* out = (float*)d_out;

    char* ws = (char*)d_ws;
    size_t off = 0;
    auto alloc = [&](size_t bytes) { void* p = ws + off; off += (bytes + 255) & ~size_t(255); return p; };
    unsigned*  Hb       = (unsigned*)alloc(sizeof(unsigned) * N_NODES * 64);    // fp16 H (pre-attn)
    _Float16*  Xh       = (_Float16*)alloc(sizeof(_Float16) * N_NODES * 128);   // fp16 layer-1 input
    _Float16*  Ob       = (_Float16*)alloc(sizeof(_Float16) * N_NODES * 128);   // fp16 layer-1 output
    float*     als      = (float*)alloc(sizeof(float) * N_NODES * 2);
    float*     ald      = (float*)alloc(sizeof(float) * N_NODES * 2);
    _Float16*  Wt0      = (_Float16*)alloc(sizeof(_Float16) * 128 * 128);
    _Float16*  Wt1      = (_Float16*)alloc(sizeof(_Float16) * 128 * 128);
    int*       deg      = (int*)alloc(sizeof(int) * N_NODES);
    int*       rank     = (int*)alloc(sizeof(int) * EA);
    int*       part     = (int*)alloc(sizeof(int) * NB_SCAN);
    int*       rowstart = (int*)alloc(sizeof(int) * (N_NODES + 1));
    uint2*     csr2     = (uint2*)alloc(sizeof(uint2) * EA);
    float*     pooled   = (float*)alloc(sizeof(float) * NG * 128);
    unsigned*  gmax     = (unsigned*)alloc(sizeof(unsigned) * 4);   // [0,1]=layer0, [2,3]=layer1

    init_kernel<<<NB_SCAN, 256, 0, stream>>>(W0, W1, Wt0, Wt1, deg, gmax);
    hist_kernel<<<(EA + 255) / 256, 256, 0, stream>>>(ei, deg, rank);
    partial_kernel<<<NB_SCAN, 256, 0, stream>>>(deg, part);
    scanpart_kernel<<<1, 256, 0, stream>>>(part, rowstart);
    rowstart_kernel<<<NB_SCAN, 256, 0, stream>>>(deg, part, rowstart);
    build_kernel<<<(EA + 255) / 256, 256, 0, stream>>>(ei, ec, nc, rowstart, rank, csr2);

    int gemm_grid   = (N_NODES + 63) / 64;            // 782
    int nwaveblocks = (N_NODES + 3) / 4;              // 12500

    // layer 0
    gemm_mfma<1><<<gemm_grid, 256, 0, stream>>>(x, Wt0, as0, ad0, Hb, als, ald, gmax);
    agg_kernel<<<nwaveblocks, 256, 0, stream>>>((const uint2*)Hb, csr2, als, ald, rowstart, gmax, b0, Xh);

    // layer 1
    gemm_mfma<0><<<gemm_grid, 256, 0, stream>>>(Xh, Wt1, as1, ad1, Hb, als, ald, gmax + 2);
    agg_kernel<<<nwaveblocks, 256, 0, stream>>>((const uint2*)Hb, csr2, als, ald, rowstart, gmax + 2, b1, Ob);

    // pool + classifier
    pool_kernel<<<NG, 256, 0, stream>>>((const half2t*)Ob, batch, pooled);
    cls_kernel<<<NG, 128, 0, stream>>>(pooled, Wc, bc, out);
}

// Round 9
// 212.957 us; speedup vs baseline: 3.8136x; 1.2400x over previous
//
#include <hip/hip_runtime.h>

#define N_NODES 50000
#define E_EDGES 800000
#define EA (E_EDGES + N_NODES)   // 850000 edges incl self loops
#define NG 128                   // num graphs
#define NEG 0.2f
#define NB_SCAN ((N_NODES + 255) / 256)   // 196 scan blocks

typedef _Float16 half8  __attribute__((ext_vector_type(8)));
typedef _Float16 half2t __attribute__((ext_vector_type(2)));
typedef float    floatx4 __attribute__((ext_vector_type(4)));

__device__ __forceinline__ half2t h2bits(unsigned u) { return __builtin_bit_cast(half2t, u); }

// ---------------- init: zero deg + W transpose/convert ----------------
__global__ void init_kernel(const float* __restrict__ W0, const float* __restrict__ W1,
                            _Float16* __restrict__ Wt0, _Float16* __restrict__ Wt1,
                            int* __restrict__ deg) {
    int i = blockIdx.x * 256 + threadIdx.x;
    if (i < N_NODES) deg[i] = 0;
    if (i < 16384) {
        int c = i >> 7, k = i & 127;
        Wt0[c * 128 + k] = (_Float16)W0[k * 128 + c];
        Wt1[c * 128 + k] = (_Float16)W1[k * 128 + c];
    }
}

// ---------------- CSR build ----------------
__global__ void hist_kernel(const int* __restrict__ ei, int* __restrict__ deg,
                            int* __restrict__ rank) {
    int e = blockIdx.x * blockDim.x + threadIdx.x;
    if (e >= EA) return;
    int d = (e < E_EDGES) ? ei[E_EDGES + e] : (e - E_EDGES);
    rank[e] = atomicAdd(&deg[d], 1);
}

__global__ void partial_kernel(const int* __restrict__ deg, int* __restrict__ part) {
    __shared__ int buf[4];
    int i = blockIdx.x * 256 + threadIdx.x;
    int v = (i < N_NODES) ? deg[i] : 0;
    for (int o = 32; o; o >>= 1) v += __shfl_xor(v, o);
    if ((threadIdx.x & 63) == 0) buf[threadIdx.x >> 6] = v;
    __syncthreads();
    if (threadIdx.x == 0) part[blockIdx.x] = buf[0] + buf[1] + buf[2] + buf[3];
}

// fused: block offset from self-scanned partials + local exclusive scan
__global__ void rowstart_kernel(const int* __restrict__ deg, const int* __restrict__ part,
                                int* __restrict__ rowstart) {
    __shared__ int buf[256];
    __shared__ int wsum[4];
    __shared__ int offs;
    int t = threadIdx.x;
    int pv = (t < blockIdx.x) ? part[t] : 0;   // blockIdx.x <= 195 < 196 entries
    for (int o = 32; o; o >>= 1) pv += __shfl_xor(pv, o);
    if ((t & 63) == 0) wsum[t >> 6] = pv;
    __syncthreads();
    if (t == 0) offs = wsum[0] + wsum[1] + wsum[2] + wsum[3];
    int i = blockIdx.x * 256 + t;
    int v = (i < N_NODES) ? deg[i] : 0;
    buf[t] = v;
    __syncthreads();
    for (int o = 1; o < 256; o <<= 1) {
        int u = (t >= o) ? buf[t - o] : 0;
        __syncthreads();
        buf[t] += u;
        __syncthreads();
    }
    if (i < N_NODES) rowstart[i] = offs + buf[t] - v;
    if (i == N_NODES - 1) rowstart[N_NODES] = offs + buf[t];
}

// atomic-free scatter of resolved (src, nq) payload
__global__ void build_kernel(const int* __restrict__ ei, const float* __restrict__ ec,
                             const float* __restrict__ nc, const int* __restrict__ rowstart,
                             const int* __restrict__ rank, uint2* __restrict__ csr2) {
    int e = blockIdx.x * blockDim.x + threadIdx.x;
    if (e >= EA) return;
    int s, d; float nq;
    if (e < E_EDGES) { s = ei[e]; d = ei[E_EDGES + e]; nq = ec[e]; }
    else             { s = e - E_EDGES; d = s; nq = nc[s]; }
    csr2[rowstart[d] + rank[e]] = make_uint2((unsigned)s, __float_as_uint(nq));
}

// ---------------- MFMA GEMM + fused alpha ----------------
// block: 256 threads (4 waves), tile 64 rows x 128 cols, K=128.
// A-frag: row = l&15, k = (l>>4)*8+j.  C/D: col = l&15, row = (l>>4)*4+reg.
template<int SRC_F32>
__global__ __launch_bounds__(256) void gemm_mfma(const void* __restrict__ Xsrc,
                                                 const _Float16* __restrict__ Wt,
                                                 const float* __restrict__ as_,
                                                 const float* __restrict__ ad_,
                                                 unsigned* __restrict__ Hb,   // fp16-packed H
                                                 float* __restrict__ als,
                                                 float* __restrict__ ald) {
    __shared__ _Float16 As[64][136];      // padded; reused as fp16 store-stage
    __shared__ _Float16 Bs[128 * 128];    // XOR-swizzled 8-elem groups
    __shared__ float als_s[4][64];
    __shared__ float ald_s[4][64];
    const int tid = threadIdx.x;
    const int row0 = blockIdx.x * 64;

    if (SRC_F32) {
        const float* X = (const float*)Xsrc;
        for (int i = 0; i < 8; ++i) {
            int idx = tid + i * 256;
            int r = idx >> 5, q = idx & 31;
            int gr = row0 + r;
            float4 v = make_float4(0.f, 0.f, 0.f, 0.f);
            if (gr < N_NODES) v = ((const float4*)X)[(size_t)gr * 32 + q];
            half2t p0 = { (_Float16)v.x, (_Float16)v.y };
            half2t p1 = { (_Float16)v.z, (_Float16)v.w };
            *(half2t*)&As[r][q * 4]     = p0;
            *(half2t*)&As[r][q * 4 + 2] = p1;
        }
    } else {
        const uint4* X = (const uint4*)Xsrc;
        for (int i = 0; i < 4; ++i) {
            int idx = tid + i * 256;
            int r = idx >> 4, q = idx & 15;
            int gr = row0 + r;
            uint4 v = make_uint4(0u, 0u, 0u, 0u);
            if (gr < N_NODES) v = X[(size_t)gr * 16 + q];
            *(uint4*)&As[r][q * 8] = v;
        }
    }
    for (int i = 0; i < 8; ++i) {
        int idx = tid + i * 256;
        int r = idx >> 4, q = idx & 15;
        *(uint4*)&Bs[r * 128 + ((q ^ (r & 15)) << 3)] = ((const uint4*)Wt)[r * 16 + q];
    }
    __syncthreads();

    const int l = tid & 63, wv = tid >> 6;
    const int c0w = wv * 32;
    const int lr = l & 15, lq = l >> 4;

    floatx4 acc[4][2];
#pragma unroll
    for (int m = 0; m < 4; ++m)
#pragma unroll
        for (int n = 0; n < 2; ++n) acc[m][n] = (floatx4){0.f, 0.f, 0.f, 0.f};

#pragma unroll
    for (int kk = 0; kk < 4; ++kk) {
        int kb = kk * 32 + lq * 8;
        int kg = (kk * 4 + lq) ^ lr;
        half8 a0 = *(const half8*)&As[lr][kb];
        half8 a1 = *(const half8*)&As[16 + lr][kb];
        half8 a2 = *(const half8*)&As[32 + lr][kb];
        half8 a3 = *(const half8*)&As[48 + lr][kb];
        half8 b0 = *(const half8*)&Bs[(c0w + lr) * 128 + (kg << 3)];
        half8 b1 = *(const half8*)&Bs[(c0w + 16 + lr) * 128 + (kg << 3)];
        acc[0][0] = __builtin_amdgcn_mfma_f32_16x16x32_f16(a0, b0, acc[0][0], 0, 0, 0);
        acc[1][0] = __builtin_amdgcn_mfma_f32_16x16x32_f16(a1, b0, acc[1][0], 0, 0, 0);
        acc[2][0] = __builtin_amdgcn_mfma_f32_16x16x32_f16(a2, b0, acc[2][0], 0, 0, 0);
        acc[3][0] = __builtin_amdgcn_mfma_f32_16x16x32_f16(a3, b0, acc[3][0], 0, 0, 0);
        acc[0][1] = __builtin_amdgcn_mfma_f32_16x16x32_f16(a0, b1, acc[0][1], 0, 0, 0);
        acc[1][1] = __builtin_amdgcn_mfma_f32_16x16x32_f16(a1, b1, acc[1][1], 0, 0, 0);
        acc[2][1] = __builtin_amdgcn_mfma_f32_16x16x32_f16(a2, b1, acc[2][1], 0, 0, 0);
        acc[3][1] = __builtin_amdgcn_mfma_f32_16x16x32_f16(a3, b1, acc[3][1], 0, 0, 0);
    }

    __syncthreads();   // reuse As as store stage

    float asv0 = as_[c0w + lr],      adv0 = ad_[c0w + lr];
    float asv1 = as_[c0w + 16 + lr], adv1 = ad_[c0w + 16 + lr];
#pragma unroll
    for (int m = 0; m < 4; ++m) {
#pragma unroll
        for (int reg = 0; reg < 4; ++reg) {
            float v0 = acc[m][0][reg];
            float v1 = acc[m][1][reg];
            int rl = 16 * m + 4 * lq + reg;
            _Float16* rowp = &As[rl][0];
            rowp[c0w + lr]      = (_Float16)v0;
            rowp[c0w + 16 + lr] = (_Float16)v1;
            float ss = v0 * asv0 + v1 * asv1;
            float dd = v0 * adv0 + v1 * adv1;
            ss += __shfl_xor(ss, 1); dd += __shfl_xor(dd, 1);
            ss += __shfl_xor(ss, 2); dd += __shfl_xor(dd, 2);
            ss += __shfl_xor(ss, 4); dd += __shfl_xor(dd, 4);
            ss += __shfl_xor(ss, 8); dd += __shfl_xor(dd, 8);
            if (lr == 0) { als_s[wv][rl] = ss; ald_s[wv][rl] = dd; }
        }
    }
    __syncthreads();

    // coalesced fp16 H stores: 64 rows x 16 uint4
    for (int i = 0; i < 4; ++i) {
        int idx = tid + i * 256;
        int r = idx >> 4, q = idx & 15;
        int grow = row0 + r;
        if (grow < N_NODES) {
            uint4 v = *(uint4*)((unsigned short*)&As[r][0] + q * 8);
            ((uint4*)Hb)[(size_t)grow * 16 + q] = v;
        }
    }
    int r = tid & 63, sel = tid >> 6;
    int grow = row0 + r;
    if (grow < N_NODES) {
        if (sel == 0)      als[grow * 2 + 0] = als_s[0][r] + als_s[1][r];
        else if (sel == 1) als[grow * 2 + 1] = als_s[2][r] + als_s[3][r];
        else if (sel == 2) ald[grow * 2 + 0] = ald_s[0][r] + ald_s[1][r];
        else               ald[grow * 2 + 1] = ald_s[2][r] + ald_s[3][r];
    }
}

// ---------------- per-node softmax + aggregation ----------------
// softmax: lane j owns edge j. gather: 16-lane groups, 4 edges/iter via LDS (s,w0,w1) broadcast.
__global__ __launch_bounds__(256) void agg_kernel(const uint4* __restrict__ Hb4,
                                                  const uint2* __restrict__ csr2,
                                                  const float* __restrict__ als,
                                                  const float* __restrict__ ald,
                                                  const int* __restrict__ rowstart,
                                                  const float* __restrict__ bias,
                                                  _Float16* __restrict__ outp) {
    __shared__ uint4 sw[4][64];
    const int wv = threadIdx.x >> 6;
    int n = blockIdx.x * 4 + wv;
    if (n >= N_NODES) return;
    const int lane = threadIdx.x & 63;
    int start = rowstart[n], end = rowstart[n + 1];
    int deg = end - start;
    const float2* als2 = (const float2*)als;
    float2 adn = ((const float2*)ald)[n];

    // lane j resolves edge j
    int   s_reg  = n;
    float nq_reg = 0.f, a0_reg = -1e30f, a1_reg = -1e30f;
    if (lane < deg) {
        uint2 v = csr2[start + lane];
        s_reg  = (int)v.x;
        nq_reg = __uint_as_float(v.y);
        float2 av = als2[s_reg];
        float a0 = av.x + adn.x; a0_reg = (a0 > 0.f) ? a0 : NEG * a0;
        float a1 = av.y + adn.y; a1_reg = (a1 > 0.f) ? a1 : NEG * a1;
    }
    // per-node max (lane-parallel; rare stride loop for deg>64)
    float m0 = a0_reg, m1 = a1_reg;
    for (int i = start + 64 + lane; i < end; i += 64) {
        uint2 v = csr2[i];
        float2 av = als2[v.x];
        float a0 = av.x + adn.x; a0 = (a0 > 0.f) ? a0 : NEG * a0;
        float a1 = av.y + adn.y; a1 = (a1 > 0.f) ? a1 : NEG * a1;
        m0 = fmaxf(m0, a0); m1 = fmaxf(m1, a1);
    }
    for (int o = 32; o; o >>= 1) { m0 = fmaxf(m0, __shfl_xor(m0, o)); m1 = fmaxf(m1, __shfl_xor(m1, o)); }

    float e0 = __expf(a0_reg - m0), e1 = __expf(a1_reg - m1);
    float s0 = e0, s1 = e1;
    for (int i = start + 64 + lane; i < end; i += 64) {
        uint2 v = csr2[i];
        float2 av = als2[v.x];
        float a0 = av.x + adn.x; a0 = (a0 > 0.f) ? a0 : NEG * a0;
        float a1 = av.y + adn.y; a1 = (a1 > 0.f) ? a1 : NEG * a1;
        s0 += __expf(a0 - m0); s1 += __expf(a1 - m1);
    }
    for (int o = 32; o; o >>= 1) { s0 += __shfl_xor(s0, o); s1 += __shfl_xor(s1, o); }
    float inv0 = 1.f / (s0 + 1e-16f), inv1 = 1.f / (s1 + 1e-16f);

    // stash (s, w0, w1); lanes >= deg have nq_reg=0 -> w=0, s=n (safe row)
    sw[wv][lane] = make_uint4((unsigned)s_reg,
                              __float_as_uint(nq_reg * e0 * inv0),
                              __float_as_uint(nq_reg * e1 * inv1), 0u);

    const int  c16   = lane & 15;      // uint4 column: channels 8*c16 .. 8*c16+7
    const int  g     = lane >> 4;      // edge group
    const bool head0 = (c16 < 8);
    float acc0 = 0.f, acc1 = 0.f, acc2 = 0.f, acc3 = 0.f;
    float acc4 = 0.f, acc5 = 0.f, acc6 = 0.f, acc7 = 0.f;
    int cnt4 = (deg < 64) ? ((deg + 3) & ~3) : 64;
#pragma unroll 4
    for (int jp = 0; jp < cnt4; jp += 4) {
        uint4 sv = sw[wv][jp + g];
        float w  = __uint_as_float(head0 ? sv.y : sv.z);
        uint4 hv = Hb4[(size_t)(sv.x * 16u + (unsigned)c16)];
        half2t h0 = h2bits(hv.x), h1 = h2bits(hv.y), h2 = h2bits(hv.z), h3 = h2bits(hv.w);
        acc0 += (float)h0.x * w; acc1 += (float)h0.y * w;
        acc2 += (float)h1.x * w; acc3 += (float)h1.y * w;
        acc4 += (float)h2.x * w; acc5 += (float)h2.y * w;
        acc6 += (float)h3.x * w; acc7 += (float)h3.y * w;
    }
    // rare deg>64: process remaining chunks of 64
    for (int cbase = start + 64; cbase < end; cbase += 64) {
        int   s2 = n; float w0f = 0.f, w1f = 0.f;
        int i = cbase + lane;
        if (i < end) {
            uint2 v = csr2[i];
            s2 = (int)v.x;
            float nq = __uint_as_float(v.y);
            float2 av = als2[s2];
            float a0 = av.x + adn.x; a0 = (a0 > 0.f) ? a0 : NEG * a0;
            float a1 = av.y + adn.y; a1 = (a1 > 0.f) ? a1 : NEG * a1;
            w0f = nq * __expf(a0 - m0) * inv0;
            w1f = nq * __expf(a1 - m1) * inv1;
        }
        sw[wv][lane] = make_uint4((unsigned)s2, __float_as_uint(w0f), __float_as_uint(w1f), 0u);
        int rem = end - cbase; if (rem > 64) rem = 64;
        int r4 = (rem + 3) & ~3;
        for (int jp = 0; jp < r4; jp += 4) {
            uint4 sv = sw[wv][jp + g];
            float w  = __uint_as_float(head0 ? sv.y : sv.z);
            uint4 hv = Hb4[(size_t)(sv.x * 16u + (unsigned)c16)];
            half2t h0 = h2bits(hv.x), h1 = h2bits(hv.y), h2 = h2bits(hv.z), h3 = h2bits(hv.w);
            acc0 += (float)h0.x * w; acc1 += (float)h0.y * w;
            acc2 += (float)h1.x * w; acc3 += (float)h1.y * w;
            acc4 += (float)h2.x * w; acc5 += (float)h2.y * w;
            acc6 += (float)h3.x * w; acc7 += (float)h3.y * w;
        }
    }
    // reduce across the 4 edge groups
    acc0 += __shfl_xor(acc0, 16); acc1 += __shfl_xor(acc1, 16);
    acc2 += __shfl_xor(acc2, 16); acc3 += __shfl_xor(acc3, 16);
    acc4 += __shfl_xor(acc4, 16); acc5 += __shfl_xor(acc5, 16);
    acc6 += __shfl_xor(acc6, 16); acc7 += __shfl_xor(acc7, 16);
    acc0 += __shfl_xor(acc0, 32); acc1 += __shfl_xor(acc1, 32);
    acc2 += __shfl_xor(acc2, 32); acc3 += __shfl_xor(acc3, 32);
    acc4 += __shfl_xor(acc4, 32); acc5 += __shfl_xor(acc5, 32);
    acc6 += __shfl_xor(acc6, 32); acc7 += __shfl_xor(acc7, 32);

    if (g == 0) {
        float4 ba = ((const float4*)bias)[c16 * 2];
        float4 bb = ((const float4*)bias)[c16 * 2 + 1];
        float o0 = acc0 + ba.x; o0 = o0 > 0.f ? o0 : 0.f;
        float o1 = acc1 + ba.y; o1 = o1 > 0.f ? o1 : 0.f;
        float o2 = acc2 + ba.z; o2 = o2 > 0.f ? o2 : 0.f;
        float o3 = acc3 + ba.w; o3 = o3 > 0.f ? o3 : 0.f;
        float o4 = acc4 + bb.x; o4 = o4 > 0.f ? o4 : 0.f;
        float o5 = acc5 + bb.y; o5 = o5 > 0.f ? o5 : 0.f;
        float o6 = acc6 + bb.z; o6 = o6 > 0.f ? o6 : 0.f;
        float o7 = acc7 + bb.w; o7 = o7 > 0.f ? o7 : 0.f;
        half8 hv = { (_Float16)o0, (_Float16)o1, (_Float16)o2, (_Float16)o3,
                     (_Float16)o4, (_Float16)o5, (_Float16)o6, (_Float16)o7 };
        *(half8*)(outp + (size_t)n * 128 + 8 * c16) = hv;
    }
}

// ---------------- fused global mean pool + classifier ----------------
__global__ __launch_bounds__(256) void poolcls_kernel(const half2t* __restrict__ Obh,
                                                      const int* __restrict__ batch,
                                                      const float* __restrict__ Wc,
                                                      const float* __restrict__ bc,
                                                      float* __restrict__ outp) {
    int g = blockIdx.x;
    int lo = 0, hi = N_NODES;
    while (lo < hi) { int mid = (lo + hi) >> 1; if (batch[mid] < g) lo = mid + 1; else hi = mid; }
    int start = lo;
    hi = N_NODES;
    while (lo < hi) { int mid = (lo + hi) >> 1; if (batch[mid] <= g) lo = mid + 1; else hi = mid; }
    int end = lo;

    int c2 = threadIdx.x & 63;   // half2 index: channels 2c2, 2c2+1
    int r4 = threadIdx.x >> 6;   // row group
    float a0 = 0.f, a1 = 0.f;
    for (int i = start + r4; i < end; i += 4) {
        half2t hv = Obh[(size_t)i * 64 + c2];
        a0 += (float)hv.x;
        a1 += (float)hv.y;
    }
    __shared__ float2 red[4][64];
    __shared__ float p[128];
    red[r4][c2].x = a0; red[r4][c2].y = a1;
    __syncthreads();
    if (threadIdx.x < 64) {
        int t = threadIdx.x;
        float inv = 1.f / fmaxf((float)(end - start), 1.f);
        float2 r0 = red[0][t], r1 = red[1][t], r2 = red[2][t], r3 = red[3][t];
        p[2 * t]     = (r0.x + r1.x + r2.x + r3.x) * inv;
        p[2 * t + 1] = (r0.y + r1.y + r2.y + r3.y) * inv;
    }
    __syncthreads();
    if (threadIdx.x < 10) {
        float acc = bc[threadIdx.x];
        for (int k = 0; k < 128; ++k) acc += p[k] * Wc[k * 10 + threadIdx.x];
        outp[g * 10 + threadIdx.x] = acc;
    }
}

extern "C" void kernel_launch(void* const* d_in, const int* in_sizes, int n_in,
                              void* d_out, int out_size, void* d_ws, size_t ws_size,
                              hipStream_t stream) {
    const float* x     = (const float*)d_in[0];
    const int*   ei    = (const int*)d_in[1];
    const int*   batch = (const int*)d_in[2];
    const float* nc    = (const float*)d_in[3];
    const float* ec    = (const float*)d_in[4];
    const float* W0    = (const float*)d_in[5];
    const float* as0   = (const float*)d_in[6];
    const float* ad0   = (const float*)d_in[7];
    const float* b0    = (const float*)d_in[8];
    const float* W1    = (const float*)d_in[9];
    const float* as1   = (const float*)d_in[10];
    const float* ad1   = (const float*)d_in[11];
    const float* b1    = (const float*)d_in[12];
    const float* Wc    = (const float*)d_in[13];
    const float* bc    = (const float*)d_in[14];
    float* out = (float*)d_out;

    char* ws = (char*)d_ws;
    size_t off = 0;
    auto alloc = [&](size_t bytes) { void* p = ws + off; off += (bytes + 255) & ~size_t(255); return p; };
    unsigned*  Hb       = (unsigned*)alloc(sizeof(unsigned) * N_NODES * 64);    // fp16 H (pre-attn)
    _Float16*  Xh       = (_Float16*)alloc(sizeof(_Float16) * N_NODES * 128);   // fp16 layer-1 input
    _Float16*  Ob       = (_Float16*)alloc(sizeof(_Float16) * N_NODES * 128);   // fp16 layer-1 output
    float*     als      = (float*)alloc(sizeof(float) * N_NODES * 2);
    float*     ald      = (float*)alloc(sizeof(float) * N_NODES * 2);
    _Float16*  Wt0      = (_Float16*)alloc(sizeof(_Float16) * 128 * 128);
    _Float16*  Wt1      = (_Float16*)alloc(sizeof(_Float16) * 128 * 128);
    int*       deg      = (int*)alloc(sizeof(int) * N_NODES);
    int*       rank     = (int*)alloc(sizeof(int) * EA);
    int*       part     = (int*)alloc(sizeof(int) * NB_SCAN);
    int*       rowstart = (int*)alloc(sizeof(int) * (N_NODES + 1));
    uint2*     csr2     = (uint2*)alloc(sizeof(uint2) * EA);

    init_kernel<<<NB_SCAN, 256, 0, stream>>>(W0, W1, Wt0, Wt1, deg);
    hist_kernel<<<(EA + 255) / 256, 256, 0, stream>>>(ei, deg, rank);
    partial_kernel<<<NB_SCAN, 256, 0, stream>>>(deg, part);
    rowstart_kernel<<<NB_SCAN, 256, 0, stream>>>(deg, part, rowstart);
    build_kernel<<<(EA + 255) / 256, 256, 0, stream>>>(ei, ec, nc, rowstart, rank, csr2);

    int gemm_grid   = (N_NODES + 63) / 64;            // 782
    int nwaveblocks = (N_NODES + 3) / 4;              // 12500

    // layer 0
    gemm_mfma<1><<<gemm_grid, 256, 0, stream>>>(x, Wt0, as0, ad0, Hb, als, ald);
    agg_kernel<<<nwaveblocks, 256, 0, stream>>>((const uint4*)Hb, csr2, als, ald, rowstart, b0, Xh);

    // layer 1
    gemm_mfma<0><<<gemm_grid, 256, 0, stream>>>(Xh, Wt1, as1, ad1, Hb, als, ald);
    agg_kernel<<<nwaveblocks, 256, 0, stream>>>((const uint4*)Hb, csr2, als, ald, rowstart, b1, Ob);

    // pool + classifier (fused)
    poolcls_kernel<<<NG, 256, 0, stream>>>((const half2t*)Ob, batch, Wc, bc, out);
}

// Round 10
// 198.009 us; speedup vs baseline: 4.1015x; 1.0755x over previous
//
#include <hip/hip_runtime.h>

#define N_NODES 50000
#define E_EDGES 800000
#define EA (E_EDGES + N_NODES)   // 850000 edges incl self loops
#define NG 128                   // num graphs
#define NEG 0.2f
#define NB_SCAN ((N_NODES + 255) / 256)   // 196 scan blocks
#define PCH 64                   // pool rows per block

typedef _Float16 half8  __attribute__((ext_vector_type(8)));
typedef _Float16 half2t __attribute__((ext_vector_type(2)));
typedef float    floatx4 __attribute__((ext_vector_type(4)));

__device__ __forceinline__ half2t h2bits(unsigned u) { return __builtin_bit_cast(half2t, u); }

// ---------------- init: zero deg + pool sums + W transpose/convert ----------------
__global__ void init_kernel(const float* __restrict__ W0, const float* __restrict__ W1,
                            _Float16* __restrict__ Wt0, _Float16* __restrict__ Wt1,
                            int* __restrict__ deg, float* __restrict__ sums) {
    int i = blockIdx.x * 256 + threadIdx.x;
    if (i < N_NODES) deg[i] = 0;
    if (i < NG * 128) sums[i] = 0.f;
    if (i < 16384) {
        int c = i >> 7, k = i & 127;
        Wt0[c * 128 + k] = (_Float16)W0[k * 128 + c];
        Wt1[c * 128 + k] = (_Float16)W1[k * 128 + c];
    }
}

// ---------------- CSR build ----------------
__global__ void hist_kernel(const int* __restrict__ ei, int* __restrict__ deg,
                            int* __restrict__ rank) {
    int e = blockIdx.x * blockDim.x + threadIdx.x;
    if (e >= EA) return;
    int d = (e < E_EDGES) ? ei[E_EDGES + e] : (e - E_EDGES);
    rank[e] = atomicAdd(&deg[d], 1);
}

__global__ void partial_kernel(const int* __restrict__ deg, int* __restrict__ part) {
    __shared__ int buf[4];
    int i = blockIdx.x * 256 + threadIdx.x;
    int v = (i < N_NODES) ? deg[i] : 0;
    for (int o = 32; o; o >>= 1) v += __shfl_xor(v, o);
    if ((threadIdx.x & 63) == 0) buf[threadIdx.x >> 6] = v;
    __syncthreads();
    if (threadIdx.x == 0) part[blockIdx.x] = buf[0] + buf[1] + buf[2] + buf[3];
}

// fused: block offset from self-scanned partials + local exclusive scan
__global__ void rowstart_kernel(const int* __restrict__ deg, const int* __restrict__ part,
                                int* __restrict__ rowstart) {
    __shared__ int buf[256];
    __shared__ int wsum[4];
    __shared__ int offs;
    int t = threadIdx.x;
    int pv = (t < blockIdx.x) ? part[t] : 0;
    for (int o = 32; o; o >>= 1) pv += __shfl_xor(pv, o);
    if ((t & 63) == 0) wsum[t >> 6] = pv;
    __syncthreads();
    if (t == 0) offs = wsum[0] + wsum[1] + wsum[2] + wsum[3];
    int i = blockIdx.x * 256 + t;
    int v = (i < N_NODES) ? deg[i] : 0;
    buf[t] = v;
    __syncthreads();
    for (int o = 1; o < 256; o <<= 1) {
        int u = (t >= o) ? buf[t - o] : 0;
        __syncthreads();
        buf[t] += u;
        __syncthreads();
    }
    if (i < N_NODES) rowstart[i] = offs + buf[t] - v;
    if (i == N_NODES - 1) rowstart[N_NODES] = offs + buf[t];
}

// atomic-free scatter of resolved (src, nq) payload
__global__ void build_kernel(const int* __restrict__ ei, const float* __restrict__ ec,
                             const float* __restrict__ nc, const int* __restrict__ rowstart,
                             const int* __restrict__ rank, uint2* __restrict__ csr2) {
    int e = blockIdx.x * blockDim.x + threadIdx.x;
    if (e >= EA) return;
    int s, d; float nq;
    if (e < E_EDGES) { s = ei[e]; d = ei[E_EDGES + e]; nq = ec[e]; }
    else             { s = e - E_EDGES; d = s; nq = nc[s]; }
    csr2[rowstart[d] + rank[e]] = make_uint2((unsigned)s, __float_as_uint(nq));
}

// ---------------- MFMA GEMM + fused alpha ----------------
// block: 256 threads (4 waves), tile 64 rows x 128 cols, K=128.
// A-frag: row = l&15, k = (l>>4)*8+j.  C/D: col = l&15, row = (l>>4)*4+reg.
template<int SRC_F32>
__global__ __launch_bounds__(256) void gemm_mfma(const void* __restrict__ Xsrc,
                                                 const _Float16* __restrict__ Wt,
                                                 const float* __restrict__ as_,
                                                 const float* __restrict__ ad_,
                                                 unsigned* __restrict__ Hb,   // fp16-packed H
                                                 float* __restrict__ als,
                                                 float* __restrict__ ald) {
    __shared__ _Float16 As[64][136];      // padded; reused as fp16 store-stage
    __shared__ _Float16 Bs[128 * 128];    // XOR-swizzled 8-elem groups
    __shared__ float als_s[4][64];
    __shared__ float ald_s[4][64];
    const int tid = threadIdx.x;
    const int row0 = blockIdx.x * 64;

    if (SRC_F32) {
        const float* X = (const float*)Xsrc;
        for (int i = 0; i < 8; ++i) {
            int idx = tid + i * 256;
            int r = idx >> 5, q = idx & 31;
            int gr = row0 + r;
            float4 v = make_float4(0.f, 0.f, 0.f, 0.f);
            if (gr < N_NODES) v = ((const float4*)X)[(size_t)gr * 32 + q];
            half2t p0 = { (_Float16)v.x, (_Float16)v.y };
            half2t p1 = { (_Float16)v.z, (_Float16)v.w };
            *(half2t*)&As[r][q * 4]     = p0;
            *(half2t*)&As[r][q * 4 + 2] = p1;
        }
    } else {
        const uint4* X = (const uint4*)Xsrc;
        for (int i = 0; i < 4; ++i) {
            int idx = tid + i * 256;
            int r = idx >> 4, q = idx & 15;
            int gr = row0 + r;
            uint4 v = make_uint4(0u, 0u, 0u, 0u);
            if (gr < N_NODES) v = X[(size_t)gr * 16 + q];
            *(uint4*)&As[r][q * 8] = v;
        }
    }
    for (int i = 0; i < 8; ++i) {
        int idx = tid + i * 256;
        int r = idx >> 4, q = idx & 15;
        *(uint4*)&Bs[r * 128 + ((q ^ (r & 15)) << 3)] = ((const uint4*)Wt)[r * 16 + q];
    }
    __syncthreads();

    const int l = tid & 63, wv = tid >> 6;
    const int c0w = wv * 32;
    const int lr = l & 15, lq = l >> 4;

    floatx4 acc[4][2];
#pragma unroll
    for (int m = 0; m < 4; ++m)
#pragma unroll
        for (int n = 0; n < 2; ++n) acc[m][n] = (floatx4){0.f, 0.f, 0.f, 0.f};

#pragma unroll
    for (int kk = 0; kk < 4; ++kk) {
        int kb = kk * 32 + lq * 8;
        int kg = (kk * 4 + lq) ^ lr;
        half8 a0 = *(const half8*)&As[lr][kb];
        half8 a1 = *(const half8*)&As[16 + lr][kb];
        half8 a2 = *(const half8*)&As[32 + lr][kb];
        half8 a3 = *(const half8*)&As[48 + lr][kb];
        half8 b0 = *(const half8*)&Bs[(c0w + lr) * 128 + (kg << 3)];
        half8 b1 = *(const half8*)&Bs[(c0w + 16 + lr) * 128 + (kg << 3)];
        acc[0][0] = __builtin_amdgcn_mfma_f32_16x16x32_f16(a0, b0, acc[0][0], 0, 0, 0);
        acc[1][0] = __builtin_amdgcn_mfma_f32_16x16x32_f16(a1, b0, acc[1][0], 0, 0, 0);
        acc[2][0] = __builtin_amdgcn_mfma_f32_16x16x32_f16(a2, b0, acc[2][0], 0, 0, 0);
        acc[3][0] = __builtin_amdgcn_mfma_f32_16x16x32_f16(a3, b0, acc[3][0], 0, 0, 0);
        acc[0][1] = __builtin_amdgcn_mfma_f32_16x16x32_f16(a0, b1, acc[0][1], 0, 0, 0);
        acc[1][1] = __builtin_amdgcn_mfma_f32_16x16x32_f16(a1, b1, acc[1][1], 0, 0, 0);
        acc[2][1] = __builtin_amdgcn_mfma_f32_16x16x32_f16(a2, b1, acc[2][1], 0, 0, 0);
        acc[3][1] = __builtin_amdgcn_mfma_f32_16x16x32_f16(a3, b1, acc[3][1], 0, 0, 0);
    }

    __syncthreads();   // reuse As as store stage

    float asv0 = as_[c0w + lr],      adv0 = ad_[c0w + lr];
    float asv1 = as_[c0w + 16 + lr], adv1 = ad_[c0w + 16 + lr];
#pragma unroll
    for (int m = 0; m < 4; ++m) {
#pragma unroll
        for (int reg = 0; reg < 4; ++reg) {
            float v0 = acc[m][0][reg];
            float v1 = acc[m][1][reg];
            int rl = 16 * m + 4 * lq + reg;
            _Float16* rowp = &As[rl][0];
            rowp[c0w + lr]      = (_Float16)v0;
            rowp[c0w + 16 + lr] = (_Float16)v1;
            float ss = v0 * asv0 + v1 * asv1;
            float dd = v0 * adv0 + v1 * adv1;
            ss += __shfl_xor(ss, 1); dd += __shfl_xor(dd, 1);
            ss += __shfl_xor(ss, 2); dd += __shfl_xor(dd, 2);
            ss += __shfl_xor(ss, 4); dd += __shfl_xor(dd, 4);
            ss += __shfl_xor(ss, 8); dd += __shfl_xor(dd, 8);
            if (lr == 0) { als_s[wv][rl] = ss; ald_s[wv][rl] = dd; }
        }
    }
    __syncthreads();

    // coalesced fp16 H stores: 64 rows x 16 uint4
    for (int i = 0; i < 4; ++i) {
        int idx = tid + i * 256;
        int r = idx >> 4, q = idx & 15;
        int grow = row0 + r;
        if (grow < N_NODES) {
            uint4 v = *(uint4*)((unsigned short*)&As[r][0] + q * 8);
            ((uint4*)Hb)[(size_t)grow * 16 + q] = v;
        }
    }
    int r = tid & 63, sel = tid >> 6;
    int grow = row0 + r;
    if (grow < N_NODES) {
        if (sel == 0)      als[grow * 2 + 0] = als_s[0][r] + als_s[1][r];
        else if (sel == 1) als[grow * 2 + 1] = als_s[2][r] + als_s[3][r];
        else if (sel == 2) ald[grow * 2 + 0] = ald_s[0][r] + ald_s[1][r];
        else               ald[grow * 2 + 1] = ald_s[2][r] + ald_s[3][r];
    }
}

// ---------------- per-node softmax + aggregation ----------------
// softmax: lane j owns edge j. gather: 16-lane groups, 4 edges/iter via LDS (s,w0,w1) broadcast.
__global__ __launch_bounds__(256) void agg_kernel(const uint4* __restrict__ Hb4,
                                                  const uint2* __restrict__ csr2,
                                                  const float* __restrict__ als,
                                                  const float* __restrict__ ald,
                                                  const int* __restrict__ rowstart,
                                                  const float* __restrict__ bias,
                                                  _Float16* __restrict__ outp) {
    __shared__ uint4 sw[4][64];
    const int wv = threadIdx.x >> 6;
    int n = blockIdx.x * 4 + wv;
    if (n >= N_NODES) return;
    const int lane = threadIdx.x & 63;
    int start = rowstart[n], end = rowstart[n + 1];
    int deg = end - start;
    const float2* als2 = (const float2*)als;
    float2 adn = ((const float2*)ald)[n];

    // lane j resolves edge j
    int   s_reg  = n;
    float nq_reg = 0.f, a0_reg = -1e30f, a1_reg = -1e30f;
    if (lane < deg) {
        uint2 v = csr2[start + lane];
        s_reg  = (int)v.x;
        nq_reg = __uint_as_float(v.y);
        float2 av = als2[s_reg];
        float a0 = av.x + adn.x; a0_reg = (a0 > 0.f) ? a0 : NEG * a0;
        float a1 = av.y + adn.y; a1_reg = (a1 > 0.f) ? a1 : NEG * a1;
    }
    // per-node max (lane-parallel; rare stride loop for deg>64)
    float m0 = a0_reg, m1 = a1_reg;
    for (int i = start + 64 + lane; i < end; i += 64) {
        uint2 v = csr2[i];
        float2 av = als2[v.x];
        float a0 = av.x + adn.x; a0 = (a0 > 0.f) ? a0 : NEG * a0;
        float a1 = av.y + adn.y; a1 = (a1 > 0.f) ? a1 : NEG * a1;
        m0 = fmaxf(m0, a0); m1 = fmaxf(m1, a1);
    }
    for (int o = 32; o; o >>= 1) { m0 = fmaxf(m0, __shfl_xor(m0, o)); m1 = fmaxf(m1, __shfl_xor(m1, o)); }

    float e0 = __expf(a0_reg - m0), e1 = __expf(a1_reg - m1);
    float s0 = e0, s1 = e1;
    for (int i = start + 64 + lane; i < end; i += 64) {
        uint2 v = csr2[i];
        float2 av = als2[v.x];
        float a0 = av.x + adn.x; a0 = (a0 > 0.f) ? a0 : NEG * a0;
        float a1 = av.y + adn.y; a1 = (a1 > 0.f) ? a1 : NEG * a1;
        s0 += __expf(a0 - m0); s1 += __expf(a1 - m1);
    }
    for (int o = 32; o; o >>= 1) { s0 += __shfl_xor(s0, o); s1 += __shfl_xor(s1, o); }
    float inv0 = 1.f / (s0 + 1e-16f), inv1 = 1.f / (s1 + 1e-16f);

    // stash (s, w0, w1); lanes >= deg have nq_reg=0 -> w=0, s=n (safe row)
    sw[wv][lane] = make_uint4((unsigned)s_reg,
                              __float_as_uint(nq_reg * e0 * inv0),
                              __float_as_uint(nq_reg * e1 * inv1), 0u);

    const int  c16   = lane & 15;      // uint4 column: channels 8*c16 .. 8*c16+7
    const int  g     = lane >> 4;      // edge group
    const bool head0 = (c16 < 8);
    float acc0 = 0.f, acc1 = 0.f, acc2 = 0.f, acc3 = 0.f;
    float acc4 = 0.f, acc5 = 0.f, acc6 = 0.f, acc7 = 0.f;
    int cnt4 = (deg < 64) ? ((deg + 3) & ~3) : 64;
#pragma unroll 4
    for (int jp = 0; jp < cnt4; jp += 4) {
        uint4 sv = sw[wv][jp + g];
        float w  = __uint_as_float(head0 ? sv.y : sv.z);
        uint4 hv = Hb4[(size_t)(sv.x * 16u + (unsigned)c16)];
        half2t h0 = h2bits(hv.x), h1 = h2bits(hv.y), h2 = h2bits(hv.z), h3 = h2bits(hv.w);
        acc0 += (float)h0.x * w; acc1 += (float)h0.y * w;
        acc2 += (float)h1.x * w; acc3 += (float)h1.y * w;
        acc4 += (float)h2.x * w; acc5 += (float)h2.y * w;
        acc6 += (float)h3.x * w; acc7 += (float)h3.y * w;
    }
    // rare deg>64: process remaining chunks of 64
    for (int cbase = start + 64; cbase < end; cbase += 64) {
        int   s2 = n; float w0f = 0.f, w1f = 0.f;
        int i = cbase + lane;
        if (i < end) {
            uint2 v = csr2[i];
            s2 = (int)v.x;
            float nq = __uint_as_float(v.y);
            float2 av = als2[s2];
            float a0 = av.x + adn.x; a0 = (a0 > 0.f) ? a0 : NEG * a0;
            float a1 = av.y + adn.y; a1 = (a1 > 0.f) ? a1 : NEG * a1;
            w0f = nq * __expf(a0 - m0) * inv0;
            w1f = nq * __expf(a1 - m1) * inv1;
        }
        sw[wv][lane] = make_uint4((unsigned)s2, __float_as_uint(w0f), __float_as_uint(w1f), 0u);
        int rem = end - cbase; if (rem > 64) rem = 64;
        int r4 = (rem + 3) & ~3;
        for (int jp = 0; jp < r4; jp += 4) {
            uint4 sv = sw[wv][jp + g];
            float w  = __uint_as_float(head0 ? sv.y : sv.z);
            uint4 hv = Hb4[(size_t)(sv.x * 16u + (unsigned)c16)];
            half2t h0 = h2bits(hv.x), h1 = h2bits(hv.y), h2 = h2bits(hv.z), h3 = h2bits(hv.w);
            acc0 += (float)h0.x * w; acc1 += (float)h0.y * w;
            acc2 += (float)h1.x * w; acc3 += (float)h1.y * w;
            acc4 += (float)h2.x * w; acc5 += (float)h2.y * w;
            acc6 += (float)h3.x * w; acc7 += (float)h3.y * w;
        }
    }
    // reduce across the 4 edge groups
    acc0 += __shfl_xor(acc0, 16); acc1 += __shfl_xor(acc1, 16);
    acc2 += __shfl_xor(acc2, 16); acc3 += __shfl_xor(acc3, 16);
    acc4 += __shfl_xor(acc4, 16); acc5 += __shfl_xor(acc5, 16);
    acc6 += __shfl_xor(acc6, 16); acc7 += __shfl_xor(acc7, 16);
    acc0 += __shfl_xor(acc0, 32); acc1 += __shfl_xor(acc1, 32);
    acc2 += __shfl_xor(acc2, 32); acc3 += __shfl_xor(acc3, 32);
    acc4 += __shfl_xor(acc4, 32); acc5 += __shfl_xor(acc5, 32);
    acc6 += __shfl_xor(acc6, 32); acc7 += __shfl_xor(acc7, 32);

    if (g == 0) {
        float4 ba = ((const float4*)bias)[c16 * 2];
        float4 bb = ((const float4*)bias)[c16 * 2 + 1];
        float o0 = acc0 + ba.x; o0 = o0 > 0.f ? o0 : 0.f;
        float o1 = acc1 + ba.y; o1 = o1 > 0.f ? o1 : 0.f;
        float o2 = acc2 + ba.z; o2 = o2 > 0.f ? o2 : 0.f;
        float o3 = acc3 + ba.w; o3 = o3 > 0.f ? o3 : 0.f;
        float o4 = acc4 + bb.x; o4 = o4 > 0.f ? o4 : 0.f;
        float o5 = acc5 + bb.y; o5 = o5 > 0.f ? o5 : 0.f;
        float o6 = acc6 + bb.z; o6 = o6 > 0.f ? o6 : 0.f;
        float o7 = acc7 + bb.w; o7 = o7 > 0.f ? o7 : 0.f;
        half8 hv = { (_Float16)o0, (_Float16)o1, (_Float16)o2, (_Float16)o3,
                     (_Float16)o4, (_Float16)o5, (_Float16)o6, (_Float16)o7 };
        *(half8*)(outp + (size_t)n * 128 + 8 * c16) = hv;
    }
}

// ---------------- global mean pool: chunked partial sums + atomics ----------------
__global__ __launch_bounds__(256) void pool_partial(const half2t* __restrict__ Obh,
                                                    const int* __restrict__ batch,
                                                    float* __restrict__ sums) {
    int row0 = blockIdx.x * PCH;
    int c2 = threadIdx.x & 63;   // half2 column: channels 2c2, 2c2+1
    int r4 = threadIdx.x >> 6;   // 0..3 row phase
    int end = row0 + PCH; if (end > N_NODES) end = N_NODES;
    float a0 = 0.f, a1 = 0.f;
    int curg = -1;
    for (int i = row0 + r4; i < end; i += 4) {
        int g = batch[i];
        if (g != curg) {
            if (curg >= 0) {
                atomicAdd(&sums[curg * 128 + 2 * c2],     a0);
                atomicAdd(&sums[curg * 128 + 2 * c2 + 1], a1);
            }
            a0 = 0.f; a1 = 0.f; curg = g;
        }
        half2t hv = Obh[(size_t)i * 64 + c2];
        a0 += (float)hv.x;
        a1 += (float)hv.y;
    }
    if (curg >= 0) {
        atomicAdd(&sums[curg * 128 + 2 * c2],     a0);
        atomicAdd(&sums[curg * 128 + 2 * c2 + 1], a1);
    }
}

// ---------------- classifier: (sums/cnt) @ Wc + bc ----------------
__global__ void cls_kernel(const float* __restrict__ sums, const int* __restrict__ batch,
                           const float* __restrict__ Wc, const float* __restrict__ bc,
                           float* __restrict__ outp) {
    int g = blockIdx.x;
    __shared__ float p[128];
    __shared__ int cnt_s;
    if (threadIdx.x == 0) {
        int lo = 0, hi = N_NODES;
        while (lo < hi) { int mid = (lo + hi) >> 1; if (batch[mid] < g) lo = mid + 1; else hi = mid; }
        int start = lo;
        hi = N_NODES;
        while (lo < hi) { int mid = (lo + hi) >> 1; if (batch[mid] <= g) lo = mid + 1; else hi = mid; }
        cnt_s = lo - start;
    }
    __syncthreads();
    float inv = 1.f / fmaxf((float)cnt_s, 1.f);
    p[threadIdx.x] = sums[g * 128 + threadIdx.x] * inv;
    __syncthreads();
    if (threadIdx.x < 10) {
        float acc = bc[threadIdx.x];
        for (int k = 0; k < 128; ++k) acc += p[k] * Wc[k * 10 + threadIdx.x];
        outp[g * 10 + threadIdx.x] = acc;
    }
}

extern "C" void kernel_launch(void* const* d_in, const int* in_sizes, int n_in,
                              void* d_out, int out_size, void* d_ws, size_t ws_size,
                              hipStream_t stream) {
    const float* x     = (const float*)d_in[0];
    const int*   ei    = (const int*)d_in[1];
    const int*   batch = (const int*)d_in[2];
    const float* nc    = (const float*)d_in[3];
    const float* ec    = (const float*)d_in[4];
    const float* W0    = (const float*)d_in[5];
    const float* as0   = (const float*)d_in[6];
    const float* ad0   = (const float*)d_in[7];
    const float* b0    = (const float*)d_in[8];
    const float* W1    = (const float*)d_in[9];
    const float* as1   = (const float*)d_in[10];
    const float* ad1   = (const float*)d_in[11];
    const float* b1    = (const float*)d_in[12];
    const float* Wc    = (const float*)d_in[13];
    const float* bc    = (const float*)d_in[14];
    float* out = (float*)d_out;

    char* ws = (char*)d_ws;
    size_t off = 0;
    auto alloc = [&](size_t bytes) { void* p = ws + off; off += (bytes + 255) & ~size_t(255); return p; };
    unsigned*  Hb       = (unsigned*)alloc(sizeof(unsigned) * N_NODES * 64);    // fp16 H (pre-attn)
    _Float16*  Xh       = (_Float16*)alloc(sizeof(_Float16) * N_NODES * 128);   // fp16 layer-1 input
    _Float16*  Ob       = (_Float16*)alloc(sizeof(_Float16) * N_NODES * 128);   // fp16 layer-1 output
    float*     als      = (float*)alloc(sizeof(float) * N_NODES * 2);
    float*     ald      = (float*)alloc(sizeof(float) * N_NODES * 2);
    _Float16*  Wt0      = (_Float16*)alloc(sizeof(_Float16) * 128 * 128);
    _Float16*  Wt1      = (_Float16*)alloc(sizeof(_Float16) * 128 * 128);
    int*       deg      = (int*)alloc(sizeof(int) * N_NODES);
    int*       rank     = (int*)alloc(sizeof(int) * EA);
    int*       part     = (int*)alloc(sizeof(int) * NB_SCAN);
    int*       rowstart = (int*)alloc(sizeof(int) * (N_NODES + 1));
    uint2*     csr2     = (uint2*)alloc(sizeof(uint2) * EA);
    float*     sums     = (float*)alloc(sizeof(float) * NG * 128);

    init_kernel<<<NB_SCAN, 256, 0, stream>>>(W0, W1, Wt0, Wt1, deg, sums);
    hist_kernel<<<(EA + 255) / 256, 256, 0, stream>>>(ei, deg, rank);
    partial_kernel<<<NB_SCAN, 256, 0, stream>>>(deg, part);
    rowstart_kernel<<<NB_SCAN, 256, 0, stream>>>(deg, part, rowstart);
    build_kernel<<<(EA + 255) / 256, 256, 0, stream>>>(ei, ec, nc, rowstart, rank, csr2);

    int gemm_grid   = (N_NODES + 63) / 64;            // 782
    int nwaveblocks = (N_NODES + 3) / 4;              // 12500

    // layer 0
    gemm_mfma<1><<<gemm_grid, 256, 0, stream>>>(x, Wt0, as0, ad0, Hb, als, ald);
    agg_kernel<<<nwaveblocks, 256, 0, stream>>>((const uint4*)Hb, csr2, als, ald, rowstart, b0, Xh);

    // layer 1
    gemm_mfma<0><<<gemm_grid, 256, 0, stream>>>(Xh, Wt1, as1, ad1, Hb, als, ald);
    agg_kernel<<<nwaveblocks, 256, 0, stream>>>((const uint4*)Hb, csr2, als, ald, rowstart, b1, Ob);

    // pool (chunked partials) + classifier
    pool_partial<<<(N_NODES + PCH - 1) / PCH, 256, 0, stream>>>((const half2t*)Ob, batch, sums);
    cls_kernel<<<NG, 128, 0, stream>>>(sums, batch, Wc, bc, out);
}